// Round 1
// 1549.267 us; speedup vs baseline: 1.7245x; 1.7245x over previous
//
#include <hip/hip_runtime.h>

typedef unsigned short u16;
typedef short short8 __attribute__((ext_vector_type(8)));
typedef float floatx4 __attribute__((ext_vector_type(4)));

__device__ __forceinline__ float b2f(u16 h) {
  union { unsigned int u; float f; } z;
  z.u = ((unsigned int)h) << 16;
  return z.f;
}
__device__ __forceinline__ u16 f2b(float f) {
  union { float f; unsigned int u; } z;
  z.f = f;
  unsigned int u = z.u;
  unsigned int r = (u + 0x7fffu + ((u >> 16) & 1u)) >> 16;
  return (u16)r;
}

// ---------------- softmax over the 3 lambda scalars (fp32) -> scale weights ---------
__global__ void softmax3_kernel(const float* __restrict__ lam, float* __restrict__ w) {
  if (threadIdx.x == 0) {
    float a = lam[0], b = lam[1], c = lam[2];
    float m = fmaxf(a, fmaxf(b, c));
    float ea = __expf(a - m), eb = __expf(b - m), ec = __expf(c - m);
    float s = ea + eb + ec;
    w[0] = ea / s; w[1] = eb / s; w[2] = ec / s;
  }
}

// ---------------- cast fp32 -> bf16, 8 elems/thread ---------------------------------
__global__ __launch_bounds__(256)
void cast_f32_bf16(const float* __restrict__ src, u16* __restrict__ dst) {
  const long i = ((long)blockIdx.x * 256 + threadIdx.x) * 8;
  float4 v0 = *(const float4*)(src + i);
  float4 v1 = *(const float4*)(src + i + 4);
  u16 r[8] __attribute__((aligned(16)));
  r[0] = f2b(v0.x); r[1] = f2b(v0.y); r[2] = f2b(v0.z); r[3] = f2b(v0.w);
  r[4] = f2b(v1.x); r[5] = f2b(v1.y); r[6] = f2b(v1.z); r[7] = f2b(v1.w);
  *(uint4*)(dst + i) = *(const uint4*)r;
}

// ---------------- transpose fp32 src (b,R,Cc) -> bf16 dst (b,Cc,R) ------------------
__global__ __launch_bounds__(256)
void transpose_f32(const float* __restrict__ src, u16* __restrict__ dst,
                   int R, int Cc, long sSrc, long sDst) {
  __shared__ u16 t[64][66];
  const int tid = threadIdx.x;
  const long r0 = (long)blockIdx.x << 6;
  const long c0 = (long)blockIdx.y << 6;
  const float* s = src + (long)blockIdx.z * sSrc;
  u16* d = dst + (long)blockIdx.z * sDst;
  const int rr = tid >> 2;
  const int cb = (tid & 3) << 2;  // 0,4,8,12
#pragma unroll
  for (int h = 0; h < 4; h++) {
    int cc = cb + h * 16;
    float4 v = *(const float4*)(s + (r0 + rr) * Cc + c0 + cc);
    t[rr][cc + 0] = f2b(v.x); t[rr][cc + 1] = f2b(v.y);
    t[rr][cc + 2] = f2b(v.z); t[rr][cc + 3] = f2b(v.w);
  }
  __syncthreads();
  const int cr = tid >> 2;
  const int nb0 = (tid & 3) << 3;
#pragma unroll
  for (int h = 0; h < 2; h++) {
    int rb = nb0 + h * 32;
    u16 res[8] __attribute__((aligned(16)));
#pragma unroll
    for (int j = 0; j < 8; j++) res[j] = t[rb + j][cr];
    *(uint4*)(d + (c0 + cr) * R + r0 + rb) = *(const uint4*)res;
  }
}

// ---------------- GEMM: C = alpha * A(row-major MxK) * B^T (B is NxK row-major) ------
// BIAS_MODE: 0 none, 1 per-n, 2 per-m (bias fp32). OUT_F32: fp32 out else bf16.
// BMASK: if nonzero, B's k index is wrapped (k & BMASK) -> implicit K-repeat of B.
template <int BIAS_MODE, bool OUT_F32, bool BETA_ACC, int BMASK>
__global__ __launch_bounds__(256)
void gemm_nt(const u16* __restrict__ A, long sA, int lda,
             const u16* __restrict__ Bm, long sB, int ldb,
             void* __restrict__ Cv, long sC, int ldc,
             const float* __restrict__ bias,
             const float* __restrict__ alphap, float alphac, int K) {
  __shared__ __align__(16) u16 As[128][40];
  __shared__ __align__(16) u16 Bs[128][40];
  const int tid = threadIdx.x;
  const long m0 = (long)blockIdx.x * 128;
  const long n0 = (long)blockIdx.y * 128;
  const u16* Ab = A + (long)blockIdx.z * sA + m0 * lda;
  const u16* Bb = Bm + (long)blockIdx.z * sB + n0 * ldb;
  const int sm = tid >> 2;
  const int sk = (tid & 3) << 3;
  const int wave = tid >> 6;
  const int lane = tid & 63;
  const int wr = (wave >> 1) << 6;
  const int wc = (wave & 1) << 6;
  const int quad = lane >> 4;
  const int lr = lane & 15;
  floatx4 acc[4][4] = {};
  for (int k0 = 0; k0 < K; k0 += 32) {
    const int kb = BMASK ? (k0 & BMASK) : k0;
    uint4 a0 = *(const uint4*)(Ab + (long)sm * lda + k0 + sk);
    uint4 a1 = *(const uint4*)(Ab + (long)(sm + 64) * lda + k0 + sk);
    uint4 b0 = *(const uint4*)(Bb + (long)sm * ldb + kb + sk);
    uint4 b1 = *(const uint4*)(Bb + (long)(sm + 64) * ldb + kb + sk);
    __syncthreads();
    *(uint4*)(&As[sm][sk]) = a0;
    *(uint4*)(&As[sm + 64][sk]) = a1;
    *(uint4*)(&Bs[sm][sk]) = b0;
    *(uint4*)(&Bs[sm + 64][sk]) = b1;
    __syncthreads();
    short8 af[4], bfr[4];
#pragma unroll
    for (int i = 0; i < 4; i++) af[i] = *(const short8*)(&As[wr + i * 16 + lr][quad << 3]);
#pragma unroll
    for (int j = 0; j < 4; j++) bfr[j] = *(const short8*)(&Bs[wc + j * 16 + lr][quad << 3]);
#pragma unroll
    for (int i = 0; i < 4; i++)
#pragma unroll
      for (int j = 0; j < 4; j++)
        acc[i][j] = __builtin_amdgcn_mfma_f32_16x16x32_bf16(af[i], bfr[j], acc[i][j], 0, 0, 0);
  }
  const float alpha = alphac * (alphap ? alphap[0] : 1.0f);
  const long cb = (long)blockIdx.z * sC;
#pragma unroll
  for (int i = 0; i < 4; i++) {
#pragma unroll
    for (int r = 0; r < 4; r++) {
      long m = m0 + wr + i * 16 + quad * 4 + r;
      float bm = (BIAS_MODE == 2) ? bias[m] : 0.0f;
#pragma unroll
      for (int j = 0; j < 4; j++) {
        long n = n0 + wc + j * 16 + lr;
        float v = alpha * acc[i][j][r];
        if (BIAS_MODE == 1) v += bias[n];
        if (BIAS_MODE == 2) v += bm;
        long off = cb + m * (long)ldc + n;
        if (OUT_F32) {
          float* Cf = (float*)Cv;
          if (BETA_ACC) v += Cf[off];
          Cf[off] = v;
        } else {
          ((u16*)Cv)[off] = f2b(v);
        }
      }
    }
  }
}

// ---------------- bkq[b,l] = 0.03125 * sum_c ktxt[b,l,c] * bq[c] ---------------------
__global__ __launch_bounds__(256)
void bkq_kernel(const u16* __restrict__ ktxt, const float* __restrict__ bq,
                float* __restrict__ bkq) {
  const long row = (long)blockIdx.x * 4 + (threadIdx.x >> 6);  // [0, 8192)
  const int lane = threadIdx.x & 63;
  const u16* kr = ktxt + row * 1024;
  float s = 0.f;
#pragma unroll
  for (int h = 0; h < 2; h++) {
    uint4 kv = *(const uint4*)(kr + h * 512 + lane * 8);
    const u16* ku = (const u16*)&kv;
    float4 b0 = *(const float4*)(bq + h * 512 + lane * 8);
    float4 b1 = *(const float4*)(bq + h * 512 + lane * 8 + 4);
    s += b2f(ku[0]) * b0.x + b2f(ku[1]) * b0.y + b2f(ku[2]) * b0.z + b2f(ku[3]) * b0.w +
         b2f(ku[4]) * b1.x + b2f(ku[5]) * b1.y + b2f(ku[6]) * b1.z + b2f(ku[7]) * b1.w;
  }
#pragma unroll
  for (int o = 32; o > 0; o >>= 1) s += __shfl_xor(s, o);
  if (lane == 0) bkq[row] = 0.03125f * s;
}

// ---------------- horizontal pool pass on S1 (chunk rows = 4608, row len 512) --------
// dst[n,l] = sum_{dx} src[n+dx, l] (same y only; no normalization here)
template <int KP>
__global__ __launch_bounds__(256)
void hpool(const float* __restrict__ src, float* __restrict__ dst) {
  const int row = blockIdx.x;                 // [0, 4608)
  const int x = (row % 2304) % 48;
  const int t = threadIdx.x;
  float2 s = {0.f, 0.f};
#pragma unroll
  for (int dx = -(KP / 2); dx <= KP / 2; dx++) {
    int xx = x + dx;
    if (xx < 0 || xx >= 48) continue;
    float2 v = *(const float2*)(src + (long)(row + dx) * 512 + t * 2);
    s.x += v.x; s.y += v.y;
  }
  *(float2*)(dst + (long)row * 512 + t * 2) = s;
}

// ---------------- vertical pool + bkq + softmax + *w -> bf16 P slice -----------------
// KP==1: src is S1 directly. KP>1: src is hpool output; divides by KP*KP.
template <int KP>
__global__ __launch_bounds__(256)
void vp_softmax(const float* __restrict__ src, const float* __restrict__ bkq,
                u16* __restrict__ P, int colOff,
                const float* __restrict__ wts, int widx) {
  const int row = blockIdx.x * 4 + (threadIdx.x >> 6);  // [0, 4608)
  const int lane = threadIdx.x & 63;
  const int bloc = row / 2304;
  const int nn = row - bloc * 2304;
  const int y = nn / 48;
  float4 a0 = {0.f, 0.f, 0.f, 0.f}, a1 = {0.f, 0.f, 0.f, 0.f};
#pragma unroll
  for (int dy = -(KP / 2); dy <= KP / 2; dy++) {
    int yy = y + dy;
    if (yy < 0 || yy >= 48) continue;
    const float* r = src + (long)(row + dy * 48) * 512;
    float4 v0 = *(const float4*)(r + lane * 4);
    float4 v1 = *(const float4*)(r + 256 + lane * 4);
    a0.x += v0.x; a0.y += v0.y; a0.z += v0.z; a0.w += v0.w;
    a1.x += v1.x; a1.y += v1.y; a1.z += v1.z; a1.w += v1.w;
  }
  const float ik = 1.0f / (float)(KP * KP);
  const float* bk = bkq + (long)bloc * 512;
  float4 q0 = *(const float4*)(bk + lane * 4);
  float4 q1v = *(const float4*)(bk + 256 + lane * 4);
  a0.x = a0.x * ik + q0.x;  a0.y = a0.y * ik + q0.y;
  a0.z = a0.z * ik + q0.z;  a0.w = a0.w * ik + q0.w;
  a1.x = a1.x * ik + q1v.x; a1.y = a1.y * ik + q1v.y;
  a1.z = a1.z * ik + q1v.z; a1.w = a1.w * ik + q1v.w;
  float m = fmaxf(fmaxf(fmaxf(a0.x, a0.y), fmaxf(a0.z, a0.w)),
                  fmaxf(fmaxf(a1.x, a1.y), fmaxf(a1.z, a1.w)));
#pragma unroll
  for (int o = 32; o > 0; o >>= 1) m = fmaxf(m, __shfl_xor(m, o));
  float e0 = __expf(a0.x - m), e1 = __expf(a0.y - m), e2 = __expf(a0.z - m), e3 = __expf(a0.w - m);
  float e4 = __expf(a1.x - m), e5 = __expf(a1.y - m), e6 = __expf(a1.z - m), e7 = __expf(a1.w - m);
  float s = ((e0 + e1) + (e2 + e3)) + ((e4 + e5) + (e6 + e7));
#pragma unroll
  for (int o = 32; o > 0; o >>= 1) s += __shfl_xor(s, o);
  const float inv = wts[widx] / s;
  union { u16 u[4]; uint2 v; } pk;
  u16* pr = P + (long)row * 1536 + colOff;
  pk.u[0] = f2b(e0 * inv); pk.u[1] = f2b(e1 * inv); pk.u[2] = f2b(e2 * inv); pk.u[3] = f2b(e3 * inv);
  *(uint2*)(pr + lane * 4) = pk.v;
  pk.u[0] = f2b(e4 * inv); pk.u[1] = f2b(e5 * inv); pk.u[2] = f2b(e6 * inv); pk.u[3] = f2b(e7 * inv);
  *(uint2*)(pr + 256 + lane * 4) = pk.v;
}

// ---------------- epilogue: out(b,c,n) = v_feat(b,c,n) + agg(b,n,c) (all fp32) -------
__global__ __launch_bounds__(256)
void epilogue_kernel(const float* __restrict__ agg, const float* __restrict__ vfeat,
                     float* __restrict__ out) {
  __shared__ float t[64][65];
  const int tid = threadIdx.x;
  const long n0 = (long)blockIdx.x << 6;
  const long c0 = (long)blockIdx.y << 6;
  const long b = blockIdx.z;
  const float* a = agg + b * (2304L * 1024);
  const int nr = tid >> 2;
  const int cb4 = (tid & 3) << 4;
#pragma unroll
  for (int h = 0; h < 4; h++) {
    int cc = cb4 + h * 4;
    float4 v = *(const float4*)(a + (n0 + nr) * 1024 + c0 + cc);
    t[nr][cc + 0] = v.x; t[nr][cc + 1] = v.y; t[nr][cc + 2] = v.z; t[nr][cc + 3] = v.w;
  }
  __syncthreads();
  const int cr = tid >> 2;
  const int nbase = (tid & 3) << 3;
#pragma unroll
  for (int h = 0; h < 2; h++) {
    int nb = nbase + h * 32;
    long row = (b * 1024 + c0 + cr) * 2304 + n0 + nb;
    float4 vf0 = *(const float4*)(vfeat + row);
    float4 vf1 = *(const float4*)(vfeat + row + 4);
    float4 o0, o1;
    o0.x = t[nb + 0][cr] + vf0.x; o0.y = t[nb + 1][cr] + vf0.y;
    o0.z = t[nb + 2][cr] + vf0.z; o0.w = t[nb + 3][cr] + vf0.w;
    o1.x = t[nb + 4][cr] + vf1.x; o1.y = t[nb + 5][cr] + vf1.y;
    o1.z = t[nb + 6][cr] + vf1.z; o1.w = t[nb + 7][cr] + vf1.w;
    *(float4*)(out + row) = o0;
    *(float4*)(out + row + 4) = o1;
  }
}

extern "C" void kernel_launch(void* const* d_in, const int* in_sizes, int n_in,
                              void* d_out, int out_size, void* d_ws, size_t ws_size,
                              hipStream_t stream) {
  const float* v_feat = (const float*)d_in[0];
  const float* t_tok  = (const float*)d_in[1];
  const float* Wq  = (const float*)d_in[2];
  const float* bq  = (const float*)d_in[3];
  const float* Wk  = (const float*)d_in[4];
  const float* bk  = (const float*)d_in[5];
  const float* Wv  = (const float*)d_in[6];
  const float* bv  = (const float*)d_in[7];
  const float* lam = (const float*)d_in[8];

  // Workspace layout (90.7 MB total; NB=2 batch chunks):
  //  globals: wts | WqT | WkT | WvT | ktxt | vtxtT | bkq            = 38,830,336 B
  //  chunk union (51,904,512 B): tt16 (12.6 MB, pre-loop only)
  //      vflat(9.44) q1(9.44) S1(9.44) hs(9.44) P(14.16); agg(18.87) aliases S1+hs
  char* const wsb = (char*)d_ws;
  float* wts  = (float*)(wsb);
  u16* WqT    = (u16*)(wsb + 256);
  u16* WkT    = (u16*)(wsb + 2097408);
  u16* WvT    = (u16*)(wsb + 3670272);
  u16* ktxt   = (u16*)(wsb + 5243136);     // (B*L, C) bf16, 16.8 MB
  u16* vtxtT  = (u16*)(wsb + 22020352);    // (B, C, L) bf16, 16.8 MB
  float* bkq  = (float*)(wsb + 38797568);  // (B, L) fp32, 32 KB
  char* const chunk = wsb + 38830336;
  u16* tt16   = (u16*)chunk;               // (B*L, Ct) bf16 (pre-loop; aliases vflat/q1)
  u16* vflat  = (u16*)chunk;               // (NB*N, C) bf16
  u16* q1     = (u16*)(chunk + 9437184);   // (NB*N, C) bf16 (no bias!)
  float* S1   = (float*)(chunk + 18874368);// (NB*N, L) fp32
  float* hs   = (float*)(chunk + 28311552);// (NB*N, L) fp32 horizontal-pool temp
  float* aggc = (float*)(chunk + 18874368);// (NB*N, C) fp32 — aliases S1+hs (dead by PV)
  u16* Pc     = (u16*)(chunk + 37748736);  // (NB*N, 3*L) bf16

  float* out0 = (float*)d_out;
  const long CN = 1024L * 2304;

  softmax3_kernel<<<1, 64, 0, stream>>>(lam, wts);

  transpose_f32<<<dim3(16, 16, 1), 256, 0, stream>>>(Wq, WqT, 1024, 1024, 0, 0);
  transpose_f32<<<dim3(12, 16, 1), 256, 0, stream>>>(Wk, WkT, 768, 1024, 0, 0);
  transpose_f32<<<dim3(12, 16, 1), 256, 0, stream>>>(Wv, WvT, 768, 1024, 0, 0);
  cast_f32_bf16<<<3072, 256, 0, stream>>>(t_tok, tt16);  // 6291456 elems

  // k_txt = t_tok_flat @ Wk + bk : (8192,1024), K=768
  gemm_nt<1, false, false, 0><<<dim3(64, 8, 1), 256, 0, stream>>>(
      tt16, 0, 768, WkT, 0, 768, ktxt, 0, 1024, bk, nullptr, 1.0f, 768);
  // v_txtT(b) = Wv^T @ t_tok(b)^T + bv (per-m) : (1024,512) per batch, K=768
  gemm_nt<2, false, false, 0><<<dim3(8, 4, 16), 256, 0, stream>>>(
      WvT, 0, 768, tt16, 512L * 768, 768, vtxtT, 1024L * 512, 512, bv, nullptr, 1.0f, 768);
  // bkq[b,l] = scale * ktxt[b,l,:] . bq  (rank-1 softmax-logit correction for the
  // bias that must be excluded from pooling: pool_k(const) != const at borders)
  bkq_kernel<<<2048, 256, 0, stream>>>(ktxt, bq, bkq);

  for (int ch = 0; ch < 8; ch++) {
    const long bb = 2L * ch;
    const float* vf_ch = v_feat + bb * CN;
    // vflat = transpose(v_feat chunk) as bf16: (NB*N, C)
    transpose_f32<<<dim3(16, 36, 2), 256, 0, stream>>>(
        vf_ch, vflat, 1024, 2304, CN, 2304L * 1024);
    // q1 = vflat @ Wq (NO bias — pooling commutes only with the bias pulled out)
    gemm_nt<0, false, false, 0><<<dim3(36, 8, 1), 256, 0, stream>>>(
        vflat, 0, 1024, WqT, 0, 1024, q1, 0, 1024, nullptr, nullptr, 1.0f, 1024);
    // S1 = (q1 @ ktxt^T) / 32  (fp32, per batch)
    gemm_nt<0, true, false, 0><<<dim3(18, 4, 2), 256, 0, stream>>>(
        q1, 2304L * 1024, 1024, ktxt + bb * (512L * 1024), 512L * 1024, 1024,
        S1, 2304L * 512, 512, nullptr, nullptr, 0.03125f, 1024);
    // scale 1: P[:,0:512] = w0 * softmax(S1 + bkq)
    vp_softmax<1><<<1152, 256, 0, stream>>>(S1, bkq + bb * 512, Pc, 0, wts, 0);
    // scale 3: pool3(S1) = pool3 of S applied in logit space (pooling commutes
    // with the channel-wise linears); separable h-then-v, softmax fused in v-pass.
    hpool<3><<<4608, 256, 0, stream>>>(S1, hs);
    vp_softmax<3><<<1152, 256, 0, stream>>>(hs, bkq + bb * 512, Pc, 512, wts, 1);
    // scale 5
    hpool<5><<<4608, 256, 0, stream>>>(S1, hs);
    vp_softmax<5><<<1152, 256, 0, stream>>>(hs, bkq + bb * 512, Pc, 1024, wts, 2);
    // agg = P_all @ [V;V;V] in one K=1536 GEMM (B k-index wrapped & 511;
    // scale weights already folded into P) — no fp32 agg read-modify-write.
    gemm_nt<0, true, false, 511><<<dim3(18, 8, 2), 256, 0, stream>>>(
        Pc, 2304L * 1536, 1536, vtxtT + bb * (1024L * 512), 1024L * 512, 512,
        aggc, 2304L * 1024, 1024, nullptr, nullptr, 1.0f, 1536);
    // out chunk = v_feat + agg^T (fp32)
    epilogue_kernel<<<dim3(36, 16, 2), 256, 0, stream>>>(aggc, vf_ch, out0 + bb * CN);
  }

  // out1 = t_tok (raw fp32 copy)
  hipMemcpyAsync((void*)(out0 + 37748736L), (const void*)t_tok, 25165824L,
                 hipMemcpyDeviceToDevice, stream);
}

// Round 2
// 1391.823 us; speedup vs baseline: 1.9195x; 1.1131x over previous
//
#include <hip/hip_runtime.h>

typedef unsigned short u16;
typedef short short8 __attribute__((ext_vector_type(8)));
typedef float floatx4 __attribute__((ext_vector_type(4)));

__device__ __forceinline__ float b2f(u16 h) {
  union { unsigned int u; float f; } z;
  z.u = ((unsigned int)h) << 16;
  return z.f;
}
__device__ __forceinline__ u16 f2b(float f) {
  union { float f; unsigned int u; } z;
  z.f = f;
  unsigned int u = z.u;
  unsigned int r = (u + 0x7fffu + ((u >> 16) & 1u)) >> 16;
  return (u16)r;
}

// ---------------- softmax over the 3 lambda scalars (fp32) -> scale weights ---------
__global__ void softmax3_kernel(const float* __restrict__ lam, float* __restrict__ w) {
  if (threadIdx.x == 0) {
    float a = lam[0], b = lam[1], c = lam[2];
    float m = fmaxf(a, fmaxf(b, c));
    float ea = __expf(a - m), eb = __expf(b - m), ec = __expf(c - m);
    float s = ea + eb + ec;
    w[0] = ea / s; w[1] = eb / s; w[2] = ec / s;
  }
}

// ---------------- cast fp32 -> bf16, 8 elems/thread ---------------------------------
__global__ __launch_bounds__(256)
void cast_f32_bf16(const float* __restrict__ src, u16* __restrict__ dst) {
  const long i = ((long)blockIdx.x * 256 + threadIdx.x) * 8;
  float4 v0 = *(const float4*)(src + i);
  float4 v1 = *(const float4*)(src + i + 4);
  u16 r[8] __attribute__((aligned(16)));
  r[0] = f2b(v0.x); r[1] = f2b(v0.y); r[2] = f2b(v0.z); r[3] = f2b(v0.w);
  r[4] = f2b(v1.x); r[5] = f2b(v1.y); r[6] = f2b(v1.z); r[7] = f2b(v1.w);
  *(uint4*)(dst + i) = *(const uint4*)r;
}

// ---------------- transpose fp32 src (b,R,Cc) -> bf16 dst (b,Cc,R) ------------------
__global__ __launch_bounds__(256)
void transpose_f32(const float* __restrict__ src, u16* __restrict__ dst,
                   int R, int Cc, long sSrc, long sDst) {
  __shared__ u16 t[64][66];
  const int tid = threadIdx.x;
  const long r0 = (long)blockIdx.x << 6;
  const long c0 = (long)blockIdx.y << 6;
  const float* s = src + (long)blockIdx.z * sSrc;
  u16* d = dst + (long)blockIdx.z * sDst;
  const int rr = tid >> 2;
  const int cb = (tid & 3) << 2;  // 0,4,8,12
#pragma unroll
  for (int h = 0; h < 4; h++) {
    int cc = cb + h * 16;
    float4 v = *(const float4*)(s + (r0 + rr) * Cc + c0 + cc);
    t[rr][cc + 0] = f2b(v.x); t[rr][cc + 1] = f2b(v.y);
    t[rr][cc + 2] = f2b(v.z); t[rr][cc + 3] = f2b(v.w);
  }
  __syncthreads();
  const int cr = tid >> 2;
  const int nb0 = (tid & 3) << 3;
#pragma unroll
  for (int h = 0; h < 2; h++) {
    int rb = nb0 + h * 32;
    u16 res[8] __attribute__((aligned(16)));
#pragma unroll
    for (int j = 0; j < 8; j++) res[j] = t[rb + j][cr];
    *(uint4*)(d + (c0 + cr) * R + r0 + rb) = *(const uint4*)res;
  }
}

// ---------------- GEMM: C = alpha * A(row-major MxK) * B^T (B is NxK row-major) ------
// BIAS_MODE: 0 none, 1 per-n, 2 per-m (bias fp32).
// OUT_MODE: 0 bf16, 1 fp32, 2 fp32 transposed + residual add (out[n][m] = acc + resid).
// BMASK: if nonzero, B's k index is wrapped (k & BMASK) -> implicit K-repeat of B.
template <int BIAS_MODE, int OUT_MODE, bool BETA_ACC, int BMASK>
__global__ __launch_bounds__(256)
void gemm_nt(const u16* __restrict__ A, long sA, int lda,
             const u16* __restrict__ Bm, long sB, int ldb,
             void* __restrict__ Cv, long sC, int ldc,
             const float* __restrict__ bias, const float* __restrict__ resid,
             const float* __restrict__ alphap, float alphac, int K) {
  __shared__ __align__(16) u16 As[128][40];
  __shared__ __align__(16) u16 Bs[128][40];
  const int tid = threadIdx.x;
  const long m0 = (long)blockIdx.x * 128;
  const long n0 = (long)blockIdx.y * 128;
  const u16* Ab = A + (long)blockIdx.z * sA + m0 * lda;
  const u16* Bb = Bm + (long)blockIdx.z * sB + n0 * ldb;
  const int sm = tid >> 2;
  const int sk = (tid & 3) << 3;
  const int wave = tid >> 6;
  const int lane = tid & 63;
  const int wr = (wave >> 1) << 6;
  const int wc = (wave & 1) << 6;
  const int quad = lane >> 4;
  const int lr = lane & 15;
  floatx4 acc[4][4] = {};
  for (int k0 = 0; k0 < K; k0 += 32) {
    const int kb = BMASK ? (k0 & BMASK) : k0;
    uint4 a0 = *(const uint4*)(Ab + (long)sm * lda + k0 + sk);
    uint4 a1 = *(const uint4*)(Ab + (long)(sm + 64) * lda + k0 + sk);
    uint4 b0 = *(const uint4*)(Bb + (long)sm * ldb + kb + sk);
    uint4 b1 = *(const uint4*)(Bb + (long)(sm + 64) * ldb + kb + sk);
    __syncthreads();
    *(uint4*)(&As[sm][sk]) = a0;
    *(uint4*)(&As[sm + 64][sk]) = a1;
    *(uint4*)(&Bs[sm][sk]) = b0;
    *(uint4*)(&Bs[sm + 64][sk]) = b1;
    __syncthreads();
    short8 af[4], bfr[4];
#pragma unroll
    for (int i = 0; i < 4; i++) af[i] = *(const short8*)(&As[wr + i * 16 + lr][quad << 3]);
#pragma unroll
    for (int j = 0; j < 4; j++) bfr[j] = *(const short8*)(&Bs[wc + j * 16 + lr][quad << 3]);
#pragma unroll
    for (int i = 0; i < 4; i++)
#pragma unroll
      for (int j = 0; j < 4; j++)
        acc[i][j] = __builtin_amdgcn_mfma_f32_16x16x32_bf16(af[i], bfr[j], acc[i][j], 0, 0, 0);
  }
  const float alpha = alphac * (alphap ? alphap[0] : 1.0f);
  const long cb = (long)blockIdx.z * sC;
  if (OUT_MODE == 2) {
    // transposed residual store: out[n][m..m+3] = alpha*acc + resid[n][m..m+3]
#pragma unroll
    for (int i = 0; i < 4; i++) {
      long m4 = m0 + wr + i * 16 + quad * 4;
#pragma unroll
      for (int j = 0; j < 4; j++) {
        long n = n0 + wc + j * 16 + lr;
        long off = cb + n * (long)ldc + m4;
        float4 vf = *(const float4*)(resid + off);
        float4 o;
        o.x = alpha * acc[i][j][0] + vf.x;
        o.y = alpha * acc[i][j][1] + vf.y;
        o.z = alpha * acc[i][j][2] + vf.z;
        o.w = alpha * acc[i][j][3] + vf.w;
        *(float4*)((float*)Cv + off) = o;
      }
    }
  } else {
#pragma unroll
    for (int i = 0; i < 4; i++) {
#pragma unroll
      for (int r = 0; r < 4; r++) {
        long m = m0 + wr + i * 16 + quad * 4 + r;
        float bm = (BIAS_MODE == 2) ? bias[m] : 0.0f;
#pragma unroll
        for (int j = 0; j < 4; j++) {
          long n = n0 + wc + j * 16 + lr;
          float v = alpha * acc[i][j][r];
          if (BIAS_MODE == 1) v += bias[n];
          if (BIAS_MODE == 2) v += bm;
          long off = cb + m * (long)ldc + n;
          if (OUT_MODE == 1) {
            float* Cf = (float*)Cv;
            if (BETA_ACC) v += Cf[off];
            Cf[off] = v;
          } else {
            ((u16*)Cv)[off] = f2b(v);
          }
        }
      }
    }
  }
}

// ---------------- bkq[b,l] = 0.03125 * sum_c ktxt[b,l,c] * bq[c] ---------------------
__global__ __launch_bounds__(256)
void bkq_kernel(const u16* __restrict__ ktxt, const float* __restrict__ bq,
                float* __restrict__ bkq) {
  const long row = (long)blockIdx.x * 4 + (threadIdx.x >> 6);  // [0, 8192)
  const int lane = threadIdx.x & 63;
  const u16* kr = ktxt + row * 1024;
  float s = 0.f;
#pragma unroll
  for (int h = 0; h < 2; h++) {
    uint4 kv = *(const uint4*)(kr + h * 512 + lane * 8);
    const u16* ku = (const u16*)&kv;
    float4 b0 = *(const float4*)(bq + h * 512 + lane * 8);
    float4 b1 = *(const float4*)(bq + h * 512 + lane * 8 + 4);
    s += b2f(ku[0]) * b0.x + b2f(ku[1]) * b0.y + b2f(ku[2]) * b0.z + b2f(ku[3]) * b0.w +
         b2f(ku[4]) * b1.x + b2f(ku[5]) * b1.y + b2f(ku[6]) * b1.z + b2f(ku[7]) * b1.w;
  }
#pragma unroll
  for (int o = 32; o > 0; o >>= 1) s += __shfl_xor(s, o);
  if (lane == 0) bkq[row] = 0.03125f * s;
}

// ---------------- fused: hpool3+hpool5 (one S1 read) + scale-1 softmax -> P[:,0:512] --
// One wave per row. hs3/hs5 get raw horizontal sums (normalized later in vp35).
__global__ __launch_bounds__(256)
void hpool35sm(const float* __restrict__ S1, const float* __restrict__ bkq,
               float* __restrict__ hs3, float* __restrict__ hs5,
               u16* __restrict__ P, const float* __restrict__ wts) {
  const int row = blockIdx.x * 4 + (threadIdx.x >> 6);  // [0, 4608)
  const int lane = threadIdx.x & 63;
  const int bloc = row / 2304;
  const int nn = row - bloc * 2304;
  const int x = nn % 48;
  float4 c0 = {0.f, 0.f, 0.f, 0.f}, c1 = {0.f, 0.f, 0.f, 0.f};
  float4 s3a = {0.f, 0.f, 0.f, 0.f}, s3b = {0.f, 0.f, 0.f, 0.f};
  float4 s5a = {0.f, 0.f, 0.f, 0.f}, s5b = {0.f, 0.f, 0.f, 0.f};
#pragma unroll
  for (int dx = -2; dx <= 2; dx++) {
    int xx = x + dx;
    if (xx < 0 || xx >= 48) continue;
    const float* r = S1 + (long)(row + dx) * 512;
    float4 v0 = *(const float4*)(r + lane * 4);
    float4 v1 = *(const float4*)(r + 256 + lane * 4);
    s5a.x += v0.x; s5a.y += v0.y; s5a.z += v0.z; s5a.w += v0.w;
    s5b.x += v1.x; s5b.y += v1.y; s5b.z += v1.z; s5b.w += v1.w;
    if (dx >= -1 && dx <= 1) {
      s3a.x += v0.x; s3a.y += v0.y; s3a.z += v0.z; s3a.w += v0.w;
      s3b.x += v1.x; s3b.y += v1.y; s3b.z += v1.z; s3b.w += v1.w;
    }
    if (dx == 0) { c0 = v0; c1 = v1; }
  }
  float* h3 = hs3 + (long)row * 512;
  float* h5 = hs5 + (long)row * 512;
  *(float4*)(h3 + lane * 4) = s3a; *(float4*)(h3 + 256 + lane * 4) = s3b;
  *(float4*)(h5 + lane * 4) = s5a; *(float4*)(h5 + 256 + lane * 4) = s5b;
  // scale-1 softmax on center row + bkq
  const float* bk = bkq + (long)bloc * 512;
  float4 q0 = *(const float4*)(bk + lane * 4);
  float4 q1v = *(const float4*)(bk + 256 + lane * 4);
  c0.x += q0.x;  c0.y += q0.y;  c0.z += q0.z;  c0.w += q0.w;
  c1.x += q1v.x; c1.y += q1v.y; c1.z += q1v.z; c1.w += q1v.w;
  float m = fmaxf(fmaxf(fmaxf(c0.x, c0.y), fmaxf(c0.z, c0.w)),
                  fmaxf(fmaxf(c1.x, c1.y), fmaxf(c1.z, c1.w)));
#pragma unroll
  for (int o = 32; o > 0; o >>= 1) m = fmaxf(m, __shfl_xor(m, o));
  float e0 = __expf(c0.x - m), e1 = __expf(c0.y - m), e2 = __expf(c0.z - m), e3 = __expf(c0.w - m);
  float e4 = __expf(c1.x - m), e5 = __expf(c1.y - m), e6 = __expf(c1.z - m), e7 = __expf(c1.w - m);
  float s = ((e0 + e1) + (e2 + e3)) + ((e4 + e5) + (e6 + e7));
#pragma unroll
  for (int o = 32; o > 0; o >>= 1) s += __shfl_xor(s, o);
  const float inv = wts[0] / s;
  union { u16 u[4]; uint2 v; } pk;
  u16* pr = P + (long)row * 1536;
  pk.u[0] = f2b(e0 * inv); pk.u[1] = f2b(e1 * inv); pk.u[2] = f2b(e2 * inv); pk.u[3] = f2b(e3 * inv);
  *(uint2*)(pr + lane * 4) = pk.v;
  pk.u[0] = f2b(e4 * inv); pk.u[1] = f2b(e5 * inv); pk.u[2] = f2b(e6 * inv); pk.u[3] = f2b(e7 * inv);
  *(uint2*)(pr + 256 + lane * 4) = pk.v;
}

// ---------------- vertical pool + bkq + softmax + *w for scales 3 & 5 (grid.y) -------
__global__ __launch_bounds__(256)
void vp35(const float* __restrict__ hs3, const float* __restrict__ hs5,
          const float* __restrict__ bkq, u16* __restrict__ P,
          const float* __restrict__ wts) {
  const int sc = blockIdx.y;  // 0 -> kp=3, 1 -> kp=5
  const float* src = sc ? hs5 : hs3;
  const int dmax = sc ? 2 : 1;
  const float ik = sc ? (1.0f / 25.0f) : (1.0f / 9.0f);
  const int colOff = sc ? 1024 : 512;
  const int widx = sc ? 2 : 1;
  const int row = blockIdx.x * 4 + (threadIdx.x >> 6);  // [0, 4608)
  const int lane = threadIdx.x & 63;
  const int bloc = row / 2304;
  const int nn = row - bloc * 2304;
  const int y = nn / 48;
  float4 a0 = {0.f, 0.f, 0.f, 0.f}, a1 = {0.f, 0.f, 0.f, 0.f};
#pragma unroll
  for (int dy = -2; dy <= 2; dy++) {
    if (dy < -dmax || dy > dmax) continue;
    int yy = y + dy;
    if (yy < 0 || yy >= 48) continue;
    const float* r = src + (long)(row + dy * 48) * 512;
    float4 v0 = *(const float4*)(r + lane * 4);
    float4 v1 = *(const float4*)(r + 256 + lane * 4);
    a0.x += v0.x; a0.y += v0.y; a0.z += v0.z; a0.w += v0.w;
    a1.x += v1.x; a1.y += v1.y; a1.z += v1.z; a1.w += v1.w;
  }
  const float* bk = bkq + (long)bloc * 512;
  float4 q0 = *(const float4*)(bk + lane * 4);
  float4 q1v = *(const float4*)(bk + 256 + lane * 4);
  a0.x = a0.x * ik + q0.x;  a0.y = a0.y * ik + q0.y;
  a0.z = a0.z * ik + q0.z;  a0.w = a0.w * ik + q0.w;
  a1.x = a1.x * ik + q1v.x; a1.y = a1.y * ik + q1v.y;
  a1.z = a1.z * ik + q1v.z; a1.w = a1.w * ik + q1v.w;
  float m = fmaxf(fmaxf(fmaxf(a0.x, a0.y), fmaxf(a0.z, a0.w)),
                  fmaxf(fmaxf(a1.x, a1.y), fmaxf(a1.z, a1.w)));
#pragma unroll
  for (int o = 32; o > 0; o >>= 1) m = fmaxf(m, __shfl_xor(m, o));
  float e0 = __expf(a0.x - m), e1 = __expf(a0.y - m), e2 = __expf(a0.z - m), e3 = __expf(a0.w - m);
  float e4 = __expf(a1.x - m), e5 = __expf(a1.y - m), e6 = __expf(a1.z - m), e7 = __expf(a1.w - m);
  float s = ((e0 + e1) + (e2 + e3)) + ((e4 + e5) + (e6 + e7));
#pragma unroll
  for (int o = 32; o > 0; o >>= 1) s += __shfl_xor(s, o);
  const float inv = wts[widx] / s;
  union { u16 u[4]; uint2 v; } pk;
  u16* pr = P + (long)row * 1536 + colOff;
  pk.u[0] = f2b(e0 * inv); pk.u[1] = f2b(e1 * inv); pk.u[2] = f2b(e2 * inv); pk.u[3] = f2b(e3 * inv);
  *(uint2*)(pr + lane * 4) = pk.v;
  pk.u[0] = f2b(e4 * inv); pk.u[1] = f2b(e5 * inv); pk.u[2] = f2b(e6 * inv); pk.u[3] = f2b(e7 * inv);
  *(uint2*)(pr + 256 + lane * 4) = pk.v;
}

extern "C" void kernel_launch(void* const* d_in, const int* in_sizes, int n_in,
                              void* d_out, int out_size, void* d_ws, size_t ws_size,
                              hipStream_t stream) {
  const float* v_feat = (const float*)d_in[0];
  const float* t_tok  = (const float*)d_in[1];
  const float* Wq  = (const float*)d_in[2];
  const float* bq  = (const float*)d_in[3];
  const float* Wk  = (const float*)d_in[4];
  const float* bk  = (const float*)d_in[5];
  const float* Wv  = (const float*)d_in[6];
  const float* bv  = (const float*)d_in[7];
  const float* lam = (const float*)d_in[8];

  // Workspace layout (81.3 MB total; NB=2 batch chunks):
  //  globals: wts | WqT | WkT | WvT | ktxt | vtxtT | bkq  = 38,830,336 B
  //  chunk union (42,467,328 B):
  //    vflat(9.44) q1(9.44) S1(9.44) P(14.16); hs3 aliases vflat, hs5 aliases q1
  //    (both dead after the S-GEMM); tt16 (12.6 MB) uses chunk pre-loop only.
  char* const wsb = (char*)d_ws;
  float* wts  = (float*)(wsb);
  u16* WqT    = (u16*)(wsb + 256);
  u16* WkT    = (u16*)(wsb + 2097408);
  u16* WvT    = (u16*)(wsb + 3670272);
  u16* ktxt   = (u16*)(wsb + 5243136);     // (B*L, C) bf16, 16.8 MB
  u16* vtxtT  = (u16*)(wsb + 22020352);    // (B, C, L) bf16, 16.8 MB
  float* bkq  = (float*)(wsb + 38797568);  // (B, L) fp32, 32 KB
  char* const chunk = wsb + 38830336;
  u16* tt16   = (u16*)chunk;               // (B*L, Ct) bf16 (pre-loop only)
  u16* vflat  = (u16*)chunk;               // (NB*N, C) bf16
  u16* q1     = (u16*)(chunk + 9437184);   // (NB*N, C) bf16 (no bias!)
  float* S1   = (float*)(chunk + 18874368);// (NB*N, L) fp32
  u16* Pc     = (u16*)(chunk + 28311552);  // (NB*N, 3*L) bf16
  float* hs3  = (float*)chunk;             // aliases vflat (dead after q1-GEMM)
  float* hs5  = (float*)(chunk + 9437184); // aliases q1 (dead after S-GEMM)

  float* out0 = (float*)d_out;
  const long CN = 1024L * 2304;

  softmax3_kernel<<<1, 64, 0, stream>>>(lam, wts);

  transpose_f32<<<dim3(16, 16, 1), 256, 0, stream>>>(Wq, WqT, 1024, 1024, 0, 0);
  transpose_f32<<<dim3(12, 16, 1), 256, 0, stream>>>(Wk, WkT, 768, 1024, 0, 0);
  transpose_f32<<<dim3(12, 16, 1), 256, 0, stream>>>(Wv, WvT, 768, 1024, 0, 0);
  cast_f32_bf16<<<3072, 256, 0, stream>>>(t_tok, tt16);  // 6291456 elems

  // k_txt = t_tok_flat @ Wk + bk : (8192,1024), K=768
  gemm_nt<1, 0, false, 0><<<dim3(64, 8, 1), 256, 0, stream>>>(
      tt16, 0, 768, WkT, 0, 768, ktxt, 0, 1024, bk, nullptr, nullptr, 1.0f, 768);
  // v_txtT(b) = Wv^T @ t_tok(b)^T + bv (per-m) : (1024,512) per batch, K=768
  gemm_nt<2, 0, false, 0><<<dim3(8, 4, 16), 256, 0, stream>>>(
      WvT, 0, 768, tt16, 512L * 768, 768, vtxtT, 1024L * 512, 512, bv, nullptr, nullptr, 1.0f, 768);
  // bkq[b,l] = scale * ktxt[b,l,:] . bq  (rank-1 softmax-logit correction for the
  // bias that must be excluded from pooling: pool_k(const) != const at borders)
  bkq_kernel<<<2048, 256, 0, stream>>>(ktxt, bq, bkq);

  for (int ch = 0; ch < 8; ch++) {
    const long bb = 2L * ch;
    const float* vf_ch = v_feat + bb * CN;
    // vflat = transpose(v_feat chunk) as bf16: (NB*N, C)
    transpose_f32<<<dim3(16, 36, 2), 256, 0, stream>>>(
        vf_ch, vflat, 1024, 2304, CN, 2304L * 1024);
    // q1 = vflat @ Wq (NO bias — pooling commutes only with the bias pulled out)
    gemm_nt<0, 0, false, 0><<<dim3(36, 8, 1), 256, 0, stream>>>(
        vflat, 0, 1024, WqT, 0, 1024, q1, 0, 1024, nullptr, nullptr, nullptr, 1.0f, 1024);
    // S1 = (q1 @ ktxt^T) / 32  (fp32, per batch)
    gemm_nt<0, 1, false, 0><<<dim3(18, 4, 2), 256, 0, stream>>>(
        q1, 2304L * 1024, 1024, ktxt + bb * (512L * 1024), 512L * 1024, 1024,
        S1, 2304L * 512, 512, nullptr, nullptr, nullptr, 0.03125f, 1024);
    // fused: hs3/hs5 horizontal sums (single S1 read) + scale-1 softmax -> P[:,0:512]
    hpool35sm<<<1152, 256, 0, stream>>>(S1, bkq + bb * 512, hs3, hs5, Pc, wts);
    // scales 3 & 5: vertical pool + bkq + softmax + weight -> P slices (one launch)
    vp35<<<dim3(1152, 2), 256, 0, stream>>>(hs3, hs5, bkq + bb * 512, Pc, wts);
    // agg = P_all @ [V;V;V] in one K=1536 GEMM (B k wrapped & 511, weights folded
    // into P). Epilogue fused: out[b,c,n] = v_feat[b,c,n] + acc (transposed store,
    // float4 over 4 consecutive spatial positions per lane quad).
    gemm_nt<0, 2, false, 511><<<dim3(18, 8, 2), 256, 0, stream>>>(
        Pc, 2304L * 1536, 1536, vtxtT + bb * (1024L * 512), 1024L * 512, 512,
        out0 + bb * CN, CN, 2304, nullptr, vf_ch, nullptr, 1.0f, 1536);
  }

  // out1 = t_tok (raw fp32 copy)
  hipMemcpyAsync((void*)(out0 + 37748736L), (const void*)t_tok, 25165824L,
                 hipMemcpyDeviceToDevice, stream);
}

// Round 3
// 1172.402 us; speedup vs baseline: 2.2788x; 1.1872x over previous
//
#include <hip/hip_runtime.h>

typedef unsigned short u16;
typedef short short8 __attribute__((ext_vector_type(8)));
typedef float floatx4 __attribute__((ext_vector_type(4)));

__device__ __forceinline__ float b2f(u16 h) {
  union { unsigned int u; float f; } z;
  z.u = ((unsigned int)h) << 16;
  return z.f;
}
__device__ __forceinline__ u16 f2b(float f) {
  union { float f; unsigned int u; } z;
  z.f = f;
  unsigned int u = z.u;
  unsigned int r = (u + 0x7fffu + ((u >> 16) & 1u)) >> 16;
  return (u16)r;
}

// ---------------- softmax over the 3 lambda scalars (fp32) -> scale weights ---------
__global__ void softmax3_kernel(const float* __restrict__ lam, float* __restrict__ w) {
  if (threadIdx.x == 0) {
    float a = lam[0], b = lam[1], c = lam[2];
    float m = fmaxf(a, fmaxf(b, c));
    float ea = __expf(a - m), eb = __expf(b - m), ec = __expf(c - m);
    float s = ea + eb + ec;
    w[0] = ea / s; w[1] = eb / s; w[2] = ec / s;
  }
}

// ---------------- cast fp32 -> bf16, 8 elems/thread ---------------------------------
__global__ __launch_bounds__(256)
void cast_f32_bf16(const float* __restrict__ src, u16* __restrict__ dst) {
  const long i = ((long)blockIdx.x * 256 + threadIdx.x) * 8;
  float4 v0 = *(const float4*)(src + i);
  float4 v1 = *(const float4*)(src + i + 4);
  u16 r[8] __attribute__((aligned(16)));
  r[0] = f2b(v0.x); r[1] = f2b(v0.y); r[2] = f2b(v0.z); r[3] = f2b(v0.w);
  r[4] = f2b(v1.x); r[5] = f2b(v1.y); r[6] = f2b(v1.z); r[7] = f2b(v1.w);
  *(uint4*)(dst + i) = *(const uint4*)r;
}

// ---------------- transpose fp32 src (b,R,Cc) -> bf16 dst (b,Cc,R) ------------------
__global__ __launch_bounds__(256)
void transpose_f32(const float* __restrict__ src, u16* __restrict__ dst,
                   int R, int Cc, long sSrc, long sDst) {
  __shared__ u16 t[64][66];
  const int tid = threadIdx.x;
  const long r0 = (long)blockIdx.x << 6;
  const long c0 = (long)blockIdx.y << 6;
  const float* s = src + (long)blockIdx.z * sSrc;
  u16* d = dst + (long)blockIdx.z * sDst;
  const int rr = tid >> 2;
  const int cb = (tid & 3) << 2;  // 0,4,8,12
#pragma unroll
  for (int h = 0; h < 4; h++) {
    int cc = cb + h * 16;
    float4 v = *(const float4*)(s + (r0 + rr) * Cc + c0 + cc);
    t[rr][cc + 0] = f2b(v.x); t[rr][cc + 1] = f2b(v.y);
    t[rr][cc + 2] = f2b(v.z); t[rr][cc + 3] = f2b(v.w);
  }
  __syncthreads();
  const int cr = tid >> 2;
  const int nb0 = (tid & 3) << 3;
#pragma unroll
  for (int h = 0; h < 2; h++) {
    int rb = nb0 + h * 32;
    u16 res[8] __attribute__((aligned(16)));
#pragma unroll
    for (int j = 0; j < 8; j++) res[j] = t[rb + j][cr];
    *(uint4*)(d + (c0 + cr) * R + r0 + rb) = *(const uint4*)res;
  }
}

// ---------------- GEMM: C = alpha * A(row-major MxK) * B^T (B is NxK row-major) ------
// BIAS_MODE: 0 none, 1 per-n, 2 per-m (bias fp32).
// OUT_MODE: 0 bf16, 1 fp32, 3 fp32 + residual add (out[m][n] = acc + resid[m][n]).
// AMASK: if nonzero, A's k index is wrapped (k & AMASK) -> implicit K-repeat of A.
template <int BIAS_MODE, int OUT_MODE, bool BETA_ACC, int AMASK>
__global__ __launch_bounds__(256)
void gemm_nt(const u16* __restrict__ A, long sA, int lda,
             const u16* __restrict__ Bm, long sB, int ldb,
             void* __restrict__ Cv, long sC, int ldc,
             const float* __restrict__ bias, const float* __restrict__ resid,
             const float* __restrict__ alphap, float alphac, int K) {
  __shared__ __align__(16) u16 As[128][40];
  __shared__ __align__(16) u16 Bs[128][40];
  const int tid = threadIdx.x;
  const long m0 = (long)blockIdx.x * 128;
  const long n0 = (long)blockIdx.y * 128;
  const u16* Ab = A + (long)blockIdx.z * sA + m0 * lda;
  const u16* Bb = Bm + (long)blockIdx.z * sB + n0 * ldb;
  const int sm = tid >> 2;
  const int sk = (tid & 3) << 3;
  const int wave = tid >> 6;
  const int lane = tid & 63;
  const int wr = (wave >> 1) << 6;
  const int wc = (wave & 1) << 6;
  const int quad = lane >> 4;
  const int lr = lane & 15;
  floatx4 acc[4][4] = {};
  for (int k0 = 0; k0 < K; k0 += 32) {
    const int ka = AMASK ? (k0 & AMASK) : k0;
    uint4 a0 = *(const uint4*)(Ab + (long)sm * lda + ka + sk);
    uint4 a1 = *(const uint4*)(Ab + (long)(sm + 64) * lda + ka + sk);
    uint4 b0 = *(const uint4*)(Bb + (long)sm * ldb + k0 + sk);
    uint4 b1 = *(const uint4*)(Bb + (long)(sm + 64) * ldb + k0 + sk);
    __syncthreads();
    *(uint4*)(&As[sm][sk]) = a0;
    *(uint4*)(&As[sm + 64][sk]) = a1;
    *(uint4*)(&Bs[sm][sk]) = b0;
    *(uint4*)(&Bs[sm + 64][sk]) = b1;
    __syncthreads();
    short8 af[4], bfr[4];
#pragma unroll
    for (int i = 0; i < 4; i++) af[i] = *(const short8*)(&As[wr + i * 16 + lr][quad << 3]);
#pragma unroll
    for (int j = 0; j < 4; j++) bfr[j] = *(const short8*)(&Bs[wc + j * 16 + lr][quad << 3]);
#pragma unroll
    for (int i = 0; i < 4; i++)
#pragma unroll
      for (int j = 0; j < 4; j++)
        acc[i][j] = __builtin_amdgcn_mfma_f32_16x16x32_bf16(af[i], bfr[j], acc[i][j], 0, 0, 0);
  }
  const float alpha = alphac * (alphap ? alphap[0] : 1.0f);
  const long cb = (long)blockIdx.z * sC;
#pragma unroll
  for (int i = 0; i < 4; i++) {
#pragma unroll
    for (int r = 0; r < 4; r++) {
      long m = m0 + wr + i * 16 + quad * 4 + r;
      float bm = (BIAS_MODE == 2) ? bias[m] : 0.0f;
#pragma unroll
      for (int j = 0; j < 4; j++) {
        long n = n0 + wc + j * 16 + lr;
        float v = alpha * acc[i][j][r];
        if (BIAS_MODE == 1) v += bias[n];
        if (BIAS_MODE == 2) v += bm;
        long off = cb + m * (long)ldc + n;
        if (OUT_MODE == 3) {
          float* Cf = (float*)Cv;
          Cf[off] = v + resid[off];
        } else if (OUT_MODE == 1) {
          float* Cf = (float*)Cv;
          if (BETA_ACC) v += Cf[off];
          Cf[off] = v;
        } else {
          ((u16*)Cv)[off] = f2b(v);
        }
      }
    }
  }
}

// ---------------- small dot-product vectors: h = Wq.bk, u = Wk.bq, beta0 = bk.bq ------
// rows 0..1023 -> hvec[ci] = sum_co Wq[ci][co]*bk[co]
// rows 1024..1791 -> uvec[t] = sum_co Wk[t][co]*bq[co]
// row 1792 -> uvec[768] = sum_co bk[co]*bq[co]
__global__ __launch_bounds__(256)
void smallvecs_kernel(const float* __restrict__ Wq, const float* __restrict__ Wk,
                      const float* __restrict__ bq, const float* __restrict__ bk,
                      float* __restrict__ hvec, float* __restrict__ uvec) {
  const int row = blockIdx.x * 4 + (threadIdx.x >> 6);
  if (row > 1792) return;
  const int lane = threadIdx.x & 63;
  const float* src; const float* vec; float* dst;
  if (row < 1024) { src = Wq + (long)row * 1024; vec = bk; dst = hvec + row; }
  else if (row < 1792) { src = Wk + (long)(row - 1024) * 1024; vec = bq; dst = uvec + (row - 1024); }
  else { src = bk; vec = bq; dst = uvec + 768; }
  float s = 0.f;
#pragma unroll
  for (int h = 0; h < 4; h++) {
    float4 a = *(const float4*)(src + h * 256 + lane * 4);
    float4 b = *(const float4*)(vec + h * 256 + lane * 4);
    s += a.x * b.x + a.y * b.y + a.z * b.z + a.w * b.w;
  }
#pragma unroll
  for (int o = 32; o > 0; o >>= 1) s += __shfl_xor(s, o);
  if (lane == 0) *dst = s;
}

// ---------------- bkq[b,l] = 0.03125 * (tt16[b,l,:].uvec + beta0) --------------------
__global__ __launch_bounds__(256)
void bkq_kernel(const u16* __restrict__ tt, const float* __restrict__ uvec,
                float* __restrict__ bkq) {
  const long row = (long)blockIdx.x * 4 + (threadIdx.x >> 6);  // [0, 8192)
  const int lane = threadIdx.x & 63;
  const u16* tr = tt + row * 768;
  float s = 0.f;
#pragma unroll
  for (int h = 0; h < 3; h++) {
    uint2 kv = *(const uint2*)(tr + h * 256 + lane * 4);
    const u16* ku = (const u16*)&kv;
    float4 b = *(const float4*)(uvec + h * 256 + lane * 4);
    s += b2f(ku[0]) * b.x + b2f(ku[1]) * b.y + b2f(ku[2]) * b.z + b2f(ku[3]) * b.w;
  }
#pragma unroll
  for (int o = 32; o > 0; o >>= 1) s += __shfl_xor(s, o);
  if (lane == 0) bkq[row] = 0.03125f * (s + uvec[768]);
}

// ---------------- fused: hpool3+hpool5 (one S1 read) + scale-1 softmax -> P[:,0:512] --
// One wave per row. hs3/hs5 get raw horizontal sums (normalized later in vp35).
__global__ __launch_bounds__(256)
void hpool35sm(const float* __restrict__ S1, const float* __restrict__ bkq,
               float* __restrict__ hs3, float* __restrict__ hs5,
               u16* __restrict__ P, const float* __restrict__ wts) {
  const int row = blockIdx.x * 4 + (threadIdx.x >> 6);  // [0, 4608)
  const int lane = threadIdx.x & 63;
  const int bloc = row / 2304;
  const int nn = row - bloc * 2304;
  const int x = nn % 48;
  float4 c0 = {0.f, 0.f, 0.f, 0.f}, c1 = {0.f, 0.f, 0.f, 0.f};
  float4 s3a = {0.f, 0.f, 0.f, 0.f}, s3b = {0.f, 0.f, 0.f, 0.f};
  float4 s5a = {0.f, 0.f, 0.f, 0.f}, s5b = {0.f, 0.f, 0.f, 0.f};
#pragma unroll
  for (int dx = -2; dx <= 2; dx++) {
    int xx = x + dx;
    if (xx < 0 || xx >= 48) continue;
    const float* r = S1 + (long)(row + dx) * 512;
    float4 v0 = *(const float4*)(r + lane * 4);
    float4 v1 = *(const float4*)(r + 256 + lane * 4);
    s5a.x += v0.x; s5a.y += v0.y; s5a.z += v0.z; s5a.w += v0.w;
    s5b.x += v1.x; s5b.y += v1.y; s5b.z += v1.z; s5b.w += v1.w;
    if (dx >= -1 && dx <= 1) {
      s3a.x += v0.x; s3a.y += v0.y; s3a.z += v0.z; s3a.w += v0.w;
      s3b.x += v1.x; s3b.y += v1.y; s3b.z += v1.z; s3b.w += v1.w;
    }
    if (dx == 0) { c0 = v0; c1 = v1; }
  }
  float* h3 = hs3 + (long)row * 512;
  float* h5 = hs5 + (long)row * 512;
  *(float4*)(h3 + lane * 4) = s3a; *(float4*)(h3 + 256 + lane * 4) = s3b;
  *(float4*)(h5 + lane * 4) = s5a; *(float4*)(h5 + 256 + lane * 4) = s5b;
  // scale-1 softmax on center row + bkq
  const float* bk = bkq + (long)bloc * 512;
  float4 q0 = *(const float4*)(bk + lane * 4);
  float4 q1v = *(const float4*)(bk + 256 + lane * 4);
  c0.x += q0.x;  c0.y += q0.y;  c0.z += q0.z;  c0.w += q0.w;
  c1.x += q1v.x; c1.y += q1v.y; c1.z += q1v.z; c1.w += q1v.w;
  float m = fmaxf(fmaxf(fmaxf(c0.x, c0.y), fmaxf(c0.z, c0.w)),
                  fmaxf(fmaxf(c1.x, c1.y), fmaxf(c1.z, c1.w)));
#pragma unroll
  for (int o = 32; o > 0; o >>= 1) m = fmaxf(m, __shfl_xor(m, o));
  float e0 = __expf(c0.x - m), e1 = __expf(c0.y - m), e2 = __expf(c0.z - m), e3 = __expf(c0.w - m);
  float e4 = __expf(c1.x - m), e5 = __expf(c1.y - m), e6 = __expf(c1.z - m), e7 = __expf(c1.w - m);
  float s = ((e0 + e1) + (e2 + e3)) + ((e4 + e5) + (e6 + e7));
#pragma unroll
  for (int o = 32; o > 0; o >>= 1) s += __shfl_xor(s, o);
  const float inv = wts[0] / s;
  union { u16 u[4]; uint2 v; } pk;
  u16* pr = P + (long)row * 1536;
  pk.u[0] = f2b(e0 * inv); pk.u[1] = f2b(e1 * inv); pk.u[2] = f2b(e2 * inv); pk.u[3] = f2b(e3 * inv);
  *(uint2*)(pr + lane * 4) = pk.v;
  pk.u[0] = f2b(e4 * inv); pk.u[1] = f2b(e5 * inv); pk.u[2] = f2b(e6 * inv); pk.u[3] = f2b(e7 * inv);
  *(uint2*)(pr + 256 + lane * 4) = pk.v;
}

// ---------------- vertical pool + bkq + softmax + *w for scales 3 & 5 (grid.y) -------
__global__ __launch_bounds__(256)
void vp35(const float* __restrict__ hs3, const float* __restrict__ hs5,
          const float* __restrict__ bkq, u16* __restrict__ P,
          const float* __restrict__ wts) {
  const int sc = blockIdx.y;  // 0 -> kp=3, 1 -> kp=5
  const float* src = sc ? hs5 : hs3;
  const int dmax = sc ? 2 : 1;
  const float ik = sc ? (1.0f / 25.0f) : (1.0f / 9.0f);
  const int colOff = sc ? 1024 : 512;
  const int widx = sc ? 2 : 1;
  const int row = blockIdx.x * 4 + (threadIdx.x >> 6);  // [0, 4608)
  const int lane = threadIdx.x & 63;
  const int bloc = row / 2304;
  const int nn = row - bloc * 2304;
  const int y = nn / 48;
  float4 a0 = {0.f, 0.f, 0.f, 0.f}, a1 = {0.f, 0.f, 0.f, 0.f};
#pragma unroll
  for (int dy = -2; dy <= 2; dy++) {
    if (dy < -dmax || dy > dmax) continue;
    int yy = y + dy;
    if (yy < 0 || yy >= 48) continue;
    const float* r = src + (long)(row + dy * 48) * 512;
    float4 v0 = *(const float4*)(r + lane * 4);
    float4 v1 = *(const float4*)(r + 256 + lane * 4);
    a0.x += v0.x; a0.y += v0.y; a0.z += v0.z; a0.w += v0.w;
    a1.x += v1.x; a1.y += v1.y; a1.z += v1.z; a1.w += v1.w;
  }
  const float* bk = bkq + (long)bloc * 512;
  float4 q0 = *(const float4*)(bk + lane * 4);
  float4 q1v = *(const float4*)(bk + 256 + lane * 4);
  a0.x = a0.x * ik + q0.x;  a0.y = a0.y * ik + q0.y;
  a0.z = a0.z * ik + q0.z;  a0.w = a0.w * ik + q0.w;
  a1.x = a1.x * ik + q1v.x; a1.y = a1.y * ik + q1v.y;
  a1.z = a1.z * ik + q1v.z; a1.w = a1.w * ik + q1v.w;
  float m = fmaxf(fmaxf(fmaxf(a0.x, a0.y), fmaxf(a0.z, a0.w)),
                  fmaxf(fmaxf(a1.x, a1.y), fmaxf(a1.z, a1.w)));
#pragma unroll
  for (int o = 32; o > 0; o >>= 1) m = fmaxf(m, __shfl_xor(m, o));
  float e0 = __expf(a0.x - m), e1 = __expf(a0.y - m), e2 = __expf(a0.z - m), e3 = __expf(a0.w - m);
  float e4 = __expf(a1.x - m), e5 = __expf(a1.y - m), e6 = __expf(a1.z - m), e7 = __expf(a1.w - m);
  float s = ((e0 + e1) + (e2 + e3)) + ((e4 + e5) + (e6 + e7));
#pragma unroll
  for (int o = 32; o > 0; o >>= 1) s += __shfl_xor(s, o);
  const float inv = wts[widx] / s;
  union { u16 u[4]; uint2 v; } pk;
  u16* pr = P + (long)row * 1536 + colOff;
  pk.u[0] = f2b(e0 * inv); pk.u[1] = f2b(e1 * inv); pk.u[2] = f2b(e2 * inv); pk.u[3] = f2b(e3 * inv);
  *(uint2*)(pr + lane * 4) = pk.v;
  pk.u[0] = f2b(e4 * inv); pk.u[1] = f2b(e5 * inv); pk.u[2] = f2b(e6 * inv); pk.u[3] = f2b(e7 * inv);
  *(uint2*)(pr + 256 + lane * 4) = pk.v;
}

extern "C" void kernel_launch(void* const* d_in, const int* in_sizes, int n_in,
                              void* d_out, int out_size, void* d_ws, size_t ws_size,
                              hipStream_t stream) {
  const float* v_feat = (const float*)d_in[0];
  const float* t_tok  = (const float*)d_in[1];
  const float* Wq  = (const float*)d_in[2];
  const float* bq  = (const float*)d_in[3];
  const float* Wk  = (const float*)d_in[4];
  const float* bk  = (const float*)d_in[5];
  const float* Wv  = (const float*)d_in[6];
  const float* bv  = (const float*)d_in[7];
  const float* lam = (const float*)d_in[8];

  // Workspace layout (82.9 MB total; NB=2 batch chunks):
  //  S = (vflat@Wq)@ktxt^T folded to vflat@WkqT^T with
  //  WkqT = tt16 @ GT^T + h, GT = Wq16 @ Wk16^T  (ktxt never materialized).
  char* const wsb = (char*)d_ws;
  float* wts  = (float*)(wsb);                  // 256 B
  u16* Wq16   = (u16*)(wsb + 256);              // 2 MB
  u16* Wk16   = (u16*)(wsb + 2097408);          // 1.5 MB
  u16* WvT    = (u16*)(wsb + 3670272);          // 1.5 MB
  u16* GT     = (u16*)(wsb + 5243136);          // (1024, 768) bf16, 1.5 MB
  float* hvec = (float*)(wsb + 6816000);        // 4 KB
  float* uvec = (float*)(wsb + 6820096);        // 769 floats (+pad)
  float* bkq  = (float*)(wsb + 6824192);        // (B, L) fp32, 32 KB
  u16* WkqT   = (u16*)(wsb + 6856960);          // (B*L, C) bf16, 16.8 MB
  u16* vtxtT  = (u16*)(wsb + 23634176);         // (B, C, L) bf16, 16.8 MB
  char* const chunk = wsb + 40411392;
  u16* tt16   = (u16*)chunk;                    // (B*L, Ct) bf16, 12.6 MB (pre-loop only)
  u16* vflat  = (u16*)chunk;                    // (NB*N, C) bf16
  float* S1   = (float*)(chunk + 9437184);      // (NB*N, L) fp32
  float* hs5  = (float*)(chunk + 18874368);     // (NB*N, L) fp32
  u16* Pc     = (u16*)(chunk + 28311552);       // (NB*N, 3*L) bf16, 14.2 MB
  float* hs3  = (float*)chunk;                  // aliases vflat (dead after S-GEMM)
  // end: chunk + 42467328 = 82,878,720

  float* out0 = (float*)d_out;
  const long CN = 1024L * 2304;

  softmax3_kernel<<<1, 64, 0, stream>>>(lam, wts);

  cast_f32_bf16<<<512, 256, 0, stream>>>(Wq, Wq16);       // 1048576 elems
  cast_f32_bf16<<<384, 256, 0, stream>>>(Wk, Wk16);       // 786432 elems
  transpose_f32<<<dim3(12, 16, 1), 256, 0, stream>>>(Wv, WvT, 768, 1024, 0, 0);
  cast_f32_bf16<<<3072, 256, 0, stream>>>(t_tok, tt16);   // 6291456 elems
  smallvecs_kernel<<<449, 256, 0, stream>>>(Wq, Wk, bq, bk, hvec, uvec);

  // GT(ci,t) = sum_co Wq(ci,co) * Wk(t,co)   : (1024, 768), K=1024
  gemm_nt<0, 0, false, 0><<<dim3(8, 6, 1), 256, 0, stream>>>(
      Wq16, 0, 1024, Wk16, 0, 1024, GT, 0, 768, nullptr, nullptr, nullptr, 1.0f, 1024);
  // WkqT(l,ci) = sum_t tt16(l,t) * GT(ci,t) + h(ci)  : (8192, 1024), K=768
  gemm_nt<1, 0, false, 0><<<dim3(64, 8, 1), 256, 0, stream>>>(
      tt16, 0, 768, GT, 0, 768, WkqT, 0, 1024, hvec, nullptr, nullptr, 1.0f, 768);
  // v_txtT(b) = Wv^T @ t_tok(b)^T + bv (per-m) : (1024,512) per batch, K=768
  gemm_nt<2, 0, false, 0><<<dim3(8, 4, 16), 256, 0, stream>>>(
      WvT, 0, 768, tt16, 512L * 768, 768, vtxtT, 1024L * 512, 512, bv, nullptr, nullptr, 1.0f, 768);
  // bkq[b,l] = scale * (tt16[b,l,:].u + beta0)  (rank-1 softmax-logit correction for
  // the bias that must be excluded from pooling: pool_k(const) != const at borders)
  bkq_kernel<<<2048, 256, 0, stream>>>(tt16, uvec, bkq);

  for (int ch = 0; ch < 8; ch++) {
    const long bb = 2L * ch;
    const float* vf_ch = v_feat + bb * CN;
    // vflat = transpose(v_feat chunk) as bf16: (NB*N, C)
    transpose_f32<<<dim3(16, 36, 2), 256, 0, stream>>>(
        vf_ch, vflat, 1024, 2304, CN, 2304L * 1024);
    // S1 = (vflat @ WkqT_b^T) / 32  (fp32, per batch) — q-GEMM folded away
    gemm_nt<0, 1, false, 0><<<dim3(18, 4, 2), 256, 0, stream>>>(
        vflat, 2304L * 1024, 1024, WkqT + bb * (512L * 1024), 512L * 1024, 1024,
        S1, 2304L * 512, 512, nullptr, nullptr, nullptr, 0.03125f, 1024);
    // fused: hs3/hs5 horizontal sums (single S1 read) + scale-1 softmax -> P[:,0:512]
    hpool35sm<<<1152, 256, 0, stream>>>(S1, bkq + bb * 512, hs3, hs5, Pc, wts);
    // scales 3 & 5: vertical pool + bkq + softmax + weight -> P slices (one launch)
    vp35<<<dim3(1152, 2), 256, 0, stream>>>(hs3, hs5, bkq + bb * 512, Pc, wts);
    // out^T directly: out(c,n) = sum_l vtxtT(c,l-wrapped) * P(n,l) + v_feat(c,n)
    // (A k-index wrapped & 511 -> [V;V;V]; scale weights folded into P; coalesced
    //  fp32 stores along n)
    gemm_nt<0, 3, false, 511><<<dim3(8, 18, 2), 256, 0, stream>>>(
        vtxtT + bb * (1024L * 512), 1024L * 512, 512, Pc, 2304L * 1536, 1536,
        out0 + bb * CN, CN, 2304, nullptr, vf_ch, nullptr, 1.0f, 1536);
  }

  // out1 = t_tok (raw fp32 copy)
  hipMemcpyAsync((void*)(out0 + 37748736L), (const void*)t_tok, 25165824L,
                 hipMemcpyDeviceToDevice, stream);
}

// Round 4
// 1087.771 us; speedup vs baseline: 2.4561x; 1.0778x over previous
//
#include <hip/hip_runtime.h>

typedef unsigned short u16;
typedef short short8 __attribute__((ext_vector_type(8)));
typedef float floatx4 __attribute__((ext_vector_type(4)));

__device__ __forceinline__ float b2f(u16 h) {
  union { unsigned int u; float f; } z;
  z.u = ((unsigned int)h) << 16;
  return z.f;
}
__device__ __forceinline__ u16 f2b(float f) {
  union { float f; unsigned int u; } z;
  z.f = f;
  unsigned int u = z.u;
  unsigned int r = (u + 0x7fffu + ((u >> 16) & 1u)) >> 16;
  return (u16)r;
}

// ---------------- softmax over the 3 lambda scalars (fp32) -> scale weights ---------
__global__ void softmax3_kernel(const float* __restrict__ lam, float* __restrict__ w) {
  if (threadIdx.x == 0) {
    float a = lam[0], b = lam[1], c = lam[2];
    float m = fmaxf(a, fmaxf(b, c));
    float ea = __expf(a - m), eb = __expf(b - m), ec = __expf(c - m);
    float s = ea + eb + ec;
    w[0] = ea / s; w[1] = eb / s; w[2] = ec / s;
  }
}

// ---------------- cast fp32 -> bf16, 8 elems/thread ---------------------------------
__global__ __launch_bounds__(256)
void cast_f32_bf16(const float* __restrict__ src, u16* __restrict__ dst) {
  const long i = ((long)blockIdx.x * 256 + threadIdx.x) * 8;
  float4 v0 = *(const float4*)(src + i);
  float4 v1 = *(const float4*)(src + i + 4);
  u16 r[8] __attribute__((aligned(16)));
  r[0] = f2b(v0.x); r[1] = f2b(v0.y); r[2] = f2b(v0.z); r[3] = f2b(v0.w);
  r[4] = f2b(v1.x); r[5] = f2b(v1.y); r[6] = f2b(v1.z); r[7] = f2b(v1.w);
  *(uint4*)(dst + i) = *(const uint4*)r;
}

// ---------------- transpose fp32 src (b,R,Cc) -> bf16 dst (b,Cc,R) ------------------
__global__ __launch_bounds__(256)
void transpose_f32(const float* __restrict__ src, u16* __restrict__ dst,
                   int R, int Cc, long sSrc, long sDst) {
  __shared__ u16 t[64][66];
  const int tid = threadIdx.x;
  const long r0 = (long)blockIdx.x << 6;
  const long c0 = (long)blockIdx.y << 6;
  const float* s = src + (long)blockIdx.z * sSrc;
  u16* d = dst + (long)blockIdx.z * sDst;
  const int rr = tid >> 2;
  const int cb = (tid & 3) << 2;  // 0,4,8,12
#pragma unroll
  for (int h = 0; h < 4; h++) {
    int cc = cb + h * 16;
    float4 v = *(const float4*)(s + (r0 + rr) * Cc + c0 + cc);
    t[rr][cc + 0] = f2b(v.x); t[rr][cc + 1] = f2b(v.y);
    t[rr][cc + 2] = f2b(v.z); t[rr][cc + 3] = f2b(v.w);
  }
  __syncthreads();
  const int cr = tid >> 2;
  const int nb0 = (tid & 3) << 3;
#pragma unroll
  for (int h = 0; h < 2; h++) {
    int rb = nb0 + h * 32;
    u16 res[8] __attribute__((aligned(16)));
#pragma unroll
    for (int j = 0; j < 8; j++) res[j] = t[rb + j][cr];
    *(uint4*)(d + (c0 + cr) * R + r0 + rb) = *(const uint4*)res;
  }
}

// ---------------- GEMM: C = alpha * A(row-major MxK) * B^T (B is NxK row-major) ------
// BIAS_MODE: 0 none, 1 per-n, 2 per-m (bias fp32).
// OUT_MODE: 0 bf16, 1 fp32, 3 fp32 + residual add (out[m][n] = acc + resid[m][n]).
// AMASK: if nonzero, A's k index is wrapped (k & AMASK) -> implicit K-repeat of A.
template <int BIAS_MODE, int OUT_MODE, bool BETA_ACC, int AMASK>
__global__ __launch_bounds__(256)
void gemm_nt(const u16* __restrict__ A, long sA, int lda,
             const u16* __restrict__ Bm, long sB, int ldb,
             void* __restrict__ Cv, long sC, int ldc,
             const float* __restrict__ bias, const float* __restrict__ resid,
             const float* __restrict__ alphap, float alphac, int K) {
  __shared__ __align__(16) u16 As[128][40];
  __shared__ __align__(16) u16 Bs[128][40];
  const int tid = threadIdx.x;
  const long m0 = (long)blockIdx.x * 128;
  const long n0 = (long)blockIdx.y * 128;
  const u16* Ab = A + (long)blockIdx.z * sA + m0 * lda;
  const u16* Bb = Bm + (long)blockIdx.z * sB + n0 * ldb;
  const int sm = tid >> 2;
  const int sk = (tid & 3) << 3;
  const int wave = tid >> 6;
  const int lane = tid & 63;
  const int wr = (wave >> 1) << 6;
  const int wc = (wave & 1) << 6;
  const int quad = lane >> 4;
  const int lr = lane & 15;
  floatx4 acc[4][4] = {};
  for (int k0 = 0; k0 < K; k0 += 32) {
    const int ka = AMASK ? (k0 & AMASK) : k0;
    uint4 a0 = *(const uint4*)(Ab + (long)sm * lda + ka + sk);
    uint4 a1 = *(const uint4*)(Ab + (long)(sm + 64) * lda + ka + sk);
    uint4 b0 = *(const uint4*)(Bb + (long)sm * ldb + k0 + sk);
    uint4 b1 = *(const uint4*)(Bb + (long)(sm + 64) * ldb + k0 + sk);
    __syncthreads();
    *(uint4*)(&As[sm][sk]) = a0;
    *(uint4*)(&As[sm + 64][sk]) = a1;
    *(uint4*)(&Bs[sm][sk]) = b0;
    *(uint4*)(&Bs[sm + 64][sk]) = b1;
    __syncthreads();
    short8 af[4], bfr[4];
#pragma unroll
    for (int i = 0; i < 4; i++) af[i] = *(const short8*)(&As[wr + i * 16 + lr][quad << 3]);
#pragma unroll
    for (int j = 0; j < 4; j++) bfr[j] = *(const short8*)(&Bs[wc + j * 16 + lr][quad << 3]);
#pragma unroll
    for (int i = 0; i < 4; i++)
#pragma unroll
      for (int j = 0; j < 4; j++)
        acc[i][j] = __builtin_amdgcn_mfma_f32_16x16x32_bf16(af[i], bfr[j], acc[i][j], 0, 0, 0);
  }
  const float alpha = alphac * (alphap ? alphap[0] : 1.0f);
  const long cb = (long)blockIdx.z * sC;
#pragma unroll
  for (int i = 0; i < 4; i++) {
#pragma unroll
    for (int r = 0; r < 4; r++) {
      long m = m0 + wr + i * 16 + quad * 4 + r;
      float bm = (BIAS_MODE == 2) ? bias[m] : 0.0f;
#pragma unroll
      for (int j = 0; j < 4; j++) {
        long n = n0 + wc + j * 16 + lr;
        float v = alpha * acc[i][j][r];
        if (BIAS_MODE == 1) v += bias[n];
        if (BIAS_MODE == 2) v += bm;
        long off = cb + m * (long)ldc + n;
        if (OUT_MODE == 3) {
          float* Cf = (float*)Cv;
          Cf[off] = v + resid[off];
        } else if (OUT_MODE == 1) {
          float* Cf = (float*)Cv;
          if (BETA_ACC) v += Cf[off];
          Cf[off] = v;
        } else {
          ((u16*)Cv)[off] = f2b(v);
        }
      }
    }
  }
}

// ---------------- split-K2 GEMM for S: fp32 out = alpha * A @ B^T, K halved across ---
// 512 threads / 8 waves: waves 0-3 (h=0) do k<K/2, waves 4-7 (h=1) do k>=K/2 into
// separate accumulators + separate LDS staging; combined via 2-pass LDS scratch.
// Halves the serial K-loop latency (the S-GEMM grid is only 144 blocks -> latency-bound).
__global__ __launch_bounds__(512)
void gemm_s_sk2(const u16* __restrict__ A, long sA, int lda,
                const u16* __restrict__ Bm, long sB, int ldb,
                float* __restrict__ C, long sC, int ldc,
                float alpha, int K) {
  __shared__ __align__(16) char smem[40960];
  typedef u16 lds_t[128][40];
  lds_t* As = (lds_t*)smem;             // [2][128][40], 20480 B
  lds_t* Bs = (lds_t*)(smem + 20480);   // [2][128][40], 20480 B
  float* scr = (float*)smem;            // epilogue scratch (32 KB), aliases As/Bs
  const int tid = threadIdx.x;
  const int h = tid >> 8;               // k-half
  const int t8 = tid & 255;
  const long m0 = (long)blockIdx.x * 128;
  const long n0 = (long)blockIdx.y * 128;
  const int Kh = K >> 1;
  const u16* Ab = A + (long)blockIdx.z * sA + m0 * lda + (long)h * Kh;
  const u16* Bb = Bm + (long)blockIdx.z * sB + n0 * ldb + (long)h * Kh;
  const int sm = t8 >> 2;
  const int sk = (t8 & 3) << 3;
  const int wave = tid >> 6;            // 0..7
  const int q = wave & 3;               // output quadrant (shared between halves)
  const int lane = tid & 63;
  const int wr = (q >> 1) << 6;
  const int wc = (q & 1) << 6;
  const int quad = lane >> 4;
  const int lr = lane & 15;
  floatx4 acc[4][4] = {};
  for (int k0 = 0; k0 < Kh; k0 += 32) {
    uint4 a0 = *(const uint4*)(Ab + (long)sm * lda + k0 + sk);
    uint4 a1 = *(const uint4*)(Ab + (long)(sm + 64) * lda + k0 + sk);
    uint4 b0 = *(const uint4*)(Bb + (long)sm * ldb + k0 + sk);
    uint4 b1 = *(const uint4*)(Bb + (long)(sm + 64) * ldb + k0 + sk);
    __syncthreads();
    *(uint4*)(&As[h][sm][sk]) = a0;
    *(uint4*)(&As[h][sm + 64][sk]) = a1;
    *(uint4*)(&Bs[h][sm][sk]) = b0;
    *(uint4*)(&Bs[h][sm + 64][sk]) = b1;
    __syncthreads();
    short8 af[4], bfr[4];
#pragma unroll
    for (int i = 0; i < 4; i++) af[i] = *(const short8*)(&As[h][wr + i * 16 + lr][quad << 3]);
#pragma unroll
    for (int j = 0; j < 4; j++) bfr[j] = *(const short8*)(&Bs[h][wc + j * 16 + lr][quad << 3]);
#pragma unroll
    for (int i = 0; i < 4; i++)
#pragma unroll
      for (int j = 0; j < 4; j++)
        acc[i][j] = __builtin_amdgcn_mfma_f32_16x16x32_bf16(af[i], bfr[j], acc[i][j], 0, 0, 0);
  }
  // combine halves: 2 passes x 2 quadrants through 32 KB scratch.
  // idx: (q&1)*4096 + n_local*64 + (m4 ^ ((lr&7)<<2))  -- XOR kills the stride-64
  // same-bank collision (lanes sharing quad); write/read use identical formula.
  __syncthreads();
#pragma unroll
  for (int pass = 0; pass < 2; pass++) {
    if (h == 1 && (q >> 1) == pass) {
#pragma unroll
      for (int i = 0; i < 4; i++)
#pragma unroll
        for (int j = 0; j < 4; j++)
          *(floatx4*)&scr[(q & 1) * 4096 + (j * 16 + lr) * 64 +
                          (((i * 16 + quad * 4)) ^ ((lr & 7) << 2))] = acc[i][j];
    }
    __syncthreads();
    if (h == 0 && (q >> 1) == pass) {
#pragma unroll
      for (int i = 0; i < 4; i++)
#pragma unroll
        for (int j = 0; j < 4; j++)
          acc[i][j] += *(const floatx4*)&scr[(q & 1) * 4096 + (j * 16 + lr) * 64 +
                                             (((i * 16 + quad * 4)) ^ ((lr & 7) << 2))];
    }
    __syncthreads();
  }
  if (h == 0) {
    const long cb = (long)blockIdx.z * sC;
#pragma unroll
    for (int i = 0; i < 4; i++) {
#pragma unroll
      for (int r = 0; r < 4; r++) {
        long m = m0 + wr + i * 16 + quad * 4 + r;
#pragma unroll
        for (int j = 0; j < 4; j++) {
          long n = n0 + wc + j * 16 + lr;
          C[cb + m * (long)ldc + n] = alpha * acc[i][j][r];
        }
      }
    }
  }
}

// ---------------- small dot-product vectors: h = Wq.bk, u = Wk.bq, beta0 = bk.bq ------
__global__ __launch_bounds__(256)
void smallvecs_kernel(const float* __restrict__ Wq, const float* __restrict__ Wk,
                      const float* __restrict__ bq, const float* __restrict__ bk,
                      float* __restrict__ hvec, float* __restrict__ uvec) {
  const int row = blockIdx.x * 4 + (threadIdx.x >> 6);
  if (row > 1792) return;
  const int lane = threadIdx.x & 63;
  const float* src; const float* vec; float* dst;
  if (row < 1024) { src = Wq + (long)row * 1024; vec = bk; dst = hvec + row; }
  else if (row < 1792) { src = Wk + (long)(row - 1024) * 1024; vec = bq; dst = uvec + (row - 1024); }
  else { src = bk; vec = bq; dst = uvec + 768; }
  float s = 0.f;
#pragma unroll
  for (int h = 0; h < 4; h++) {
    float4 a = *(const float4*)(src + h * 256 + lane * 4);
    float4 b = *(const float4*)(vec + h * 256 + lane * 4);
    s += a.x * b.x + a.y * b.y + a.z * b.z + a.w * b.w;
  }
#pragma unroll
  for (int o = 32; o > 0; o >>= 1) s += __shfl_xor(s, o);
  if (lane == 0) *dst = s;
}

// ---------------- bkq[b,l] = 0.03125 * (tt16[b,l,:].uvec + beta0) --------------------
__global__ __launch_bounds__(256)
void bkq_kernel(const u16* __restrict__ tt, const float* __restrict__ uvec,
                float* __restrict__ bkq) {
  const long row = (long)blockIdx.x * 4 + (threadIdx.x >> 6);  // [0, 8192)
  const int lane = threadIdx.x & 63;
  const u16* tr = tt + row * 768;
  float s = 0.f;
#pragma unroll
  for (int h = 0; h < 3; h++) {
    uint2 kv = *(const uint2*)(tr + h * 256 + lane * 4);
    const u16* ku = (const u16*)&kv;
    float4 b = *(const float4*)(uvec + h * 256 + lane * 4);
    s += b2f(ku[0]) * b.x + b2f(ku[1]) * b.y + b2f(ku[2]) * b.z + b2f(ku[3]) * b.w;
  }
#pragma unroll
  for (int o = 32; o > 0; o >>= 1) s += __shfl_xor(s, o);
  if (lane == 0) bkq[row] = 0.03125f * (s + uvec[768]);
}

// ---------------- fused: hpool3+hpool5 (one S1 read) + scale-1 softmax -> P[:,0:512] --
__global__ __launch_bounds__(256)
void hpool35sm(const float* __restrict__ S1, const float* __restrict__ bkq,
               float* __restrict__ hs3, float* __restrict__ hs5,
               u16* __restrict__ P, const float* __restrict__ wts) {
  const int row = blockIdx.x * 4 + (threadIdx.x >> 6);  // [0, 4608)
  const int lane = threadIdx.x & 63;
  const int bloc = row / 2304;
  const int nn = row - bloc * 2304;
  const int x = nn % 48;
  float4 c0 = {0.f, 0.f, 0.f, 0.f}, c1 = {0.f, 0.f, 0.f, 0.f};
  float4 s3a = {0.f, 0.f, 0.f, 0.f}, s3b = {0.f, 0.f, 0.f, 0.f};
  float4 s5a = {0.f, 0.f, 0.f, 0.f}, s5b = {0.f, 0.f, 0.f, 0.f};
#pragma unroll
  for (int dx = -2; dx <= 2; dx++) {
    int xx = x + dx;
    if (xx < 0 || xx >= 48) continue;
    const float* r = S1 + (long)(row + dx) * 512;
    float4 v0 = *(const float4*)(r + lane * 4);
    float4 v1 = *(const float4*)(r + 256 + lane * 4);
    s5a.x += v0.x; s5a.y += v0.y; s5a.z += v0.z; s5a.w += v0.w;
    s5b.x += v1.x; s5b.y += v1.y; s5b.z += v1.z; s5b.w += v1.w;
    if (dx >= -1 && dx <= 1) {
      s3a.x += v0.x; s3a.y += v0.y; s3a.z += v0.z; s3a.w += v0.w;
      s3b.x += v1.x; s3b.y += v1.y; s3b.z += v1.z; s3b.w += v1.w;
    }
    if (dx == 0) { c0 = v0; c1 = v1; }
  }
  float* h3 = hs3 + (long)row * 512;
  float* h5 = hs5 + (long)row * 512;
  *(float4*)(h3 + lane * 4) = s3a; *(float4*)(h3 + 256 + lane * 4) = s3b;
  *(float4*)(h5 + lane * 4) = s5a; *(float4*)(h5 + 256 + lane * 4) = s5b;
  // scale-1 softmax on center row + bkq
  const float* bk = bkq + (long)bloc * 512;
  float4 q0 = *(const float4*)(bk + lane * 4);
  float4 q1v = *(const float4*)(bk + 256 + lane * 4);
  c0.x += q0.x;  c0.y += q0.y;  c0.z += q0.z;  c0.w += q0.w;
  c1.x += q1v.x; c1.y += q1v.y; c1.z += q1v.z; c1.w += q1v.w;
  float m = fmaxf(fmaxf(fmaxf(c0.x, c0.y), fmaxf(c0.z, c0.w)),
                  fmaxf(fmaxf(c1.x, c1.y), fmaxf(c1.z, c1.w)));
#pragma unroll
  for (int o = 32; o > 0; o >>= 1) m = fmaxf(m, __shfl_xor(m, o));
  float e0 = __expf(c0.x - m), e1 = __expf(c0.y - m), e2 = __expf(c0.z - m), e3 = __expf(c0.w - m);
  float e4 = __expf(c1.x - m), e5 = __expf(c1.y - m), e6 = __expf(c1.z - m), e7 = __expf(c1.w - m);
  float s = ((e0 + e1) + (e2 + e3)) + ((e4 + e5) + (e6 + e7));
#pragma unroll
  for (int o = 32; o > 0; o >>= 1) s += __shfl_xor(s, o);
  const float inv = wts[0] / s;
  union { u16 u[4]; uint2 v; } pk;
  u16* pr = P + (long)row * 1536;
  pk.u[0] = f2b(e0 * inv); pk.u[1] = f2b(e1 * inv); pk.u[2] = f2b(e2 * inv); pk.u[3] = f2b(e3 * inv);
  *(uint2*)(pr + lane * 4) = pk.v;
  pk.u[0] = f2b(e4 * inv); pk.u[1] = f2b(e5 * inv); pk.u[2] = f2b(e6 * inv); pk.u[3] = f2b(e7 * inv);
  *(uint2*)(pr + 256 + lane * 4) = pk.v;
}

// ---------------- vertical pool + bkq + softmax + *w for scales 3 & 5 (grid.y) -------
__global__ __launch_bounds__(256)
void vp35(const float* __restrict__ hs3, const float* __restrict__ hs5,
          const float* __restrict__ bkq, u16* __restrict__ P,
          const float* __restrict__ wts) {
  const int sc = blockIdx.y;  // 0 -> kp=3, 1 -> kp=5
  const float* src = sc ? hs5 : hs3;
  const int dmax = sc ? 2 : 1;
  const float ik = sc ? (1.0f / 25.0f) : (1.0f / 9.0f);
  const int colOff = sc ? 1024 : 512;
  const int widx = sc ? 2 : 1;
  const int row = blockIdx.x * 4 + (threadIdx.x >> 6);  // [0, 4608)
  const int lane = threadIdx.x & 63;
  const int bloc = row / 2304;
  const int nn = row - bloc * 2304;
  const int y = nn / 48;
  float4 a0 = {0.f, 0.f, 0.f, 0.f}, a1 = {0.f, 0.f, 0.f, 0.f};
#pragma unroll
  for (int dy = -2; dy <= 2; dy++) {
    if (dy < -dmax || dy > dmax) continue;
    int yy = y + dy;
    if (yy < 0 || yy >= 48) continue;
    const float* r = src + (long)(row + dy * 48) * 512;
    float4 v0 = *(const float4*)(r + lane * 4);
    float4 v1 = *(const float4*)(r + 256 + lane * 4);
    a0.x += v0.x; a0.y += v0.y; a0.z += v0.z; a0.w += v0.w;
    a1.x += v1.x; a1.y += v1.y; a1.z += v1.z; a1.w += v1.w;
  }
  const float* bk = bkq + (long)bloc * 512;
  float4 q0 = *(const float4*)(bk + lane * 4);
  float4 q1v = *(const float4*)(bk + 256 + lane * 4);
  a0.x = a0.x * ik + q0.x;  a0.y = a0.y * ik + q0.y;
  a0.z = a0.z * ik + q0.z;  a0.w = a0.w * ik + q0.w;
  a1.x = a1.x * ik + q1v.x; a1.y = a1.y * ik + q1v.y;
  a1.z = a1.z * ik + q1v.z; a1.w = a1.w * ik + q1v.w;
  float m = fmaxf(fmaxf(fmaxf(a0.x, a0.y), fmaxf(a0.z, a0.w)),
                  fmaxf(fmaxf(a1.x, a1.y), fmaxf(a1.z, a1.w)));
#pragma unroll
  for (int o = 32; o > 0; o >>= 1) m = fmaxf(m, __shfl_xor(m, o));
  float e0 = __expf(a0.x - m), e1 = __expf(a0.y - m), e2 = __expf(a0.z - m), e3 = __expf(a0.w - m);
  float e4 = __expf(a1.x - m), e5 = __expf(a1.y - m), e6 = __expf(a1.z - m), e7 = __expf(a1.w - m);
  float s = ((e0 + e1) + (e2 + e3)) + ((e4 + e5) + (e6 + e7));
#pragma unroll
  for (int o = 32; o > 0; o >>= 1) s += __shfl_xor(s, o);
  const float inv = wts[widx] / s;
  union { u16 u[4]; uint2 v; } pk;
  u16* pr = P + (long)row * 1536 + colOff;
  pk.u[0] = f2b(e0 * inv); pk.u[1] = f2b(e1 * inv); pk.u[2] = f2b(e2 * inv); pk.u[3] = f2b(e3 * inv);
  *(uint2*)(pr + lane * 4) = pk.v;
  pk.u[0] = f2b(e4 * inv); pk.u[1] = f2b(e5 * inv); pk.u[2] = f2b(e6 * inv); pk.u[3] = f2b(e7 * inv);
  *(uint2*)(pr + 256 + lane * 4) = pk.v;
}

extern "C" void kernel_launch(void* const* d_in, const int* in_sizes, int n_in,
                              void* d_out, int out_size, void* d_ws, size_t ws_size,
                              hipStream_t stream) {
  const float* v_feat = (const float*)d_in[0];
  const float* t_tok  = (const float*)d_in[1];
  const float* Wq  = (const float*)d_in[2];
  const float* bq  = (const float*)d_in[3];
  const float* Wk  = (const float*)d_in[4];
  const float* bk  = (const float*)d_in[5];
  const float* Wv  = (const float*)d_in[6];
  const float* bv  = (const float*)d_in[7];
  const float* lam = (const float*)d_in[8];

  // Workspace layout (92.5 MB total; loop = 4 super-chunks of 4 batches, each
  // processed as 2 halves of 2 batches; PV runs once per super-chunk with z=4):
  //  persistent: wts|Wq16|Wk16|WvT|GT|hvec|uvec|bkq|WkqT|vtxtT = 40.4 MB
  //  chunk: vflat(9.44, aliased by hs3 after S-GEMM) | S1(9.44) | hs5(9.44) | P4(28.3)
  //  tt16 (12.6 MB) aliases the chunk region pre-loop only.
  char* const wsb = (char*)d_ws;
  float* wts  = (float*)(wsb);                  // 256 B
  u16* Wq16   = (u16*)(wsb + 256);              // 2 MB
  u16* Wk16   = (u16*)(wsb + 2097408);          // 1.5 MB
  u16* WvT    = (u16*)(wsb + 3670272);          // 1.5 MB
  u16* GT     = (u16*)(wsb + 5243136);          // (1024, 768) bf16, 1.5 MB
  float* hvec = (float*)(wsb + 6816000);        // 4 KB
  float* uvec = (float*)(wsb + 6820096);        // 769 floats (+pad)
  float* bkq  = (float*)(wsb + 6824192);        // (B, L) fp32, 32 KB
  u16* WkqT   = (u16*)(wsb + 6856960);          // (B*L, C) bf16, 16.8 MB
  u16* vtxtT  = (u16*)(wsb + 23634176);         // (B, C, L) bf16, 16.8 MB
  char* const chunk = wsb + 40411392;
  u16* tt16   = (u16*)chunk;                    // (B*L, Ct) bf16, 12.6 MB (pre-loop only)
  u16* vflat  = (u16*)chunk;                    // (2N, C) bf16, 9.44 MB
  float* hs3  = (float*)chunk;                  // aliases vflat (dead after S-GEMM)
  float* S1   = (float*)(chunk + 9437184);      // (2N, L) fp32, 9.44 MB
  float* hs5  = (float*)(chunk + 18874368);     // (2N, L) fp32, 9.44 MB
  u16* Pc     = (u16*)(chunk + 28311552);       // (4N, 3*L) bf16, 28.3 MB
  // end: 40411392 + 56623104 = 97,034,496 B

  float* out0 = (float*)d_out;
  const long CN = 1024L * 2304;

  softmax3_kernel<<<1, 64, 0, stream>>>(lam, wts);

  cast_f32_bf16<<<512, 256, 0, stream>>>(Wq, Wq16);       // 1048576 elems
  cast_f32_bf16<<<384, 256, 0, stream>>>(Wk, Wk16);       // 786432 elems
  transpose_f32<<<dim3(12, 16, 1), 256, 0, stream>>>(Wv, WvT, 768, 1024, 0, 0);
  cast_f32_bf16<<<3072, 256, 0, stream>>>(t_tok, tt16);   // 6291456 elems
  smallvecs_kernel<<<449, 256, 0, stream>>>(Wq, Wk, bq, bk, hvec, uvec);

  // GT(ci,t) = sum_co Wq(ci,co) * Wk(t,co)   : (1024, 768), K=1024
  gemm_nt<0, 0, false, 0><<<dim3(8, 6, 1), 256, 0, stream>>>(
      Wq16, 0, 1024, Wk16, 0, 1024, GT, 0, 768, nullptr, nullptr, nullptr, 1.0f, 1024);
  // WkqT(l,ci) = sum_t tt16(l,t) * GT(ci,t) + h(ci)  : (8192, 1024), K=768
  gemm_nt<1, 0, false, 0><<<dim3(64, 8, 1), 256, 0, stream>>>(
      tt16, 0, 768, GT, 0, 768, WkqT, 0, 1024, hvec, nullptr, nullptr, 1.0f, 768);
  // v_txtT(b) = Wv^T @ t_tok(b)^T + bv (per-m) : (1024,512) per batch, K=768
  gemm_nt<2, 0, false, 0><<<dim3(8, 4, 16), 256, 0, stream>>>(
      WvT, 0, 768, tt16, 512L * 768, 768, vtxtT, 1024L * 512, 512, bv, nullptr, nullptr, 1.0f, 768);
  // bkq[b,l] = scale * (tt16[b,l,:].u + beta0)  (rank-1 softmax-logit correction for
  // the bias that must be excluded from pooling: pool_k(const) != const at borders)
  bkq_kernel<<<2048, 256, 0, stream>>>(tt16, uvec, bkq);

  for (int sc = 0; sc < 4; sc++) {
    const long b0 = 4L * sc;
    for (int hf = 0; hf < 2; hf++) {
      const long bb = b0 + 2 * hf;
      const float* vf_ch = v_feat + bb * CN;
      u16* Ph = Pc + (long)hf * (2L * 2304 * 1536);
      // vflat = transpose(v_feat 2-batch half) as bf16: (2N, C)
      transpose_f32<<<dim3(16, 36, 2), 256, 0, stream>>>(
          vf_ch, vflat, 1024, 2304, CN, 2304L * 1024);
      // S1 = (vflat @ WkqT_b^T) / 32  (fp32, per batch) — split-K2 halves latency
      gemm_s_sk2<<<dim3(18, 4, 2), 512, 0, stream>>>(
          vflat, 2304L * 1024, 1024, WkqT + bb * (512L * 1024), 512L * 1024, 1024,
          S1, 2304L * 512, 512, 0.03125f, 1024);
      // fused: hs3/hs5 horizontal sums (single S1 read) + scale-1 softmax -> P[:,0:512]
      // (hs3 aliases vflat — dead after the S-GEMM above)
      hpool35sm<<<1152, 256, 0, stream>>>(S1, bkq + bb * 512, hs3, hs5, Ph, wts);
      // scales 3 & 5: vertical pool + bkq + softmax + weight -> P slices (one launch)
      vp35<<<dim3(1152, 2), 256, 0, stream>>>(hs3, hs5, bkq + bb * 512, Ph, wts);
    }
    // out^T for 4 batches in one launch (576 blocks -> better CU utilization):
    // out(c,n) = sum_l vtxtT(c,l-wrapped) * P(n,l) + v_feat(c,n)
    gemm_nt<0, 3, false, 511><<<dim3(8, 18, 4), 256, 0, stream>>>(
        vtxtT + b0 * (1024L * 512), 1024L * 512, 512, Pc, 2304L * 1536, 1536,
        out0 + b0 * CN, CN, 2304, nullptr, v_feat + b0 * CN, nullptr, 1.0f, 1536);
  }

  // out1 = t_tok (raw fp32 copy)
  hipMemcpyAsync((void*)(out0 + 37748736L), (const void*)t_tok, 25165824L,
                 hipMemcpyDeviceToDevice, stream);
}

// Round 5
// 983.539 us; speedup vs baseline: 2.7164x; 1.1060x over previous
//
#include <hip/hip_runtime.h>

typedef unsigned short u16;
typedef short short8 __attribute__((ext_vector_type(8)));
typedef float floatx4 __attribute__((ext_vector_type(4)));

__device__ __forceinline__ float b2f(u16 h) {
  union { unsigned int u; float f; } z;
  z.u = ((unsigned int)h) << 16;
  return z.f;
}
__device__ __forceinline__ u16 f2b(float f) {
  union { float f; unsigned int u; } z;
  z.f = f;
  unsigned int u = z.u;
  unsigned int r = (u + 0x7fffu + ((u >> 16) & 1u)) >> 16;
  return (u16)r;
}

// ---- global_load_lds staging of a 128x64 bf16 tile (16 KB), XOR-swizzled ----------
// LDS slot s (16B) holds global chunk (row = s>>3, c8 = (s&7) ^ (row&7)).
// Dest is linear (HW: wave-uniform base + lane*16B); source address carries the
// swizzle; fragment reads apply the same involution (both-sides-or-neither rule).
__device__ __forceinline__ void stage_tile64(const u16* __restrict__ gsrc, int lda,
                                             u16* lds, int wave, int lane) {
#pragma unroll
  for (int i = 0; i < 4; i++) {
    const int s = wave * 256 + i * 64 + lane;
    const int row = s >> 3;
    const int c8 = (s & 7) ^ (row & 7);
    const u16* g = gsrc + (long)row * lda + (c8 << 3);
    u16* l = lds + (wave * 256 + i * 64) * 8;  // wave-uniform
    __builtin_amdgcn_global_load_lds(
        (const __attribute__((address_space(1))) unsigned int*)g,
        (__attribute__((address_space(3))) unsigned int*)l, 16, 0, 0);
  }
}
// swizzled 16B fragment read: row in [0,128), slot in [0,8)
__device__ __forceinline__ short8 frag64(const u16* lds, int row, int slot) {
  return *(const short8*)(lds + (row << 6) + ((slot ^ (row & 7)) << 3));
}

// ---------------- softmax over the 3 lambda scalars (fp32) -> scale weights ---------
__global__ void softmax3_kernel(const float* __restrict__ lam, float* __restrict__ w) {
  if (threadIdx.x == 0) {
    float a = lam[0], b = lam[1], c = lam[2];
    float m = fmaxf(a, fmaxf(b, c));
    float ea = __expf(a - m), eb = __expf(b - m), ec = __expf(c - m);
    float s = ea + eb + ec;
    w[0] = ea / s; w[1] = eb / s; w[2] = ec / s;
  }
}

// ---------------- cast fp32 -> bf16, 8 elems/thread ---------------------------------
__global__ __launch_bounds__(256)
void cast_f32_bf16(const float* __restrict__ src, u16* __restrict__ dst) {
  const long i = ((long)blockIdx.x * 256 + threadIdx.x) * 8;
  float4 v0 = *(const float4*)(src + i);
  float4 v1 = *(const float4*)(src + i + 4);
  u16 r[8] __attribute__((aligned(16)));
  r[0] = f2b(v0.x); r[1] = f2b(v0.y); r[2] = f2b(v0.z); r[3] = f2b(v0.w);
  r[4] = f2b(v1.x); r[5] = f2b(v1.y); r[6] = f2b(v1.z); r[7] = f2b(v1.w);
  *(uint4*)(dst + i) = *(const uint4*)r;
}

// ---------------- transpose fp32 src (b,R,Cc) -> bf16 dst (b,Cc,R) ------------------
__global__ __launch_bounds__(256)
void transpose_f32(const float* __restrict__ src, u16* __restrict__ dst,
                   int R, int Cc, long sSrc, long sDst) {
  __shared__ u16 t[64][66];
  const int tid = threadIdx.x;
  const long r0 = (long)blockIdx.x << 6;
  const long c0 = (long)blockIdx.y << 6;
  const float* s = src + (long)blockIdx.z * sSrc;
  u16* d = dst + (long)blockIdx.z * sDst;
  const int rr = tid >> 2;
  const int cb = (tid & 3) << 2;  // 0,4,8,12
#pragma unroll
  for (int h = 0; h < 4; h++) {
    int cc = cb + h * 16;
    float4 v = *(const float4*)(s + (r0 + rr) * Cc + c0 + cc);
    t[rr][cc + 0] = f2b(v.x); t[rr][cc + 1] = f2b(v.y);
    t[rr][cc + 2] = f2b(v.z); t[rr][cc + 3] = f2b(v.w);
  }
  __syncthreads();
  const int cr = tid >> 2;
  const int nb0 = (tid & 3) << 3;
#pragma unroll
  for (int h = 0; h < 2; h++) {
    int rb = nb0 + h * 32;
    u16 res[8] __attribute__((aligned(16)));
#pragma unroll
    for (int j = 0; j < 8; j++) res[j] = t[rb + j][cr];
    *(uint4*)(d + (c0 + cr) * R + r0 + rb) = *(const uint4*)res;
  }
}

// ---------------- GEMM: C = alpha * A(row-major MxK) * B^T (B is NxK row-major) ------
// BK=64, global_load_lds staging, XOR-swizzled LDS. K must be a multiple of 64.
// BIAS_MODE: 0 none, 1 per-n, 2 per-m. OUT_MODE: 0 bf16, 1 fp32, 3 fp32+resid.
// AMASK: if nonzero, A's k index is wrapped (k & AMASK) -> implicit K-repeat of A.
template <int BIAS_MODE, int OUT_MODE, bool BETA_ACC, int AMASK>
__global__ __launch_bounds__(256)
void gemm_nt(const u16* __restrict__ A, long sA, int lda,
             const u16* __restrict__ Bm, long sB, int ldb,
             void* __restrict__ Cv, long sC, int ldc,
             const float* __restrict__ bias, const float* __restrict__ resid,
             const float* __restrict__ alphap, float alphac, int K) {
  __shared__ __align__(16) u16 As[8192];
  __shared__ __align__(16) u16 Bs[8192];
  const int tid = threadIdx.x;
  const long m0 = (long)blockIdx.x * 128;
  const long n0 = (long)blockIdx.y * 128;
  const u16* Ab = A + (long)blockIdx.z * sA + m0 * lda;
  const u16* Bb = Bm + (long)blockIdx.z * sB + n0 * ldb;
  const int wave = tid >> 6;
  const int lane = tid & 63;
  const int wr = (wave >> 1) << 6;
  const int wc = (wave & 1) << 6;
  const int quad = lane >> 4;
  const int lr = lane & 15;
  floatx4 acc[4][4] = {};
  for (int k0 = 0; k0 < K; k0 += 64) {
    const int ka = AMASK ? (k0 & AMASK) : k0;
    __syncthreads();
    stage_tile64(Ab + ka, lda, As, wave, lane);
    stage_tile64(Bb + k0, ldb, Bs, wave, lane);
    __syncthreads();
#pragma unroll
    for (int kk = 0; kk < 2; kk++) {
      short8 af[4], bfr[4];
#pragma unroll
      for (int i = 0; i < 4; i++) af[i] = frag64(As, wr + i * 16 + lr, kk * 4 + quad);
#pragma unroll
      for (int j = 0; j < 4; j++) bfr[j] = frag64(Bs, wc + j * 16 + lr, kk * 4 + quad);
#pragma unroll
      for (int i = 0; i < 4; i++)
#pragma unroll
        for (int j = 0; j < 4; j++)
          acc[i][j] = __builtin_amdgcn_mfma_f32_16x16x32_bf16(af[i], bfr[j], acc[i][j], 0, 0, 0);
    }
  }
  const float alpha = alphac * (alphap ? alphap[0] : 1.0f);
  const long cb = (long)blockIdx.z * sC;
#pragma unroll
  for (int i = 0; i < 4; i++) {
#pragma unroll
    for (int r = 0; r < 4; r++) {
      long m = m0 + wr + i * 16 + quad * 4 + r;
      float bm = (BIAS_MODE == 2) ? bias[m] : 0.0f;
#pragma unroll
      for (int j = 0; j < 4; j++) {
        long n = n0 + wc + j * 16 + lr;
        float v = alpha * acc[i][j][r];
        if (BIAS_MODE == 1) v += bias[n];
        if (BIAS_MODE == 2) v += bm;
        long off = cb + m * (long)ldc + n;
        if (OUT_MODE == 3) {
          float* Cf = (float*)Cv;
          Cf[off] = v + resid[off];
        } else if (OUT_MODE == 1) {
          float* Cf = (float*)Cv;
          if (BETA_ACC) v += Cf[off];
          Cf[off] = v;
        } else {
          ((u16*)Cv)[off] = f2b(v);
        }
      }
    }
  }
}

// ---------------- split-K2 GEMM for S (latency-bound 144-block grid) -----------------
// 512 threads / 8 waves; waves 0-3 do k<K/2, waves 4-7 k>=K/2, separate LDS+acc;
// combined via 2-pass 32 KB LDS scratch. BK=64 global_load_lds staging.
__global__ __launch_bounds__(512)
void gemm_s_sk2(const u16* __restrict__ A, long sA, int lda,
                const u16* __restrict__ Bm, long sB, int ldb,
                float* __restrict__ C, long sC, int ldc,
                float alpha, int K) {
  __shared__ __align__(16) u16 smem[32768];  // 64 KB
  float* scr = (float*)smem;                 // epilogue scratch aliases staging
  const int tid = threadIdx.x;
  const int h = tid >> 8;               // k-half
  const long m0 = (long)blockIdx.x * 128;
  const long n0 = (long)blockIdx.y * 128;
  const int Kh = K >> 1;
  const u16* Ab = A + (long)blockIdx.z * sA + m0 * lda + (long)h * Kh;
  const u16* Bb = Bm + (long)blockIdx.z * sB + n0 * ldb + (long)h * Kh;
  u16* AsH = smem + h * 8192;
  u16* BsH = smem + 16384 + h * 8192;
  const int wave = tid >> 6;            // 0..7
  const int w4 = wave & 3;              // wave within half
  const int q = wave & 3;               // output quadrant (shared between halves)
  const int lane = tid & 63;
  const int wr = (q >> 1) << 6;
  const int wc = (q & 1) << 6;
  const int quad = lane >> 4;
  const int lr = lane & 15;
  floatx4 acc[4][4] = {};
  for (int k0 = 0; k0 < Kh; k0 += 64) {
    __syncthreads();
    stage_tile64(Ab + k0, lda, AsH, w4, lane);
    stage_tile64(Bb + k0, ldb, BsH, w4, lane);
    __syncthreads();
#pragma unroll
    for (int kk = 0; kk < 2; kk++) {
      short8 af[4], bfr[4];
#pragma unroll
      for (int i = 0; i < 4; i++) af[i] = frag64(AsH, wr + i * 16 + lr, kk * 4 + quad);
#pragma unroll
      for (int j = 0; j < 4; j++) bfr[j] = frag64(BsH, wc + j * 16 + lr, kk * 4 + quad);
#pragma unroll
      for (int i = 0; i < 4; i++)
#pragma unroll
        for (int j = 0; j < 4; j++)
          acc[i][j] = __builtin_amdgcn_mfma_f32_16x16x32_bf16(af[i], bfr[j], acc[i][j], 0, 0, 0);
    }
  }
  // combine halves: 2 passes x 2 quadrants through 32 KB scratch.
  // idx: (q&1)*4096 + n_local*64 + (m4 ^ ((lr&7)<<2)) — XOR kills the stride-64
  // same-bank collision; write/read use identical formula.
  __syncthreads();
#pragma unroll
  for (int pass = 0; pass < 2; pass++) {
    if (h == 1 && (q >> 1) == pass) {
#pragma unroll
      for (int i = 0; i < 4; i++)
#pragma unroll
        for (int j = 0; j < 4; j++)
          *(floatx4*)&scr[(q & 1) * 4096 + (j * 16 + lr) * 64 +
                          (((i * 16 + quad * 4)) ^ ((lr & 7) << 2))] = acc[i][j];
    }
    __syncthreads();
    if (h == 0 && (q >> 1) == pass) {
#pragma unroll
      for (int i = 0; i < 4; i++)
#pragma unroll
        for (int j = 0; j < 4; j++)
          acc[i][j] += *(const floatx4*)&scr[(q & 1) * 4096 + (j * 16 + lr) * 64 +
                                             (((i * 16 + quad * 4)) ^ ((lr & 7) << 2))];
    }
    __syncthreads();
  }
  if (h == 0) {
    const long cb = (long)blockIdx.z * sC;
#pragma unroll
    for (int i = 0; i < 4; i++) {
#pragma unroll
      for (int r = 0; r < 4; r++) {
        long m = m0 + wr + i * 16 + quad * 4 + r;
#pragma unroll
        for (int j = 0; j < 4; j++) {
          long n = n0 + wc + j * 16 + lr;
          C[cb + m * (long)ldc + n] = alpha * acc[i][j][r];
        }
      }
    }
  }
}

// ---------------- small dot-product vectors: h = Wq.bk, u = Wk.bq, beta0 = bk.bq ------
__global__ __launch_bounds__(256)
void smallvecs_kernel(const float* __restrict__ Wq, const float* __restrict__ Wk,
                      const float* __restrict__ bq, const float* __restrict__ bk,
                      float* __restrict__ hvec, float* __restrict__ uvec) {
  const int row = blockIdx.x * 4 + (threadIdx.x >> 6);
  if (row > 1792) return;
  const int lane = threadIdx.x & 63;
  const float* src; const float* vec; float* dst;
  if (row < 1024) { src = Wq + (long)row * 1024; vec = bk; dst = hvec + row; }
  else if (row < 1792) { src = Wk + (long)(row - 1024) * 1024; vec = bq; dst = uvec + (row - 1024); }
  else { src = bk; vec = bq; dst = uvec + 768; }
  float s = 0.f;
#pragma unroll
  for (int h = 0; h < 4; h++) {
    float4 a = *(const float4*)(src + h * 256 + lane * 4);
    float4 b = *(const float4*)(vec + h * 256 + lane * 4);
    s += a.x * b.x + a.y * b.y + a.z * b.z + a.w * b.w;
  }
#pragma unroll
  for (int o = 32; o > 0; o >>= 1) s += __shfl_xor(s, o);
  if (lane == 0) *dst = s;
}

// ---------------- bkq[b,l] = 0.03125 * (tt16[b,l,:].uvec + beta0) --------------------
__global__ __launch_bounds__(256)
void bkq_kernel(const u16* __restrict__ tt, const float* __restrict__ uvec,
                float* __restrict__ bkq) {
  const long row = (long)blockIdx.x * 4 + (threadIdx.x >> 6);  // [0, 8192)
  const int lane = threadIdx.x & 63;
  const u16* tr = tt + row * 768;
  float s = 0.f;
#pragma unroll
  for (int h = 0; h < 3; h++) {
    uint2 kv = *(const uint2*)(tr + h * 256 + lane * 4);
    const u16* ku = (const u16*)&kv;
    float4 b = *(const float4*)(uvec + h * 256 + lane * 4);
    s += b2f(ku[0]) * b.x + b2f(ku[1]) * b.y + b2f(ku[2]) * b.z + b2f(ku[3]) * b.w;
  }
#pragma unroll
  for (int o = 32; o > 0; o >>= 1) s += __shfl_xor(s, o);
  if (lane == 0) bkq[row] = 0.03125f * (s + uvec[768]);
}

// ---------------- fused: hpool3+hpool5 (one S1 read) + scale-1 softmax -> P[:,0:512] --
__global__ __launch_bounds__(256)
void hpool35sm(const float* __restrict__ S1, const float* __restrict__ bkq,
               float* __restrict__ hs3, float* __restrict__ hs5,
               u16* __restrict__ P, const float* __restrict__ wts) {
  const int row = blockIdx.x * 4 + (threadIdx.x >> 6);  // [0, 4608)
  const int lane = threadIdx.x & 63;
  const int bloc = row / 2304;
  const int nn = row - bloc * 2304;
  const int x = nn % 48;
  float4 c0 = {0.f, 0.f, 0.f, 0.f}, c1 = {0.f, 0.f, 0.f, 0.f};
  float4 s3a = {0.f, 0.f, 0.f, 0.f}, s3b = {0.f, 0.f, 0.f, 0.f};
  float4 s5a = {0.f, 0.f, 0.f, 0.f}, s5b = {0.f, 0.f, 0.f, 0.f};
#pragma unroll
  for (int dx = -2; dx <= 2; dx++) {
    int xx = x + dx;
    if (xx < 0 || xx >= 48) continue;
    const float* r = S1 + (long)(row + dx) * 512;
    float4 v0 = *(const float4*)(r + lane * 4);
    float4 v1 = *(const float4*)(r + 256 + lane * 4);
    s5a.x += v0.x; s5a.y += v0.y; s5a.z += v0.z; s5a.w += v0.w;
    s5b.x += v1.x; s5b.y += v1.y; s5b.z += v1.z; s5b.w += v1.w;
    if (dx >= -1 && dx <= 1) {
      s3a.x += v0.x; s3a.y += v0.y; s3a.z += v0.z; s3a.w += v0.w;
      s3b.x += v1.x; s3b.y += v1.y; s3b.z += v1.z; s3b.w += v1.w;
    }
    if (dx == 0) { c0 = v0; c1 = v1; }
  }
  float* h3 = hs3 + (long)row * 512;
  float* h5 = hs5 + (long)row * 512;
  *(float4*)(h3 + lane * 4) = s3a; *(float4*)(h3 + 256 + lane * 4) = s3b;
  *(float4*)(h5 + lane * 4) = s5a; *(float4*)(h5 + 256 + lane * 4) = s5b;
  // scale-1 softmax on center row + bkq
  const float* bk = bkq + (long)bloc * 512;
  float4 q0 = *(const float4*)(bk + lane * 4);
  float4 q1v = *(const float4*)(bk + 256 + lane * 4);
  c0.x += q0.x;  c0.y += q0.y;  c0.z += q0.z;  c0.w += q0.w;
  c1.x += q1v.x; c1.y += q1v.y; c1.z += q1v.z; c1.w += q1v.w;
  float m = fmaxf(fmaxf(fmaxf(c0.x, c0.y), fmaxf(c0.z, c0.w)),
                  fmaxf(fmaxf(c1.x, c1.y), fmaxf(c1.z, c1.w)));
#pragma unroll
  for (int o = 32; o > 0; o >>= 1) m = fmaxf(m, __shfl_xor(m, o));
  float e0 = __expf(c0.x - m), e1 = __expf(c0.y - m), e2 = __expf(c0.z - m), e3 = __expf(c0.w - m);
  float e4 = __expf(c1.x - m), e5 = __expf(c1.y - m), e6 = __expf(c1.z - m), e7 = __expf(c1.w - m);
  float s = ((e0 + e1) + (e2 + e3)) + ((e4 + e5) + (e6 + e7));
#pragma unroll
  for (int o = 32; o > 0; o >>= 1) s += __shfl_xor(s, o);
  const float inv = wts[0] / s;
  union { u16 u[4]; uint2 v; } pk;
  u16* pr = P + (long)row * 1536;
  pk.u[0] = f2b(e0 * inv); pk.u[1] = f2b(e1 * inv); pk.u[2] = f2b(e2 * inv); pk.u[3] = f2b(e3 * inv);
  *(uint2*)(pr + lane * 4) = pk.v;
  pk.u[0] = f2b(e4 * inv); pk.u[1] = f2b(e5 * inv); pk.u[2] = f2b(e6 * inv); pk.u[3] = f2b(e7 * inv);
  *(uint2*)(pr + 256 + lane * 4) = pk.v;
}

// ---------------- vertical pool + bkq + softmax + *w for scales 3 & 5 (grid.y) -------
__global__ __launch_bounds__(256)
void vp35(const float* __restrict__ hs3, const float* __restrict__ hs5,
          const float* __restrict__ bkq, u16* __restrict__ P,
          const float* __restrict__ wts) {
  const int sc = blockIdx.y;  // 0 -> kp=3, 1 -> kp=5
  const float* src = sc ? hs5 : hs3;
  const int dmax = sc ? 2 : 1;
  const float ik = sc ? (1.0f / 25.0f) : (1.0f / 9.0f);
  const int colOff = sc ? 1024 : 512;
  const int widx = sc ? 2 : 1;
  const int row = blockIdx.x * 4 + (threadIdx.x >> 6);  // [0, 4608)
  const int lane = threadIdx.x & 63;
  const int bloc = row / 2304;
  const int nn = row - bloc * 2304;
  const int y = nn / 48;
  float4 a0 = {0.f, 0.f, 0.f, 0.f}, a1 = {0.f, 0.f, 0.f, 0.f};
#pragma unroll
  for (int dy = -2; dy <= 2; dy++) {
    if (dy < -dmax || dy > dmax) continue;
    int yy = y + dy;
    if (yy < 0 || yy >= 48) continue;
    const float* r = src + (long)(row + dy * 48) * 512;
    float4 v0 = *(const float4*)(r + lane * 4);
    float4 v1 = *(const float4*)(r + 256 + lane * 4);
    a0.x += v0.x; a0.y += v0.y; a0.z += v0.z; a0.w += v0.w;
    a1.x += v1.x; a1.y += v1.y; a1.z += v1.z; a1.w += v1.w;
  }
  const float* bk = bkq + (long)bloc * 512;
  float4 q0 = *(const float4*)(bk + lane * 4);
  float4 q1v = *(const float4*)(bk + 256 + lane * 4);
  a0.x = a0.x * ik + q0.x;  a0.y = a0.y * ik + q0.y;
  a0.z = a0.z * ik + q0.z;  a0.w = a0.w * ik + q0.w;
  a1.x = a1.x * ik + q1v.x; a1.y = a1.y * ik + q1v.y;
  a1.z = a1.z * ik + q1v.z; a1.w = a1.w * ik + q1v.w;
  float m = fmaxf(fmaxf(fmaxf(a0.x, a0.y), fmaxf(a0.z, a0.w)),
                  fmaxf(fmaxf(a1.x, a1.y), fmaxf(a1.z, a1.w)));
#pragma unroll
  for (int o = 32; o > 0; o >>= 1) m = fmaxf(m, __shfl_xor(m, o));
  float e0 = __expf(a0.x - m), e1 = __expf(a0.y - m), e2 = __expf(a0.z - m), e3 = __expf(a0.w - m);
  float e4 = __expf(a1.x - m), e5 = __expf(a1.y - m), e6 = __expf(a1.z - m), e7 = __expf(a1.w - m);
  float s = ((e0 + e1) + (e2 + e3)) + ((e4 + e5) + (e6 + e7));
#pragma unroll
  for (int o = 32; o > 0; o >>= 1) s += __shfl_xor(s, o);
  const float inv = wts[widx] / s;
  union { u16 u[4]; uint2 v; } pk;
  u16* pr = P + (long)row * 1536 + colOff;
  pk.u[0] = f2b(e0 * inv); pk.u[1] = f2b(e1 * inv); pk.u[2] = f2b(e2 * inv); pk.u[3] = f2b(e3 * inv);
  *(uint2*)(pr + lane * 4) = pk.v;
  pk.u[0] = f2b(e4 * inv); pk.u[1] = f2b(e5 * inv); pk.u[2] = f2b(e6 * inv); pk.u[3] = f2b(e7 * inv);
  *(uint2*)(pr + 256 + lane * 4) = pk.v;
}

extern "C" void kernel_launch(void* const* d_in, const int* in_sizes, int n_in,
                              void* d_out, int out_size, void* d_ws, size_t ws_size,
                              hipStream_t stream) {
  const float* v_feat = (const float*)d_in[0];
  const float* t_tok  = (const float*)d_in[1];
  const float* Wq  = (const float*)d_in[2];
  const float* bq  = (const float*)d_in[3];
  const float* Wk  = (const float*)d_in[4];
  const float* bk  = (const float*)d_in[5];
  const float* Wv  = (const float*)d_in[6];
  const float* bv  = (const float*)d_in[7];
  const float* lam = (const float*)d_in[8];

  // Workspace layout (97.0 MB total; loop = 4 super-chunks of 4 batches, each
  // processed as 2 halves of 2 batches; PV runs once per super-chunk with z=4).
  char* const wsb = (char*)d_ws;
  float* wts  = (float*)(wsb);                  // 256 B
  u16* Wq16   = (u16*)(wsb + 256);              // 2 MB
  u16* Wk16   = (u16*)(wsb + 2097408);          // 1.5 MB
  u16* WvT    = (u16*)(wsb + 3670272);          // 1.5 MB
  u16* GT     = (u16*)(wsb + 5243136);          // (1024, 768) bf16, 1.5 MB
  float* hvec = (float*)(wsb + 6816000);        // 4 KB
  float* uvec = (float*)(wsb + 6820096);        // 769 floats (+pad)
  float* bkq  = (float*)(wsb + 6824192);        // (B, L) fp32, 32 KB
  u16* WkqT   = (u16*)(wsb + 6856960);          // (B*L, C) bf16, 16.8 MB
  u16* vtxtT  = (u16*)(wsb + 23634176);         // (B, C, L) bf16, 16.8 MB
  char* const chunk = wsb + 40411392;
  u16* tt16   = (u16*)chunk;                    // (B*L, Ct) bf16, 12.6 MB (pre-loop only)
  u16* vflat  = (u16*)chunk;                    // (2N, C) bf16, 9.44 MB
  float* hs3  = (float*)chunk;                  // aliases vflat (dead after S-GEMM)
  float* S1   = (float*)(chunk + 9437184);      // (2N, L) fp32, 9.44 MB
  float* hs5  = (float*)(chunk + 18874368);     // (2N, L) fp32, 9.44 MB
  u16* Pc     = (u16*)(chunk + 28311552);       // (4N, 3*L) bf16, 28.3 MB
  // end: 40411392 + 56623104 = 97,034,496 B

  float* out0 = (float*)d_out;
  const long CN = 1024L * 2304;

  softmax3_kernel<<<1, 64, 0, stream>>>(lam, wts);

  cast_f32_bf16<<<512, 256, 0, stream>>>(Wq, Wq16);       // 1048576 elems
  cast_f32_bf16<<<384, 256, 0, stream>>>(Wk, Wk16);       // 786432 elems
  transpose_f32<<<dim3(12, 16, 1), 256, 0, stream>>>(Wv, WvT, 768, 1024, 0, 0);
  cast_f32_bf16<<<3072, 256, 0, stream>>>(t_tok, tt16);   // 6291456 elems
  smallvecs_kernel<<<449, 256, 0, stream>>>(Wq, Wk, bq, bk, hvec, uvec);

  // GT(ci,t) = sum_co Wq(ci,co) * Wk(t,co)   : (1024, 768), K=1024
  gemm_nt<0, 0, false, 0><<<dim3(8, 6, 1), 256, 0, stream>>>(
      Wq16, 0, 1024, Wk16, 0, 1024, GT, 0, 768, nullptr, nullptr, nullptr, 1.0f, 1024);
  // WkqT(l,ci) = sum_t tt16(l,t) * GT(ci,t) + h(ci)  : (8192, 1024), K=768
  gemm_nt<1, 0, false, 0><<<dim3(64, 8, 1), 256, 0, stream>>>(
      tt16, 0, 768, GT, 0, 768, WkqT, 0, 1024, hvec, nullptr, nullptr, 1.0f, 768);
  // v_txtT(b) = Wv^T @ t_tok(b)^T + bv (per-m) : (1024,512) per batch, K=768
  gemm_nt<2, 0, false, 0><<<dim3(8, 4, 16), 256, 0, stream>>>(
      WvT, 0, 768, tt16, 512L * 768, 768, vtxtT, 1024L * 512, 512, bv, nullptr, nullptr, 1.0f, 768);
  // bkq[b,l] = scale * (tt16[b,l,:].u + beta0)  (rank-1 softmax-logit correction for
  // the bias that must be excluded from pooling: pool_k(const) != const at borders)
  bkq_kernel<<<2048, 256, 0, stream>>>(tt16, uvec, bkq);

  for (int sc = 0; sc < 4; sc++) {
    const long b0 = 4L * sc;
    for (int hf = 0; hf < 2; hf++) {
      const long bb = b0 + 2 * hf;
      const float* vf_ch = v_feat + bb * CN;
      u16* Ph = Pc + (long)hf * (2L * 2304 * 1536);
      // vflat = transpose(v_feat 2-batch half) as bf16: (2N, C)
      transpose_f32<<<dim3(16, 36, 2), 256, 0, stream>>>(
          vf_ch, vflat, 1024, 2304, CN, 2304L * 1024);
      // S1 = (vflat @ WkqT_b^T) / 32  (fp32, per batch) — split-K2 halves latency
      gemm_s_sk2<<<dim3(18, 4, 2), 512, 0, stream>>>(
          vflat, 2304L * 1024, 1024, WkqT + bb * (512L * 1024), 512L * 1024, 1024,
          S1, 2304L * 512, 512, 0.03125f, 1024);
      // fused: hs3/hs5 horizontal sums (single S1 read) + scale-1 softmax -> P[:,0:512]
      hpool35sm<<<1152, 256, 0, stream>>>(S1, bkq + bb * 512, hs3, hs5, Ph, wts);
      // scales 3 & 5: vertical pool + bkq + softmax + weight -> P slices (one launch)
      vp35<<<dim3(1152, 2), 256, 0, stream>>>(hs3, hs5, bkq + bb * 512, Ph, wts);
    }
    // out^T for 4 batches in one launch (576 blocks):
    // out(c,n) = sum_l vtxtT(c,l-wrapped) * P(n,l) + v_feat(c,n)
    gemm_nt<0, 3, false, 511><<<dim3(8, 18, 4), 256, 0, stream>>>(
        vtxtT + b0 * (1024L * 512), 1024L * 512, 512, Pc, 2304L * 1536, 1536,
        out0 + b0 * CN, CN, 2304, nullptr, v_feat + b0 * CN, nullptr, 1.0f, 1536);
  }

  // out1 = t_tok (raw fp32 copy)
  hipMemcpyAsync((void*)(out0 + 37748736L), (const void*)t_tok, 25165824L,
                 hipMemcpyDeviceToDevice, stream);
}

// Round 6
// 975.562 us; speedup vs baseline: 2.7386x; 1.0082x over previous
//
#include <hip/hip_runtime.h>

typedef unsigned short u16;
typedef short short8 __attribute__((ext_vector_type(8)));
typedef float floatx4 __attribute__((ext_vector_type(4)));

__device__ __forceinline__ float b2f(u16 h) {
  union { unsigned int u; float f; } z;
  z.u = ((unsigned int)h) << 16;
  return z.f;
}
__device__ __forceinline__ u16 f2b(float f) {
  union { float f; unsigned int u; } z;
  z.f = f;
  unsigned int u = z.u;
  unsigned int r = (u + 0x7fffu + ((u >> 16) & 1u)) >> 16;
  return (u16)r;
}

// ---- global_load_lds staging of a 128x64 bf16 tile (16 KB), XOR-swizzled ----------
__device__ __forceinline__ void stage_tile64(const u16* __restrict__ gsrc, int lda,
                                             u16* lds, int wave, int lane) {
#pragma unroll
  for (int i = 0; i < 4; i++) {
    const int s = wave * 256 + i * 64 + lane;
    const int row = s >> 3;
    const int c8 = (s & 7) ^ (row & 7);
    const u16* g = gsrc + (long)row * lda + (c8 << 3);
    u16* l = lds + (wave * 256 + i * 64) * 8;  // wave-uniform
    __builtin_amdgcn_global_load_lds(
        (const __attribute__((address_space(1))) unsigned int*)g,
        (__attribute__((address_space(3))) unsigned int*)l, 16, 0, 0);
  }
}
// swizzled 16B fragment read: row in [0,128), slot in [0,8)
__device__ __forceinline__ short8 frag64(const u16* lds, int row, int slot) {
  return *(const short8*)(lds + (row << 6) + ((slot ^ (row & 7)) << 3));
}

// ---------------- softmax over the 3 lambda scalars (fp32) -> scale weights ---------
__global__ void softmax3_kernel(const float* __restrict__ lam, float* __restrict__ w) {
  if (threadIdx.x == 0) {
    float a = lam[0], b = lam[1], c = lam[2];
    float m = fmaxf(a, fmaxf(b, c));
    float ea = __expf(a - m), eb = __expf(b - m), ec = __expf(c - m);
    float s = ea + eb + ec;
    w[0] = ea / s; w[1] = eb / s; w[2] = ec / s;
  }
}

// ---------------- cast fp32 -> bf16, 8 elems/thread ---------------------------------
__global__ __launch_bounds__(256)
void cast_f32_bf16(const float* __restrict__ src, u16* __restrict__ dst) {
  const long i = ((long)blockIdx.x * 256 + threadIdx.x) * 8;
  float4 v0 = *(const float4*)(src + i);
  float4 v1 = *(const float4*)(src + i + 4);
  u16 r[8] __attribute__((aligned(16)));
  r[0] = f2b(v0.x); r[1] = f2b(v0.y); r[2] = f2b(v0.z); r[3] = f2b(v0.w);
  r[4] = f2b(v1.x); r[5] = f2b(v1.y); r[6] = f2b(v1.z); r[7] = f2b(v1.w);
  *(uint4*)(dst + i) = *(const uint4*)r;
}

// ---------------- transpose fp32 src (b,R,Cc) -> bf16 dst (b,Cc,R) ------------------
__global__ __launch_bounds__(256)
void transpose_f32(const float* __restrict__ src, u16* __restrict__ dst,
                   int R, int Cc, long sSrc, long sDst) {
  __shared__ u16 t[64][66];
  const int tid = threadIdx.x;
  const long r0 = (long)blockIdx.x << 6;
  const long c0 = (long)blockIdx.y << 6;
  const float* s = src + (long)blockIdx.z * sSrc;
  u16* d = dst + (long)blockIdx.z * sDst;
  const int rr = tid >> 2;
  const int cb = (tid & 3) << 2;  // 0,4,8,12
#pragma unroll
  for (int h = 0; h < 4; h++) {
    int cc = cb + h * 16;
    float4 v = *(const float4*)(s + (r0 + rr) * Cc + c0 + cc);
    t[rr][cc + 0] = f2b(v.x); t[rr][cc + 1] = f2b(v.y);
    t[rr][cc + 2] = f2b(v.z); t[rr][cc + 3] = f2b(v.w);
  }
  __syncthreads();
  const int cr = tid >> 2;
  const int nb0 = (tid & 3) << 3;
#pragma unroll
  for (int h = 0; h < 2; h++) {
    int rb = nb0 + h * 32;
    u16 res[8] __attribute__((aligned(16)));
#pragma unroll
    for (int j = 0; j < 8; j++) res[j] = t[rb + j][cr];
    *(uint4*)(d + (c0 + cr) * R + r0 + rb) = *(const uint4*)res;
  }
}

// ---------------- GEMM: C = alpha * A(row-major MxK) * B^T (B is NxK row-major) ------
// BK=64, global_load_lds staging, XOR-swizzled LDS. K must be a multiple of 64.
template <int BIAS_MODE, int OUT_MODE, bool BETA_ACC, int AMASK>
__global__ __launch_bounds__(256)
void gemm_nt(const u16* __restrict__ A, long sA, int lda,
             const u16* __restrict__ Bm, long sB, int ldb,
             void* __restrict__ Cv, long sC, int ldc,
             const float* __restrict__ bias, const float* __restrict__ resid,
             const float* __restrict__ alphap, float alphac, int K) {
  __shared__ __align__(16) u16 As[8192];
  __shared__ __align__(16) u16 Bs[8192];
  const int tid = threadIdx.x;
  const long m0 = (long)blockIdx.x * 128;
  const long n0 = (long)blockIdx.y * 128;
  const u16* Ab = A + (long)blockIdx.z * sA + m0 * lda;
  const u16* Bb = Bm + (long)blockIdx.z * sB + n0 * ldb;
  const int wave = tid >> 6;
  const int lane = tid & 63;
  const int wr = (wave >> 1) << 6;
  const int wc = (wave & 1) << 6;
  const int quad = lane >> 4;
  const int lr = lane & 15;
  floatx4 acc[4][4] = {};
  for (int k0 = 0; k0 < K; k0 += 64) {
    const int ka = AMASK ? (k0 & AMASK) : k0;
    __syncthreads();
    stage_tile64(Ab + ka, lda, As, wave, lane);
    stage_tile64(Bb + k0, ldb, Bs, wave, lane);
    __syncthreads();
#pragma unroll
    for (int kk = 0; kk < 2; kk++) {
      short8 af[4], bfr[4];
#pragma unroll
      for (int i = 0; i < 4; i++) af[i] = frag64(As, wr + i * 16 + lr, kk * 4 + quad);
#pragma unroll
      for (int j = 0; j < 4; j++) bfr[j] = frag64(Bs, wc + j * 16 + lr, kk * 4 + quad);
#pragma unroll
      for (int i = 0; i < 4; i++)
#pragma unroll
        for (int j = 0; j < 4; j++)
          acc[i][j] = __builtin_amdgcn_mfma_f32_16x16x32_bf16(af[i], bfr[j], acc[i][j], 0, 0, 0);
    }
  }
  const float alpha = alphac * (alphap ? alphap[0] : 1.0f);
  const long cb = (long)blockIdx.z * sC;
#pragma unroll
  for (int i = 0; i < 4; i++) {
#pragma unroll
    for (int r = 0; r < 4; r++) {
      long m = m0 + wr + i * 16 + quad * 4 + r;
      float bm = (BIAS_MODE == 2) ? bias[m] : 0.0f;
#pragma unroll
      for (int j = 0; j < 4; j++) {
        long n = n0 + wc + j * 16 + lr;
        float v = alpha * acc[i][j][r];
        if (BIAS_MODE == 1) v += bias[n];
        if (BIAS_MODE == 2) v += bm;
        long off = cb + m * (long)ldc + n;
        if (OUT_MODE == 3) {
          float* Cf = (float*)Cv;
          Cf[off] = v + resid[off];
        } else if (OUT_MODE == 1) {
          float* Cf = (float*)Cv;
          if (BETA_ACC) v += Cf[off];
          Cf[off] = v;
        } else {
          ((u16*)Cv)[off] = f2b(v);
        }
      }
    }
  }
}

// ---------------- split-K2 GEMM for S (latency-bound 144-block grid) -----------------
__global__ __launch_bounds__(512)
void gemm_s_sk2(const u16* __restrict__ A, long sA, int lda,
                const u16* __restrict__ Bm, long sB, int ldb,
                float* __restrict__ C, long sC, int ldc,
                float alpha, int K) {
  __shared__ __align__(16) u16 smem[32768];  // 64 KB
  float* scr = (float*)smem;                 // epilogue scratch aliases staging
  const int tid = threadIdx.x;
  const int h = tid >> 8;               // k-half
  const long m0 = (long)blockIdx.x * 128;
  const long n0 = (long)blockIdx.y * 128;
  const int Kh = K >> 1;
  const u16* Ab = A + (long)blockIdx.z * sA + m0 * lda + (long)h * Kh;
  const u16* Bb = Bm + (long)blockIdx.z * sB + n0 * ldb + (long)h * Kh;
  u16* AsH = smem + h * 8192;
  u16* BsH = smem + 16384 + h * 8192;
  const int wave = tid >> 6;            // 0..7
  const int w4 = wave & 3;              // wave within half
  const int q = wave & 3;               // output quadrant (shared between halves)
  const int lane = tid & 63;
  const int wr = (q >> 1) << 6;
  const int wc = (q & 1) << 6;
  const int quad = lane >> 4;
  const int lr = lane & 15;
  floatx4 acc[4][4] = {};
  for (int k0 = 0; k0 < Kh; k0 += 64) {
    __syncthreads();
    stage_tile64(Ab + k0, lda, AsH, w4, lane);
    stage_tile64(Bb + k0, ldb, BsH, w4, lane);
    __syncthreads();
#pragma unroll
    for (int kk = 0; kk < 2; kk++) {
      short8 af[4], bfr[4];
#pragma unroll
      for (int i = 0; i < 4; i++) af[i] = frag64(AsH, wr + i * 16 + lr, kk * 4 + quad);
#pragma unroll
      for (int j = 0; j < 4; j++) bfr[j] = frag64(BsH, wc + j * 16 + lr, kk * 4 + quad);
#pragma unroll
      for (int i = 0; i < 4; i++)
#pragma unroll
        for (int j = 0; j < 4; j++)
          acc[i][j] = __builtin_amdgcn_mfma_f32_16x16x32_bf16(af[i], bfr[j], acc[i][j], 0, 0, 0);
    }
  }
  __syncthreads();
#pragma unroll
  for (int pass = 0; pass < 2; pass++) {
    if (h == 1 && (q >> 1) == pass) {
#pragma unroll
      for (int i = 0; i < 4; i++)
#pragma unroll
        for (int j = 0; j < 4; j++)
          *(floatx4*)&scr[(q & 1) * 4096 + (j * 16 + lr) * 64 +
                          (((i * 16 + quad * 4)) ^ ((lr & 7) << 2))] = acc[i][j];
    }
    __syncthreads();
    if (h == 0 && (q >> 1) == pass) {
#pragma unroll
      for (int i = 0; i < 4; i++)
#pragma unroll
        for (int j = 0; j < 4; j++)
          acc[i][j] += *(const floatx4*)&scr[(q & 1) * 4096 + (j * 16 + lr) * 64 +
                                             (((i * 16 + quad * 4)) ^ ((lr & 7) << 2))];
    }
    __syncthreads();
  }
  if (h == 0) {
    const long cb = (long)blockIdx.z * sC;
#pragma unroll
    for (int i = 0; i < 4; i++) {
#pragma unroll
      for (int r = 0; r < 4; r++) {
        long m = m0 + wr + i * 16 + quad * 4 + r;
#pragma unroll
        for (int j = 0; j < 4; j++) {
          long n = n0 + wc + j * 16 + lr;
          C[cb + m * (long)ldc + n] = alpha * acc[i][j][r];
        }
      }
    }
  }
}

// ---------------- small dot-product vectors: h = Wq.bk, u = Wk.bq, beta0 = bk.bq ------
__global__ __launch_bounds__(256)
void smallvecs_kernel(const float* __restrict__ Wq, const float* __restrict__ Wk,
                      const float* __restrict__ bq, const float* __restrict__ bk,
                      float* __restrict__ hvec, float* __restrict__ uvec) {
  const int row = blockIdx.x * 4 + (threadIdx.x >> 6);
  if (row > 1792) return;
  const int lane = threadIdx.x & 63;
  const float* src; const float* vec; float* dst;
  if (row < 1024) { src = Wq + (long)row * 1024; vec = bk; dst = hvec + row; }
  else if (row < 1792) { src = Wk + (long)(row - 1024) * 1024; vec = bq; dst = uvec + (row - 1024); }
  else { src = bk; vec = bq; dst = uvec + 768; }
  float s = 0.f;
#pragma unroll
  for (int h = 0; h < 4; h++) {
    float4 a = *(const float4*)(src + h * 256 + lane * 4);
    float4 b = *(const float4*)(vec + h * 256 + lane * 4);
    s += a.x * b.x + a.y * b.y + a.z * b.z + a.w * b.w;
  }
#pragma unroll
  for (int o = 32; o > 0; o >>= 1) s += __shfl_xor(s, o);
  if (lane == 0) *dst = s;
}

// ---------------- bkq[b,l] = 0.03125 * (tt16[b,l,:].uvec + beta0) --------------------
__global__ __launch_bounds__(256)
void bkq_kernel(const u16* __restrict__ tt, const float* __restrict__ uvec,
                float* __restrict__ bkq) {
  const long row = (long)blockIdx.x * 4 + (threadIdx.x >> 6);  // [0, 8192)
  const int lane = threadIdx.x & 63;
  const u16* tr = tt + row * 768;
  float s = 0.f;
#pragma unroll
  for (int h = 0; h < 3; h++) {
    uint2 kv = *(const uint2*)(tr + h * 256 + lane * 4);
    const u16* ku = (const u16*)&kv;
    float4 b = *(const float4*)(uvec + h * 256 + lane * 4);
    s += b2f(ku[0]) * b.x + b2f(ku[1]) * b.y + b2f(ku[2]) * b.z + b2f(ku[3]) * b.w;
  }
#pragma unroll
  for (int o = 32; o > 0; o >>= 1) s += __shfl_xor(s, o);
  if (lane == 0) bkq[row] = 0.03125f * (s + uvec[768]);
}

// ---------------- softmax + weighted bf16 write helper -------------------------------
__device__ __forceinline__ void sm_write(float4 a0, float4 a1, float w,
                                         u16* __restrict__ pr, int lane) {
  float m = fmaxf(fmaxf(fmaxf(a0.x, a0.y), fmaxf(a0.z, a0.w)),
                  fmaxf(fmaxf(a1.x, a1.y), fmaxf(a1.z, a1.w)));
#pragma unroll
  for (int o = 32; o > 0; o >>= 1) m = fmaxf(m, __shfl_xor(m, o));
  float e0 = __expf(a0.x - m), e1 = __expf(a0.y - m), e2 = __expf(a0.z - m), e3 = __expf(a0.w - m);
  float e4 = __expf(a1.x - m), e5 = __expf(a1.y - m), e6 = __expf(a1.z - m), e7 = __expf(a1.w - m);
  float s = ((e0 + e1) + (e2 + e3)) + ((e4 + e5) + (e6 + e7));
#pragma unroll
  for (int o = 32; o > 0; o >>= 1) s += __shfl_xor(s, o);
  const float inv = w / s;
  union { u16 u[4]; uint2 v; } pk;
  pk.u[0] = f2b(e0 * inv); pk.u[1] = f2b(e1 * inv); pk.u[2] = f2b(e2 * inv); pk.u[3] = f2b(e3 * inv);
  *(uint2*)(pr + lane * 4) = pk.v;
  pk.u[0] = f2b(e4 * inv); pk.u[1] = f2b(e5 * inv); pk.u[2] = f2b(e6 * inv); pk.u[3] = f2b(e7 * inv);
  *(uint2*)(pr + 256 + lane * 4) = pk.v;
}

// ---------------- fused 25-tap 2D pool + 3x softmax -> all P slices ------------------
// One wave per row over a 4-batch super-chunk (S1 is L2/L3-resident; no hs
// intermediates). Accumulation order bit-identically replicates the former
// hpool35sm/vp35 two-pass order: per-dy horizontal sums (dx ascending), then
// dy-ascending vertical accumulation; scale-1 uses the raw center row.
__global__ __launch_bounds__(256)
void pool_sm(const float* __restrict__ S1, const float* __restrict__ bkq,
             u16* __restrict__ P, const float* __restrict__ wts) {
  const int row = blockIdx.x * 4 + (threadIdx.x >> 6);  // [0, 9216)
  const int lane = threadIdx.x & 63;
  const int bloc = row / 2304;
  const int nn = row - bloc * 2304;
  const int x = nn % 48;
  const int y = nn / 48;
  float4 c0 = {0.f, 0.f, 0.f, 0.f}, c1 = {0.f, 0.f, 0.f, 0.f};
  float4 a3x = {0.f, 0.f, 0.f, 0.f}, a3y = {0.f, 0.f, 0.f, 0.f};
  float4 a5x = {0.f, 0.f, 0.f, 0.f}, a5y = {0.f, 0.f, 0.f, 0.f};
#pragma unroll
  for (int dy = -2; dy <= 2; dy++) {
    int yy = y + dy;
    if (yy < 0 || yy >= 48) continue;
    float4 h5x = {0.f, 0.f, 0.f, 0.f}, h5y = {0.f, 0.f, 0.f, 0.f};
    float4 h3x = {0.f, 0.f, 0.f, 0.f}, h3y = {0.f, 0.f, 0.f, 0.f};
#pragma unroll
    for (int dx = -2; dx <= 2; dx++) {
      int xx = x + dx;
      if (xx < 0 || xx >= 48) continue;
      const float* r = S1 + (long)(row + dy * 48 + dx) * 512;
      float4 v0 = *(const float4*)(r + lane * 4);
      float4 v1 = *(const float4*)(r + 256 + lane * 4);
      h5x.x += v0.x; h5x.y += v0.y; h5x.z += v0.z; h5x.w += v0.w;
      h5y.x += v1.x; h5y.y += v1.y; h5y.z += v1.z; h5y.w += v1.w;
      if (dx >= -1 && dx <= 1) {
        h3x.x += v0.x; h3x.y += v0.y; h3x.z += v0.z; h3x.w += v0.w;
        h3y.x += v1.x; h3y.y += v1.y; h3y.z += v1.z; h3y.w += v1.w;
      }
      if (dx == 0 && dy == 0) { c0 = v0; c1 = v1; }
    }
    a5x.x += h5x.x; a5x.y += h5x.y; a5x.z += h5x.z; a5x.w += h5x.w;
    a5y.x += h5y.x; a5y.y += h5y.y; a5y.z += h5y.z; a5y.w += h5y.w;
    if (dy >= -1 && dy <= 1) {
      a3x.x += h3x.x; a3x.y += h3x.y; a3x.z += h3x.z; a3x.w += h3x.w;
      a3y.x += h3y.x; a3y.y += h3y.y; a3y.z += h3y.z; a3y.w += h3y.w;
    }
  }
  const float* bk = bkq + (long)bloc * 512;
  float4 q0 = *(const float4*)(bk + lane * 4);
  float4 q1v = *(const float4*)(bk + 256 + lane * 4);
  u16* pr = P + (long)row * 1536;
  // scale 1: raw center + bkq
  c0.x += q0.x;  c0.y += q0.y;  c0.z += q0.z;  c0.w += q0.w;
  c1.x += q1v.x; c1.y += q1v.y; c1.z += q1v.z; c1.w += q1v.w;
  sm_write(c0, c1, wts[0], pr, lane);
  // scale 3
  const float ik3 = 1.0f / 9.0f;
  a3x.x = a3x.x * ik3 + q0.x;  a3x.y = a3x.y * ik3 + q0.y;
  a3x.z = a3x.z * ik3 + q0.z;  a3x.w = a3x.w * ik3 + q0.w;
  a3y.x = a3y.x * ik3 + q1v.x; a3y.y = a3y.y * ik3 + q1v.y;
  a3y.z = a3y.z * ik3 + q1v.z; a3y.w = a3y.w * ik3 + q1v.w;
  sm_write(a3x, a3y, wts[1], pr + 512, lane);
  // scale 5
  const float ik5 = 1.0f / 25.0f;
  a5x.x = a5x.x * ik5 + q0.x;  a5x.y = a5x.y * ik5 + q0.y;
  a5x.z = a5x.z * ik5 + q0.z;  a5x.w = a5x.w * ik5 + q0.w;
  a5y.x = a5y.x * ik5 + q1v.x; a5y.y = a5y.y * ik5 + q1v.y;
  a5y.z = a5y.z * ik5 + q1v.z; a5y.w = a5y.w * ik5 + q1v.w;
  sm_write(a5x, a5y, wts[2], pr + 1024, lane);
}

extern "C" void kernel_launch(void* const* d_in, const int* in_sizes, int n_in,
                              void* d_out, int out_size, void* d_ws, size_t ws_size,
                              hipStream_t stream) {
  const float* v_feat = (const float*)d_in[0];
  const float* t_tok  = (const float*)d_in[1];
  const float* Wq  = (const float*)d_in[2];
  const float* bq  = (const float*)d_in[3];
  const float* Wk  = (const float*)d_in[4];
  const float* bk  = (const float*)d_in[5];
  const float* Wv  = (const float*)d_in[6];
  const float* bv  = (const float*)d_in[7];
  const float* lam = (const float*)d_in[8];

  // Workspace layout (97.0 MB, same as passing R5; loop = 4 super-chunks of 4
  // batches; S14 spans the super-chunk; no hs intermediates).
  char* const wsb = (char*)d_ws;
  float* wts  = (float*)(wsb);                  // 256 B
  u16* Wq16   = (u16*)(wsb + 256);              // 2 MB
  u16* Wk16   = (u16*)(wsb + 2097408);          // 1.5 MB
  u16* WvT    = (u16*)(wsb + 3670272);          // 1.5 MB
  u16* GT     = (u16*)(wsb + 5243136);          // (1024, 768) bf16, 1.5 MB
  float* hvec = (float*)(wsb + 6816000);        // 4 KB
  float* uvec = (float*)(wsb + 6820096);        // 769 floats (+pad)
  float* bkq  = (float*)(wsb + 6824192);        // (B, L) fp32, 32 KB
  u16* WkqT   = (u16*)(wsb + 6856960);          // (B*L, C) bf16, 16.8 MB
  u16* vtxtT  = (u16*)(wsb + 23634176);         // (B, C, L) bf16, 16.8 MB
  char* const chunk = wsb + 40411392;
  u16* tt16   = (u16*)chunk;                    // (B*L, Ct) bf16, 12.6 MB (pre-loop only)
  u16* vflat  = (u16*)chunk;                    // (2N, C) bf16, 9.44 MB (per half)
  float* S14  = (float*)(chunk + 9437184);      // (4N, L) fp32, 18.87 MB (super-chunk)
  u16* Pc     = (u16*)(chunk + 28311552);       // (4N, 3*L) bf16, 28.3 MB
  // end: 40411392 + 56623104 = 97,034,496 B

  float* out0 = (float*)d_out;
  const long CN = 1024L * 2304;

  softmax3_kernel<<<1, 64, 0, stream>>>(lam, wts);

  cast_f32_bf16<<<512, 256, 0, stream>>>(Wq, Wq16);       // 1048576 elems
  cast_f32_bf16<<<384, 256, 0, stream>>>(Wk, Wk16);       // 786432 elems
  transpose_f32<<<dim3(12, 16, 1), 256, 0, stream>>>(Wv, WvT, 768, 1024, 0, 0);
  cast_f32_bf16<<<3072, 256, 0, stream>>>(t_tok, tt16);   // 6291456 elems
  smallvecs_kernel<<<449, 256, 0, stream>>>(Wq, Wk, bq, bk, hvec, uvec);

  // GT(ci,t) = sum_co Wq(ci,co) * Wk(t,co)   : (1024, 768), K=1024
  gemm_nt<0, 0, false, 0><<<dim3(8, 6, 1), 256, 0, stream>>>(
      Wq16, 0, 1024, Wk16, 0, 1024, GT, 0, 768, nullptr, nullptr, nullptr, 1.0f, 1024);
  // WkqT(l,ci) = sum_t tt16(l,t) * GT(ci,t) + h(ci)  : (8192, 1024), K=768
  gemm_nt<1, 0, false, 0><<<dim3(64, 8, 1), 256, 0, stream>>>(
      tt16, 0, 768, GT, 0, 768, WkqT, 0, 1024, hvec, nullptr, nullptr, 1.0f, 768);
  // v_txtT(b) = Wv^T @ t_tok(b)^T + bv (per-m) : (1024,512) per batch, K=768
  gemm_nt<2, 0, false, 0><<<dim3(8, 4, 16), 256, 0, stream>>>(
      WvT, 0, 768, tt16, 512L * 768, 768, vtxtT, 1024L * 512, 512, bv, nullptr, nullptr, 1.0f, 768);
  // bkq[b,l] = scale * (tt16[b,l,:].u + beta0)
  bkq_kernel<<<2048, 256, 0, stream>>>(tt16, uvec, bkq);

  for (int sc = 0; sc < 4; sc++) {
    const long b0 = 4L * sc;
    for (int hf = 0; hf < 2; hf++) {
      const long bb = b0 + 2 * hf;
      // vflat = transpose(v_feat 2-batch half) as bf16: (2N, C)
      transpose_f32<<<dim3(16, 36, 2), 256, 0, stream>>>(
          v_feat + bb * CN, vflat, 1024, 2304, CN, 2304L * 1024);
      // S1(half) = (vflat @ WkqT_b^T) / 32  (fp32, per batch)
      gemm_s_sk2<<<dim3(18, 4, 2), 512, 0, stream>>>(
          vflat, 2304L * 1024, 1024, WkqT + bb * (512L * 1024), 512L * 1024, 1024,
          S14 + (long)hf * (2L * 2304 * 512), 2304L * 512, 512, 0.03125f, 1024);
    }
    // fused 25-tap pool + 3 softmaxes for the whole super-chunk -> all P slices
    pool_sm<<<2304, 256, 0, stream>>>(S14, bkq + b0 * 512, Pc, wts);
    // out^T for 4 batches: out(c,n) = sum_l vtxtT(c,l&511) * P(n,l) + v_feat(c,n)
    gemm_nt<0, 3, false, 511><<<dim3(8, 18, 4), 256, 0, stream>>>(
        vtxtT + b0 * (1024L * 512), 1024L * 512, 512, Pc, 2304L * 1536, 1536,
        out0 + b0 * CN, CN, 2304, nullptr, v_feat + b0 * CN, nullptr, 1.0f, 1536);
  }

  // out1 = t_tok (raw fp32 copy)
  hipMemcpyAsync((void*)(out0 + 37748736L), (const void*)t_tok, 25165824L,
                 hipMemcpyDeviceToDevice, stream);
}

// Round 7
// 753.413 us; speedup vs baseline: 3.5461x; 1.2949x over previous
//
#include <hip/hip_runtime.h>

typedef unsigned short u16;
typedef short short8 __attribute__((ext_vector_type(8)));
typedef float floatx4 __attribute__((ext_vector_type(4)));

__device__ __forceinline__ float b2f(u16 h) {
  union { unsigned int u; float f; } z;
  z.u = ((unsigned int)h) << 16;
  return z.f;
}
__device__ __forceinline__ u16 f2b(float f) {
  union { float f; unsigned int u; } z;
  z.f = f;
  unsigned int u = z.u;
  unsigned int r = (u + 0x7fffu + ((u >> 16) & 1u)) >> 16;
  return (u16)r;
}

// ---- global_load_lds staging of a 128x64 bf16 tile (16 KB), XOR-swizzled ----------
__device__ __forceinline__ void stage_tile64(const u16* __restrict__ gsrc, int lda,
                                             u16* lds, int wave, int lane) {
#pragma unroll
  for (int i = 0; i < 4; i++) {
    const int s = wave * 256 + i * 64 + lane;
    const int row = s >> 3;
    const int c8 = (s & 7) ^ (row & 7);
    const u16* g = gsrc + (long)row * lda + (c8 << 3);
    u16* l = lds + (wave * 256 + i * 64) * 8;  // wave-uniform
    __builtin_amdgcn_global_load_lds(
        (const __attribute__((address_space(1))) unsigned int*)g,
        (__attribute__((address_space(3))) unsigned int*)l, 16, 0, 0);
  }
}
// swizzled 16B fragment read: row in [0,128), slot in [0,8)
__device__ __forceinline__ short8 frag64(const u16* lds, int row, int slot) {
  return *(const short8*)(lds + (row << 6) + ((slot ^ (row & 7)) << 3));
}

// ---------------- softmax over the 3 lambda scalars (fp32) -> scale weights ---------
__global__ void softmax3_kernel(const float* __restrict__ lam, float* __restrict__ w) {
  if (threadIdx.x == 0) {
    float a = lam[0], b = lam[1], c = lam[2];
    float m = fmaxf(a, fmaxf(b, c));
    float ea = __expf(a - m), eb = __expf(b - m), ec = __expf(c - m);
    float s = ea + eb + ec;
    w[0] = ea / s; w[1] = eb / s; w[2] = ec / s;
  }
}

// ---------------- cast fp32 -> bf16, 8 elems/thread ---------------------------------
__global__ __launch_bounds__(256)
void cast_f32_bf16(const float* __restrict__ src, u16* __restrict__ dst) {
  const long i = ((long)blockIdx.x * 256 + threadIdx.x) * 8;
  float4 v0 = *(const float4*)(src + i);
  float4 v1 = *(const float4*)(src + i + 4);
  u16 r[8] __attribute__((aligned(16)));
  r[0] = f2b(v0.x); r[1] = f2b(v0.y); r[2] = f2b(v0.z); r[3] = f2b(v0.w);
  r[4] = f2b(v1.x); r[5] = f2b(v1.y); r[6] = f2b(v1.z); r[7] = f2b(v1.w);
  *(uint4*)(dst + i) = *(const uint4*)r;
}

// ---------------- transpose fp32 src (b,R,Cc) -> bf16 dst (b,Cc,R) ------------------
__global__ __launch_bounds__(256)
void transpose_f32(const float* __restrict__ src, u16* __restrict__ dst,
                   int R, int Cc, long sSrc, long sDst) {
  __shared__ u16 t[64][66];
  const int tid = threadIdx.x;
  const long r0 = (long)blockIdx.x << 6;
  const long c0 = (long)blockIdx.y << 6;
  const float* s = src + (long)blockIdx.z * sSrc;
  u16* d = dst + (long)blockIdx.z * sDst;
  const int rr = tid >> 2;
  const int cb = (tid & 3) << 2;  // 0,4,8,12
#pragma unroll
  for (int h = 0; h < 4; h++) {
    int cc = cb + h * 16;
    float4 v = *(const float4*)(s + (r0 + rr) * Cc + c0 + cc);
    t[rr][cc + 0] = f2b(v.x); t[rr][cc + 1] = f2b(v.y);
    t[rr][cc + 2] = f2b(v.z); t[rr][cc + 3] = f2b(v.w);
  }
  __syncthreads();
  const int cr = tid >> 2;
  const int nb0 = (tid & 3) << 3;
#pragma unroll
  for (int h = 0; h < 2; h++) {
    int rb = nb0 + h * 32;
    u16 res[8] __attribute__((aligned(16)));
#pragma unroll
    for (int j = 0; j < 8; j++) res[j] = t[rb + j][cr];
    *(uint4*)(d + (c0 + cr) * R + r0 + rb) = *(const uint4*)res;
  }
}

// ---------------- GEMM: C = alpha * A(row-major MxK) * B^T (B is NxK row-major) ------
// BK=64, global_load_lds staging, XOR-swizzled LDS. K must be a multiple of 64.
template <int BIAS_MODE, int OUT_MODE, bool BETA_ACC>
__global__ __launch_bounds__(256)
void gemm_nt(const u16* __restrict__ A, long sA, int lda,
             const u16* __restrict__ Bm, long sB, int ldb,
             void* __restrict__ Cv, long sC, int ldc,
             const float* __restrict__ bias, const float* __restrict__ resid,
             const float* __restrict__ alphap, float alphac, int K) {
  __shared__ __align__(16) u16 As[8192];
  __shared__ __align__(16) u16 Bs[8192];
  const int tid = threadIdx.x;
  const long m0 = (long)blockIdx.x * 128;
  const long n0 = (long)blockIdx.y * 128;
  const u16* Ab = A + (long)blockIdx.z * sA + m0 * lda;
  const u16* Bb = Bm + (long)blockIdx.z * sB + n0 * ldb;
  const int wave = tid >> 6;
  const int lane = tid & 63;
  const int wr = (wave >> 1) << 6;
  const int wc = (wave & 1) << 6;
  const int quad = lane >> 4;
  const int lr = lane & 15;
  floatx4 acc[4][4] = {};
  for (int k0 = 0; k0 < K; k0 += 64) {
    __syncthreads();
    stage_tile64(Ab + k0, lda, As, wave, lane);
    stage_tile64(Bb + k0, ldb, Bs, wave, lane);
    __syncthreads();
#pragma unroll
    for (int kk = 0; kk < 2; kk++) {
      short8 af[4], bfr[4];
#pragma unroll
      for (int i = 0; i < 4; i++) af[i] = frag64(As, wr + i * 16 + lr, kk * 4 + quad);
#pragma unroll
      for (int j = 0; j < 4; j++) bfr[j] = frag64(Bs, wc + j * 16 + lr, kk * 4 + quad);
#pragma unroll
      for (int i = 0; i < 4; i++)
#pragma unroll
        for (int j = 0; j < 4; j++)
          acc[i][j] = __builtin_amdgcn_mfma_f32_16x16x32_bf16(af[i], bfr[j], acc[i][j], 0, 0, 0);
    }
  }
  const float alpha = alphac * (alphap ? alphap[0] : 1.0f);
  const long cb = (long)blockIdx.z * sC;
#pragma unroll
  for (int i = 0; i < 4; i++) {
#pragma unroll
    for (int r = 0; r < 4; r++) {
      long m = m0 + wr + i * 16 + quad * 4 + r;
      float bm = (BIAS_MODE == 2) ? bias[m] : 0.0f;
#pragma unroll
      for (int j = 0; j < 4; j++) {
        long n = n0 + wc + j * 16 + lr;
        float v = alpha * acc[i][j][r];
        if (BIAS_MODE == 1) v += bias[n];
        if (BIAS_MODE == 2) v += bm;
        long off = cb + m * (long)ldc + n;
        if (OUT_MODE == 3) {
          float* Cf = (float*)Cv;
          Cf[off] = v + resid[off];
        } else if (OUT_MODE == 1) {
          float* Cf = (float*)Cv;
          if (BETA_ACC) v += Cf[off];
          Cf[off] = v;
        } else {
          ((u16*)Cv)[off] = f2b(v);
        }
      }
    }
  }
}

// ---------------- split-K2 GEMM for S (latency-sensitive) ----------------------------
__global__ __launch_bounds__(512)
void gemm_s_sk2(const u16* __restrict__ A, long sA, int lda,
                const u16* __restrict__ Bm, long sB, int ldb,
                float* __restrict__ C, long sC, int ldc,
                float alpha, int K) {
  __shared__ __align__(16) u16 smem[32768];  // 64 KB
  float* scr = (float*)smem;                 // epilogue scratch aliases staging
  const int tid = threadIdx.x;
  const int h = tid >> 8;               // k-half
  const long m0 = (long)blockIdx.x * 128;
  const long n0 = (long)blockIdx.y * 128;
  const int Kh = K >> 1;
  const u16* Ab = A + (long)blockIdx.z * sA + m0 * lda + (long)h * Kh;
  const u16* Bb = Bm + (long)blockIdx.z * sB + n0 * ldb + (long)h * Kh;
  u16* AsH = smem + h * 8192;
  u16* BsH = smem + 16384 + h * 8192;
  const int wave = tid >> 6;            // 0..7
  const int w4 = wave & 3;              // wave within half
  const int q = wave & 3;               // output quadrant (shared between halves)
  const int lane = tid & 63;
  const int wr = (q >> 1) << 6;
  const int wc = (q & 1) << 6;
  const int quad = lane >> 4;
  const int lr = lane & 15;
  floatx4 acc[4][4] = {};
  for (int k0 = 0; k0 < Kh; k0 += 64) {
    __syncthreads();
    stage_tile64(Ab + k0, lda, AsH, w4, lane);
    stage_tile64(Bb + k0, ldb, BsH, w4, lane);
    __syncthreads();
#pragma unroll
    for (int kk = 0; kk < 2; kk++) {
      short8 af[4], bfr[4];
#pragma unroll
      for (int i = 0; i < 4; i++) af[i] = frag64(AsH, wr + i * 16 + lr, kk * 4 + quad);
#pragma unroll
      for (int j = 0; j < 4; j++) bfr[j] = frag64(BsH, wc + j * 16 + lr, kk * 4 + quad);
#pragma unroll
      for (int i = 0; i < 4; i++)
#pragma unroll
        for (int j = 0; j < 4; j++)
          acc[i][j] = __builtin_amdgcn_mfma_f32_16x16x32_bf16(af[i], bfr[j], acc[i][j], 0, 0, 0);
    }
  }
  __syncthreads();
#pragma unroll
  for (int pass = 0; pass < 2; pass++) {
    if (h == 1 && (q >> 1) == pass) {
#pragma unroll
      for (int i = 0; i < 4; i++)
#pragma unroll
        for (int j = 0; j < 4; j++)
          *(floatx4*)&scr[(q & 1) * 4096 + (j * 16 + lr) * 64 +
                          (((i * 16 + quad * 4)) ^ ((lr & 7) << 2))] = acc[i][j];
    }
    __syncthreads();
    if (h == 0 && (q >> 1) == pass) {
#pragma unroll
      for (int i = 0; i < 4; i++)
#pragma unroll
        for (int j = 0; j < 4; j++)
          acc[i][j] += *(const floatx4*)&scr[(q & 1) * 4096 + (j * 16 + lr) * 64 +
                                             (((i * 16 + quad * 4)) ^ ((lr & 7) << 2))];
    }
    __syncthreads();
  }
  if (h == 0) {
    const long cb = (long)blockIdx.z * sC;
#pragma unroll
    for (int i = 0; i < 4; i++) {
#pragma unroll
      for (int r = 0; r < 4; r++) {
        long m = m0 + wr + i * 16 + quad * 4 + r;
#pragma unroll
        for (int j = 0; j < 4; j++) {
          long n = n0 + wc + j * 16 + lr;
          C[cb + m * (long)ldc + n] = alpha * acc[i][j][r];
        }
      }
    }
  }
}

// ---------------- small dot-product vectors: h = Wq.bk, u = Wk.bq, beta0 = bk.bq ------
__global__ __launch_bounds__(256)
void smallvecs_kernel(const float* __restrict__ Wq, const float* __restrict__ Wk,
                      const float* __restrict__ bq, const float* __restrict__ bk,
                      float* __restrict__ hvec, float* __restrict__ uvec) {
  const int row = blockIdx.x * 4 + (threadIdx.x >> 6);
  if (row > 1792) return;
  const int lane = threadIdx.x & 63;
  const float* src; const float* vec; float* dst;
  if (row < 1024) { src = Wq + (long)row * 1024; vec = bk; dst = hvec + row; }
  else if (row < 1792) { src = Wk + (long)(row - 1024) * 1024; vec = bq; dst = uvec + (row - 1024); }
  else { src = bk; vec = bq; dst = uvec + 768; }
  float s = 0.f;
#pragma unroll
  for (int h = 0; h < 4; h++) {
    float4 a = *(const float4*)(src + h * 256 + lane * 4);
    float4 b = *(const float4*)(vec + h * 256 + lane * 4);
    s += a.x * b.x + a.y * b.y + a.z * b.z + a.w * b.w;
  }
#pragma unroll
  for (int o = 32; o > 0; o >>= 1) s += __shfl_xor(s, o);
  if (lane == 0) *dst = s;
}

// ---------------- bkq[b,l] = 0.03125 * (tt16[b,l,:].uvec + beta0) --------------------
__global__ __launch_bounds__(256)
void bkq_kernel(const u16* __restrict__ tt, const float* __restrict__ uvec,
                float* __restrict__ bkq) {
  const long row = (long)blockIdx.x * 4 + (threadIdx.x >> 6);  // [0, 8192)
  const int lane = threadIdx.x & 63;
  const u16* tr = tt + row * 768;
  float s = 0.f;
#pragma unroll
  for (int h = 0; h < 3; h++) {
    uint2 kv = *(const uint2*)(tr + h * 256 + lane * 4);
    const u16* ku = (const u16*)&kv;
    float4 b = *(const float4*)(uvec + h * 256 + lane * 4);
    s += b2f(ku[0]) * b.x + b2f(ku[1]) * b.y + b2f(ku[2]) * b.z + b2f(ku[3]) * b.w;
  }
#pragma unroll
  for (int o = 32; o > 0; o >>= 1) s += __shfl_xor(s, o);
  if (lane == 0) bkq[row] = 0.03125f * (s + uvec[768]);
}

// ---------------- softmax + weighted fp32 accumulate (no intermediate bf16) ----------
__device__ __forceinline__ void sm_accum(float4 a0, float4 a1, float w,
                                         float& o0, float& o1, float& o2, float& o3,
                                         float& o4, float& o5, float& o6, float& o7) {
  float m = fmaxf(fmaxf(fmaxf(a0.x, a0.y), fmaxf(a0.z, a0.w)),
                  fmaxf(fmaxf(a1.x, a1.y), fmaxf(a1.z, a1.w)));
#pragma unroll
  for (int o = 32; o > 0; o >>= 1) m = fmaxf(m, __shfl_xor(m, o));
  float e0 = __expf(a0.x - m), e1 = __expf(a0.y - m), e2 = __expf(a0.z - m), e3 = __expf(a0.w - m);
  float e4 = __expf(a1.x - m), e5 = __expf(a1.y - m), e6 = __expf(a1.z - m), e7 = __expf(a1.w - m);
  float s = ((e0 + e1) + (e2 + e3)) + ((e4 + e5) + (e6 + e7));
#pragma unroll
  for (int o = 32; o > 0; o >>= 1) s += __shfl_xor(s, o);
  const float inv = w / s;
  o0 += e0 * inv; o1 += e1 * inv; o2 += e2 * inv; o3 += e3 * inv;
  o4 += e4 * inv; o5 += e5 * inv; o6 += e6 * inv; o7 += e7 * inv;
}

// ---------------- fused 25-tap 2D pool + 3x softmax -> SINGLE weighted P -------------
// Psum(n,l) = w1*softmax(S) + w2*softmax(pool3(S)) + w3*softmax(pool5(S)) summed in
// fp32 then rounded once to bf16. (PV with wrapped k == (sum_i w_i P_i) @ V, so the
// K=1536 PV collapses to K=512.)
__global__ __launch_bounds__(256)
void pool_sm(const float* __restrict__ S1, const float* __restrict__ bkq,
             u16* __restrict__ P, const float* __restrict__ wts) {
  const int row = blockIdx.x * 4 + (threadIdx.x >> 6);  // [0, 9216)
  const int lane = threadIdx.x & 63;
  const int bloc = row / 2304;
  const int nn = row - bloc * 2304;
  const int x = nn % 48;
  const int y = nn / 48;
  float4 c0 = {0.f, 0.f, 0.f, 0.f}, c1 = {0.f, 0.f, 0.f, 0.f};
  float4 a3x = {0.f, 0.f, 0.f, 0.f}, a3y = {0.f, 0.f, 0.f, 0.f};
  float4 a5x = {0.f, 0.f, 0.f, 0.f}, a5y = {0.f, 0.f, 0.f, 0.f};
#pragma unroll
  for (int dy = -2; dy <= 2; dy++) {
    int yy = y + dy;
    if (yy < 0 || yy >= 48) continue;
    float4 h5x = {0.f, 0.f, 0.f, 0.f}, h5y = {0.f, 0.f, 0.f, 0.f};
    float4 h3x = {0.f, 0.f, 0.f, 0.f}, h3y = {0.f, 0.f, 0.f, 0.f};
#pragma unroll
    for (int dx = -2; dx <= 2; dx++) {
      int xx = x + dx;
      if (xx < 0 || xx >= 48) continue;
      const float* r = S1 + (long)(row + dy * 48 + dx) * 512;
      float4 v0 = *(const float4*)(r + lane * 4);
      float4 v1 = *(const float4*)(r + 256 + lane * 4);
      h5x.x += v0.x; h5x.y += v0.y; h5x.z += v0.z; h5x.w += v0.w;
      h5y.x += v1.x; h5y.y += v1.y; h5y.z += v1.z; h5y.w += v1.w;
      if (dx >= -1 && dx <= 1) {
        h3x.x += v0.x; h3x.y += v0.y; h3x.z += v0.z; h3x.w += v0.w;
        h3y.x += v1.x; h3y.y += v1.y; h3y.z += v1.z; h3y.w += v1.w;
      }
      if (dx == 0 && dy == 0) { c0 = v0; c1 = v1; }
    }
    a5x.x += h5x.x; a5x.y += h5x.y; a5x.z += h5x.z; a5x.w += h5x.w;
    a5y.x += h5y.x; a5y.y += h5y.y; a5y.z += h5y.z; a5y.w += h5y.w;
    if (dy >= -1 && dy <= 1) {
      a3x.x += h3x.x; a3x.y += h3x.y; a3x.z += h3x.z; a3x.w += h3x.w;
      a3y.x += h3y.x; a3y.y += h3y.y; a3y.z += h3y.z; a3y.w += h3y.w;
    }
  }
  const float* bk = bkq + (long)bloc * 512;
  float4 q0 = *(const float4*)(bk + lane * 4);
  float4 q1v = *(const float4*)(bk + 256 + lane * 4);
  float o0 = 0.f, o1 = 0.f, o2 = 0.f, o3 = 0.f, o4 = 0.f, o5 = 0.f, o6 = 0.f, o7 = 0.f;
  // scale 1: raw center + bkq
  c0.x += q0.x;  c0.y += q0.y;  c0.z += q0.z;  c0.w += q0.w;
  c1.x += q1v.x; c1.y += q1v.y; c1.z += q1v.z; c1.w += q1v.w;
  sm_accum(c0, c1, wts[0], o0, o1, o2, o3, o4, o5, o6, o7);
  // scale 3
  const float ik3 = 1.0f / 9.0f;
  a3x.x = a3x.x * ik3 + q0.x;  a3x.y = a3x.y * ik3 + q0.y;
  a3x.z = a3x.z * ik3 + q0.z;  a3x.w = a3x.w * ik3 + q0.w;
  a3y.x = a3y.x * ik3 + q1v.x; a3y.y = a3y.y * ik3 + q1v.y;
  a3y.z = a3y.z * ik3 + q1v.z; a3y.w = a3y.w * ik3 + q1v.w;
  sm_accum(a3x, a3y, wts[1], o0, o1, o2, o3, o4, o5, o6, o7);
  // scale 5
  const float ik5 = 1.0f / 25.0f;
  a5x.x = a5x.x * ik5 + q0.x;  a5x.y = a5x.y * ik5 + q0.y;
  a5x.z = a5x.z * ik5 + q0.z;  a5x.w = a5x.w * ik5 + q0.w;
  a5y.x = a5y.x * ik5 + q1v.x; a5y.y = a5y.y * ik5 + q1v.y;
  a5y.z = a5y.z * ik5 + q1v.z; a5y.w = a5y.w * ik5 + q1v.w;
  sm_accum(a5x, a5y, wts[2], o0, o1, o2, o3, o4, o5, o6, o7);
  // single bf16 write
  union { u16 u[4]; uint2 v; } pk;
  u16* pr = P + (long)row * 512;
  pk.u[0] = f2b(o0); pk.u[1] = f2b(o1); pk.u[2] = f2b(o2); pk.u[3] = f2b(o3);
  *(uint2*)(pr + lane * 4) = pk.v;
  pk.u[0] = f2b(o4); pk.u[1] = f2b(o5); pk.u[2] = f2b(o6); pk.u[3] = f2b(o7);
  *(uint2*)(pr + 256 + lane * 4) = pk.v;
}

extern "C" void kernel_launch(void* const* d_in, const int* in_sizes, int n_in,
                              void* d_out, int out_size, void* d_ws, size_t ws_size,
                              hipStream_t stream) {
  const float* v_feat = (const float*)d_in[0];
  const float* t_tok  = (const float*)d_in[1];
  const float* Wq  = (const float*)d_in[2];
  const float* bq  = (const float*)d_in[3];
  const float* Wk  = (const float*)d_in[4];
  const float* bk  = (const float*)d_in[5];
  const float* Wv  = (const float*)d_in[6];
  const float* bv  = (const float*)d_in[7];
  const float* lam = (const float*)d_in[8];

  // Workspace layout (87.6 MB; loop = 4 super-chunks of 4 batches; every loop
  // kernel is a single z=4 launch: transpose, S-GEMM, pool_sm, PV).
  char* const wsb = (char*)d_ws;
  float* wts  = (float*)(wsb);                  // 256 B
  u16* Wq16   = (u16*)(wsb + 256);              // 2 MB
  u16* Wk16   = (u16*)(wsb + 2097408);          // 1.5 MB
  u16* WvT    = (u16*)(wsb + 3670272);          // 1.5 MB
  u16* GT     = (u16*)(wsb + 5243136);          // (1024, 768) bf16, 1.5 MB
  float* hvec = (float*)(wsb + 6816000);        // 4 KB
  float* uvec = (float*)(wsb + 6820096);        // 769 floats (+pad)
  float* bkq  = (float*)(wsb + 6824192);        // (B, L) fp32, 32 KB
  u16* WkqT   = (u16*)(wsb + 6856960);          // (B*L, C) bf16, 16.8 MB
  u16* vtxtT  = (u16*)(wsb + 23634176);         // (B, C, L) bf16, 16.8 MB
  char* const chunk = wsb + 40411392;
  u16* tt16   = (u16*)chunk;                    // (B*L, Ct) bf16, 12.6 MB (pre-loop only)
  u16* vflat4 = (u16*)chunk;                    // (4N, C) bf16, 18.87 MB
  float* S14  = (float*)(chunk + 18874368);     // (4N, L) fp32, 18.87 MB
  u16* Psum   = (u16*)(chunk + 37748736);       // (4N, L) bf16, 9.44 MB
  // end: 40411392 + 47185920 = 87,597,312 B

  float* out0 = (float*)d_out;
  const long CN = 1024L * 2304;

  softmax3_kernel<<<1, 64, 0, stream>>>(lam, wts);

  cast_f32_bf16<<<512, 256, 0, stream>>>(Wq, Wq16);       // 1048576 elems
  cast_f32_bf16<<<384, 256, 0, stream>>>(Wk, Wk16);       // 786432 elems
  transpose_f32<<<dim3(12, 16, 1), 256, 0, stream>>>(Wv, WvT, 768, 1024, 0, 0);
  cast_f32_bf16<<<3072, 256, 0, stream>>>(t_tok, tt16);   // 6291456 elems
  smallvecs_kernel<<<449, 256, 0, stream>>>(Wq, Wk, bq, bk, hvec, uvec);

  // GT(ci,t) = sum_co Wq(ci,co) * Wk(t,co)   : (1024, 768), K=1024
  gemm_nt<0, 0, false><<<dim3(8, 6, 1), 256, 0, stream>>>(
      Wq16, 0, 1024, Wk16, 0, 1024, GT, 0, 768, nullptr, nullptr, nullptr, 1.0f, 1024);
  // WkqT(l,ci) = sum_t tt16(l,t) * GT(ci,t) + h(ci)  : (8192, 1024), K=768
  gemm_nt<1, 0, false><<<dim3(64, 8, 1), 256, 0, stream>>>(
      tt16, 0, 768, GT, 0, 768, WkqT, 0, 1024, hvec, nullptr, nullptr, 1.0f, 768);
  // v_txtT(b) = Wv^T @ t_tok(b)^T + bv (per-m) : (1024,512) per batch, K=768
  gemm_nt<2, 0, false><<<dim3(8, 4, 16), 256, 0, stream>>>(
      WvT, 0, 768, tt16, 512L * 768, 768, vtxtT, 1024L * 512, 512, bv, nullptr, nullptr, 1.0f, 768);
  // bkq[b,l] = scale * (tt16[b,l,:].u + beta0)
  bkq_kernel<<<2048, 256, 0, stream>>>(tt16, uvec, bkq);

  for (int sc = 0; sc < 4; sc++) {
    const long b0 = 4L * sc;
    // vflat4 = transpose(v_feat 4-batch super-chunk) as bf16: (4N, C)
    transpose_f32<<<dim3(16, 36, 4), 256, 0, stream>>>(
        v_feat + b0 * CN, vflat4, 1024, 2304, CN, 2304L * 1024);
    // S14 = (vflat4 @ WkqT_b^T) / 32  (fp32, per batch), one z=4 launch (288 blocks)
    gemm_s_sk2<<<dim3(18, 4, 4), 512, 0, stream>>>(
        vflat4, 2304L * 1024, 1024, WkqT + b0 * (512L * 1024), 512L * 1024, 1024,
        S14, 2304L * 512, 512, 0.03125f, 1024);
    // fused 25-tap pool + 3 softmaxes -> single weighted Psum (K=512 for PV)
    pool_sm<<<2304, 256, 0, stream>>>(S14, bkq + b0 * 512, Psum, wts);
    // out^T: out(c,n) = sum_l vtxtT(c,l) * Psum(n,l) + v_feat(c,n)
    gemm_nt<0, 3, false><<<dim3(8, 18, 4), 256, 0, stream>>>(
        vtxtT + b0 * (1024L * 512), 1024L * 512, 512, Psum, 2304L * 512, 512,
        out0 + b0 * CN, CN, 2304, nullptr, v_feat + b0 * CN, nullptr, 1.0f, 512);
  }

  // out1 = t_tok (raw fp32 copy)
  hipMemcpyAsync((void*)(out0 + 37748736L), (const void*)t_tok, 25165824L,
                 hipMemcpyDeviceToDevice, stream);
}

// Round 8
// 667.767 us; speedup vs baseline: 4.0009x; 1.1283x over previous
//
#include <hip/hip_runtime.h>

typedef unsigned short u16;
typedef short short8 __attribute__((ext_vector_type(8)));
typedef float floatx4 __attribute__((ext_vector_type(4)));

__device__ __forceinline__ float b2f(u16 h) {
  union { unsigned int u; float f; } z;
  z.u = ((unsigned int)h) << 16;
  return z.f;
}
__device__ __forceinline__ u16 f2b(float f) {
  union { float f; unsigned int u; } z;
  z.f = f;
  unsigned int u = z.u;
  unsigned int r = (u + 0x7fffu + ((u >> 16) & 1u)) >> 16;
  return (u16)r;
}

// ---- global_load_lds staging of a 128x64 bf16 tile (16 KB), XOR-swizzled ----------
__device__ __forceinline__ void stage_tile64(const u16* __restrict__ gsrc, int lda,
                                             u16* lds, int wave, int lane) {
#pragma unroll
  for (int i = 0; i < 4; i++) {
    const int s = wave * 256 + i * 64 + lane;
    const int row = s >> 3;
    const int c8 = (s & 7) ^ (row & 7);
    const u16* g = gsrc + (long)row * lda + (c8 << 3);
    u16* l = lds + (wave * 256 + i * 64) * 8;  // wave-uniform
    __builtin_amdgcn_global_load_lds(
        (const __attribute__((address_space(1))) unsigned int*)g,
        (__attribute__((address_space(3))) unsigned int*)l, 16, 0, 0);
  }
}
// swizzled 16B fragment read: row in [0,128), slot in [0,8)
__device__ __forceinline__ short8 frag64(const u16* lds, int row, int slot) {
  return *(const short8*)(lds + (row << 6) + ((slot ^ (row & 7)) << 3));
}

// ---------------- merged cast fp32 -> bf16 for Wq | Wk | t_tok -----------------------
// blocks [0,512): Wq (1M elems); [512,896): Wk (768K); [896,3968): t_tok (6M).
__global__ __launch_bounds__(256)
void cast3_kernel(const float* __restrict__ Wq, const float* __restrict__ Wk,
                  const float* __restrict__ tt, u16* __restrict__ Wq16,
                  u16* __restrict__ Wk16, u16* __restrict__ tt16) {
  const int blk = blockIdx.x;
  const float* src; u16* dst; long base;
  if (blk < 512) { src = Wq; dst = Wq16; base = (long)blk; }
  else if (blk < 896) { src = Wk; dst = Wk16; base = (long)(blk - 512); }
  else { src = tt; dst = tt16; base = (long)(blk - 896); }
  const long i = (base * 256 + threadIdx.x) * 8;
  float4 v0 = *(const float4*)(src + i);
  float4 v1 = *(const float4*)(src + i + 4);
  u16 r[8] __attribute__((aligned(16)));
  r[0] = f2b(v0.x); r[1] = f2b(v0.y); r[2] = f2b(v0.z); r[3] = f2b(v0.w);
  r[4] = f2b(v1.x); r[5] = f2b(v1.y); r[6] = f2b(v1.z); r[7] = f2b(v1.w);
  *(uint4*)(dst + i) = *(const uint4*)r;
}

// ---------------- transpose fp32 src (b,R,Cc) -> bf16 dst (b,Cc,R) ------------------
__global__ __launch_bounds__(256)
void transpose_f32(const float* __restrict__ src, u16* __restrict__ dst,
                   int R, int Cc, long sSrc, long sDst) {
  __shared__ u16 t[64][66];
  const int tid = threadIdx.x;
  const long r0 = (long)blockIdx.x << 6;
  const long c0 = (long)blockIdx.y << 6;
  const float* s = src + (long)blockIdx.z * sSrc;
  u16* d = dst + (long)blockIdx.z * sDst;
  const int rr = tid >> 2;
  const int cb = (tid & 3) << 2;  // 0,4,8,12
#pragma unroll
  for (int h = 0; h < 4; h++) {
    int cc = cb + h * 16;
    float4 v = *(const float4*)(s + (r0 + rr) * Cc + c0 + cc);
    t[rr][cc + 0] = f2b(v.x); t[rr][cc + 1] = f2b(v.y);
    t[rr][cc + 2] = f2b(v.z); t[rr][cc + 3] = f2b(v.w);
  }
  __syncthreads();
  const int cr = tid >> 2;
  const int nb0 = (tid & 3) << 3;
#pragma unroll
  for (int h = 0; h < 2; h++) {
    int rb = nb0 + h * 32;
    u16 res[8] __attribute__((aligned(16)));
#pragma unroll
    for (int j = 0; j < 8; j++) res[j] = t[rb + j][cr];
    *(uint4*)(d + (c0 + cr) * R + r0 + rb) = *(const uint4*)res;
  }
}

// ---------------- GEMM: C = alpha * A(row-major MxK) * B^T (B is NxK row-major) ------
// BK=64, global_load_lds staging, XOR-swizzled LDS. K must be a multiple of 64.
template <int BIAS_MODE, int OUT_MODE, bool BETA_ACC>
__global__ __launch_bounds__(256)
void gemm_nt(const u16* __restrict__ A, long sA, int lda,
             const u16* __restrict__ Bm, long sB, int ldb,
             void* __restrict__ Cv, long sC, int ldc,
             const float* __restrict__ bias, const float* __restrict__ resid,
             const float* __restrict__ alphap, float alphac, int K) {
  __shared__ __align__(16) u16 As[8192];
  __shared__ __align__(16) u16 Bs[8192];
  const int tid = threadIdx.x;
  const long m0 = (long)blockIdx.x * 128;
  const long n0 = (long)blockIdx.y * 128;
  const u16* Ab = A + (long)blockIdx.z * sA + m0 * lda;
  const u16* Bb = Bm + (long)blockIdx.z * sB + n0 * ldb;
  const int wave = tid >> 6;
  const int lane = tid & 63;
  const int wr = (wave >> 1) << 6;
  const int wc = (wave & 1) << 6;
  const int quad = lane >> 4;
  const int lr = lane & 15;
  floatx4 acc[4][4] = {};
  for (int k0 = 0; k0 < K; k0 += 64) {
    __syncthreads();
    stage_tile64(Ab + k0, lda, As, wave, lane);
    stage_tile64(Bb + k0, ldb, Bs, wave, lane);
    __syncthreads();
#pragma unroll
    for (int kk = 0; kk < 2; kk++) {
      short8 af[4], bfr[4];
#pragma unroll
      for (int i = 0; i < 4; i++) af[i] = frag64(As, wr + i * 16 + lr, kk * 4 + quad);
#pragma unroll
      for (int j = 0; j < 4; j++) bfr[j] = frag64(Bs, wc + j * 16 + lr, kk * 4 + quad);
#pragma unroll
      for (int i = 0; i < 4; i++)
#pragma unroll
        for (int j = 0; j < 4; j++)
          acc[i][j] = __builtin_amdgcn_mfma_f32_16x16x32_bf16(af[i], bfr[j], acc[i][j], 0, 0, 0);
    }
  }
  const float alpha = alphac * (alphap ? alphap[0] : 1.0f);
  const long cb = (long)blockIdx.z * sC;
#pragma unroll
  for (int i = 0; i < 4; i++) {
#pragma unroll
    for (int r = 0; r < 4; r++) {
      long m = m0 + wr + i * 16 + quad * 4 + r;
      float bm = (BIAS_MODE == 2) ? bias[m] : 0.0f;
#pragma unroll
      for (int j = 0; j < 4; j++) {
        long n = n0 + wc + j * 16 + lr;
        float v = alpha * acc[i][j][r];
        if (BIAS_MODE == 1) v += bias[n];
        if (BIAS_MODE == 2) v += bm;
        long off = cb + m * (long)ldc + n;
        if (OUT_MODE == 3) {
          float* Cf = (float*)Cv;
          Cf[off] = v + resid[off];
        } else if (OUT_MODE == 1) {
          float* Cf = (float*)Cv;
          if (BETA_ACC) v += Cf[off];
          Cf[off] = v;
        } else {
          ((u16*)Cv)[off] = f2b(v);
        }
      }
    }
  }
}

// ---------------- split-K2 GEMM for S (latency-sensitive) ----------------------------
__global__ __launch_bounds__(512)
void gemm_s_sk2(const u16* __restrict__ A, long sA, int lda,
                const u16* __restrict__ Bm, long sB, int ldb,
                float* __restrict__ C, long sC, int ldc,
                float alpha, int K) {
  __shared__ __align__(16) u16 smem[32768];  // 64 KB
  float* scr = (float*)smem;                 // epilogue scratch aliases staging
  const int tid = threadIdx.x;
  const int h = tid >> 8;               // k-half
  const long m0 = (long)blockIdx.x * 128;
  const long n0 = (long)blockIdx.y * 128;
  const int Kh = K >> 1;
  const u16* Ab = A + (long)blockIdx.z * sA + m0 * lda + (long)h * Kh;
  const u16* Bb = Bm + (long)blockIdx.z * sB + n0 * ldb + (long)h * Kh;
  u16* AsH = smem + h * 8192;
  u16* BsH = smem + 16384 + h * 8192;
  const int wave = tid >> 6;            // 0..7
  const int w4 = wave & 3;              // wave within half
  const int q = wave & 3;               // output quadrant (shared between halves)
  const int lane = tid & 63;
  const int wr = (q >> 1) << 6;
  const int wc = (q & 1) << 6;
  const int quad = lane >> 4;
  const int lr = lane & 15;
  floatx4 acc[4][4] = {};
  for (int k0 = 0; k0 < Kh; k0 += 64) {
    __syncthreads();
    stage_tile64(Ab + k0, lda, AsH, w4, lane);
    stage_tile64(Bb + k0, ldb, BsH, w4, lane);
    __syncthreads();
#pragma unroll
    for (int kk = 0; kk < 2; kk++) {
      short8 af[4], bfr[4];
#pragma unroll
      for (int i = 0; i < 4; i++) af[i] = frag64(AsH, wr + i * 16 + lr, kk * 4 + quad);
#pragma unroll
      for (int j = 0; j < 4; j++) bfr[j] = frag64(BsH, wc + j * 16 + lr, kk * 4 + quad);
#pragma unroll
      for (int i = 0; i < 4; i++)
#pragma unroll
        for (int j = 0; j < 4; j++)
          acc[i][j] = __builtin_amdgcn_mfma_f32_16x16x32_bf16(af[i], bfr[j], acc[i][j], 0, 0, 0);
    }
  }
  __syncthreads();
#pragma unroll
  for (int pass = 0; pass < 2; pass++) {
    if (h == 1 && (q >> 1) == pass) {
#pragma unroll
      for (int i = 0; i < 4; i++)
#pragma unroll
        for (int j = 0; j < 4; j++)
          *(floatx4*)&scr[(q & 1) * 4096 + (j * 16 + lr) * 64 +
                          (((i * 16 + quad * 4)) ^ ((lr & 7) << 2))] = acc[i][j];
    }
    __syncthreads();
    if (h == 0 && (q >> 1) == pass) {
#pragma unroll
      for (int i = 0; i < 4; i++)
#pragma unroll
        for (int j = 0; j < 4; j++)
          acc[i][j] += *(const floatx4*)&scr[(q & 1) * 4096 + (j * 16 + lr) * 64 +
                                             (((i * 16 + quad * 4)) ^ ((lr & 7) << 2))];
    }
    __syncthreads();
  }
  if (h == 0) {
    const long cb = (long)blockIdx.z * sC;
#pragma unroll
    for (int i = 0; i < 4; i++) {
#pragma unroll
      for (int r = 0; r < 4; r++) {
        long m = m0 + wr + i * 16 + quad * 4 + r;
#pragma unroll
        for (int j = 0; j < 4; j++) {
          long n = n0 + wc + j * 16 + lr;
          C[cb + m * (long)ldc + n] = alpha * acc[i][j][r];
        }
      }
    }
  }
}

// ---------------- small vecs + folded softmax3 ---------------------------------------
// rows 0..1023: hvec[ci] = Wq[ci].bk ; rows 1024..1791: uvec[t] = Wk[t].bq ;
// row 1792: uvec[768] = bk.bq ; row 1793: lane0 computes softmax(lam) -> w[0..2].
__global__ __launch_bounds__(256)
void smallvecs_kernel(const float* __restrict__ Wq, const float* __restrict__ Wk,
                      const float* __restrict__ bq, const float* __restrict__ bk,
                      const float* __restrict__ lam,
                      float* __restrict__ hvec, float* __restrict__ uvec,
                      float* __restrict__ w) {
  const int row = blockIdx.x * 4 + (threadIdx.x >> 6);
  const int lane = threadIdx.x & 63;
  if (row == 1793) {
    if (lane == 0) {
      float a = lam[0], b = lam[1], c = lam[2];
      float m = fmaxf(a, fmaxf(b, c));
      float ea = __expf(a - m), eb = __expf(b - m), ec = __expf(c - m);
      float s = ea + eb + ec;
      w[0] = ea / s; w[1] = eb / s; w[2] = ec / s;
    }
    return;
  }
  if (row > 1792) return;
  const float* src; const float* vec; float* dst;
  if (row < 1024) { src = Wq + (long)row * 1024; vec = bk; dst = hvec + row; }
  else if (row < 1792) { src = Wk + (long)(row - 1024) * 1024; vec = bq; dst = uvec + (row - 1024); }
  else { src = bk; vec = bq; dst = uvec + 768; }
  float s = 0.f;
#pragma unroll
  for (int h = 0; h < 4; h++) {
    float4 a = *(const float4*)(src + h * 256 + lane * 4);
    float4 b = *(const float4*)(vec + h * 256 + lane * 4);
    s += a.x * b.x + a.y * b.y + a.z * b.z + a.w * b.w;
  }
#pragma unroll
  for (int o = 32; o > 0; o >>= 1) s += __shfl_xor(s, o);
  if (lane == 0) *dst = s;
}

// ---------------- bkq[b,l] = 0.03125 * (tt16[b,l,:].uvec + beta0) --------------------
__global__ __launch_bounds__(256)
void bkq_kernel(const u16* __restrict__ tt, const float* __restrict__ uvec,
                float* __restrict__ bkq) {
  const long row = (long)blockIdx.x * 4 + (threadIdx.x >> 6);  // [0, 8192)
  const int lane = threadIdx.x & 63;
  const u16* tr = tt + row * 768;
  float s = 0.f;
#pragma unroll
  for (int h = 0; h < 3; h++) {
    uint2 kv = *(const uint2*)(tr + h * 256 + lane * 4);
    const u16* ku = (const u16*)&kv;
    float4 b = *(const float4*)(uvec + h * 256 + lane * 4);
    s += b2f(ku[0]) * b.x + b2f(ku[1]) * b.y + b2f(ku[2]) * b.z + b2f(ku[3]) * b.w;
  }
#pragma unroll
  for (int o = 32; o > 0; o >>= 1) s += __shfl_xor(s, o);
  if (lane == 0) bkq[row] = 0.03125f * (s + uvec[768]);
}

// ---------------- softmax + weighted fp32 accumulate (no intermediate bf16) ----------
__device__ __forceinline__ void sm_accum(float4 a0, float4 a1, float w,
                                         float& o0, float& o1, float& o2, float& o3,
                                         float& o4, float& o5, float& o6, float& o7) {
  float m = fmaxf(fmaxf(fmaxf(a0.x, a0.y), fmaxf(a0.z, a0.w)),
                  fmaxf(fmaxf(a1.x, a1.y), fmaxf(a1.z, a1.w)));
#pragma unroll
  for (int o = 32; o > 0; o >>= 1) m = fmaxf(m, __shfl_xor(m, o));
  float e0 = __expf(a0.x - m), e1 = __expf(a0.y - m), e2 = __expf(a0.z - m), e3 = __expf(a0.w - m);
  float e4 = __expf(a1.x - m), e5 = __expf(a1.y - m), e6 = __expf(a1.z - m), e7 = __expf(a1.w - m);
  float s = ((e0 + e1) + (e2 + e3)) + ((e4 + e5) + (e6 + e7));
#pragma unroll
  for (int o = 32; o > 0; o >>= 1) s += __shfl_xor(s, o);
  const float inv = w / s;
  o0 += e0 * inv; o1 += e1 * inv; o2 += e2 * inv; o3 += e3 * inv;
  o4 += e4 * inv; o5 += e5 * inv; o6 += e6 * inv; o7 += e7 * inv;
}

// ---------------- fused 25-tap 2D pool + 3x softmax -> SINGLE weighted P -------------
__global__ __launch_bounds__(256)
void pool_sm(const float* __restrict__ S1, const float* __restrict__ bkq,
             u16* __restrict__ P, const float* __restrict__ wts) {
  const int row = blockIdx.x * 4 + (threadIdx.x >> 6);
  const int lane = threadIdx.x & 63;
  const int bloc = row / 2304;
  const int nn = row - bloc * 2304;
  const int x = nn % 48;
  const int y = nn / 48;
  float4 c0 = {0.f, 0.f, 0.f, 0.f}, c1 = {0.f, 0.f, 0.f, 0.f};
  float4 a3x = {0.f, 0.f, 0.f, 0.f}, a3y = {0.f, 0.f, 0.f, 0.f};
  float4 a5x = {0.f, 0.f, 0.f, 0.f}, a5y = {0.f, 0.f, 0.f, 0.f};
#pragma unroll
  for (int dy = -2; dy <= 2; dy++) {
    int yy = y + dy;
    if (yy < 0 || yy >= 48) continue;
    float4 h5x = {0.f, 0.f, 0.f, 0.f}, h5y = {0.f, 0.f, 0.f, 0.f};
    float4 h3x = {0.f, 0.f, 0.f, 0.f}, h3y = {0.f, 0.f, 0.f, 0.f};
#pragma unroll
    for (int dx = -2; dx <= 2; dx++) {
      int xx = x + dx;
      if (xx < 0 || xx >= 48) continue;
      const float* r = S1 + (long)(row + dy * 48 + dx) * 512;
      float4 v0 = *(const float4*)(r + lane * 4);
      float4 v1 = *(const float4*)(r + 256 + lane * 4);
      h5x.x += v0.x; h5x.y += v0.y; h5x.z += v0.z; h5x.w += v0.w;
      h5y.x += v1.x; h5y.y += v1.y; h5y.z += v1.z; h5y.w += v1.w;
      if (dx >= -1 && dx <= 1) {
        h3x.x += v0.x; h3x.y += v0.y; h3x.z += v0.z; h3x.w += v0.w;
        h3y.x += v1.x; h3y.y += v1.y; h3y.z += v1.z; h3y.w += v1.w;
      }
      if (dx == 0 && dy == 0) { c0 = v0; c1 = v1; }
    }
    a5x.x += h5x.x; a5x.y += h5x.y; a5x.z += h5x.z; a5x.w += h5x.w;
    a5y.x += h5y.x; a5y.y += h5y.y; a5y.z += h5y.z; a5y.w += h5y.w;
    if (dy >= -1 && dy <= 1) {
      a3x.x += h3x.x; a3x.y += h3x.y; a3x.z += h3x.z; a3x.w += h3x.w;
      a3y.x += h3y.x; a3y.y += h3y.y; a3y.z += h3y.z; a3y.w += h3y.w;
    }
  }
  const float* bk = bkq + (long)bloc * 512;
  float4 q0 = *(const float4*)(bk + lane * 4);
  float4 q1v = *(const float4*)(bk + 256 + lane * 4);
  float o0 = 0.f, o1 = 0.f, o2 = 0.f, o3 = 0.f, o4 = 0.f, o5 = 0.f, o6 = 0.f, o7 = 0.f;
  // scale 1: raw center + bkq
  c0.x += q0.x;  c0.y += q0.y;  c0.z += q0.z;  c0.w += q0.w;
  c1.x += q1v.x; c1.y += q1v.y; c1.z += q1v.z; c1.w += q1v.w;
  sm_accum(c0, c1, wts[0], o0, o1, o2, o3, o4, o5, o6, o7);
  // scale 3
  const float ik3 = 1.0f / 9.0f;
  a3x.x = a3x.x * ik3 + q0.x;  a3x.y = a3x.y * ik3 + q0.y;
  a3x.z = a3x.z * ik3 + q0.z;  a3x.w = a3x.w * ik3 + q0.w;
  a3y.x = a3y.x * ik3 + q1v.x; a3y.y = a3y.y * ik3 + q1v.y;
  a3y.z = a3y.z * ik3 + q1v.z; a3y.w = a3y.w * ik3 + q1v.w;
  sm_accum(a3x, a3y, wts[1], o0, o1, o2, o3, o4, o5, o6, o7);
  // scale 5
  const float ik5 = 1.0f / 25.0f;
  a5x.x = a5x.x * ik5 + q0.x;  a5x.y = a5x.y * ik5 + q0.y;
  a5x.z = a5x.z * ik5 + q0.z;  a5x.w = a5x.w * ik5 + q0.w;
  a5y.x = a5y.x * ik5 + q1v.x; a5y.y = a5y.y * ik5 + q1v.y;
  a5y.z = a5y.z * ik5 + q1v.z; a5y.w = a5y.w * ik5 + q1v.w;
  sm_accum(a5x, a5y, wts[2], o0, o1, o2, o3, o4, o5, o6, o7);
  // single bf16 write
  union { u16 u[4]; uint2 v; } pk;
  u16* pr = P + (long)row * 512;
  pk.u[0] = f2b(o0); pk.u[1] = f2b(o1); pk.u[2] = f2b(o2); pk.u[3] = f2b(o3);
  *(uint2*)(pr + lane * 4) = pk.v;
  pk.u[0] = f2b(o4); pk.u[1] = f2b(o5); pk.u[2] = f2b(o6); pk.u[3] = f2b(o7);
  *(uint2*)(pr + 256 + lane * 4) = pk.v;
}

extern "C" void kernel_launch(void* const* d_in, const int* in_sizes, int n_in,
                              void* d_out, int out_size, void* d_ws, size_t ws_size,
                              hipStream_t stream) {
  const float* v_feat = (const float*)d_in[0];
  const float* t_tok  = (const float*)d_in[1];
  const float* Wq  = (const float*)d_in[2];
  const float* bq  = (const float*)d_in[3];
  const float* Wk  = (const float*)d_in[4];
  const float* bk  = (const float*)d_in[5];
  const float* Wv  = (const float*)d_in[6];
  const float* bv  = (const float*)d_in[7];
  const float* lam = (const float*)d_in[8];

  // Persistent region: 40.4 MB. Chunked region: NB batches x 11.8 MB
  // (vflat 4.72 + S 4.72 + Psum 2.36). NB chosen at runtime from ws_size;
  // NB=4 (87.6 MB total) is the known-passing fallback.
  char* const wsb = (char*)d_ws;
  float* wts  = (float*)(wsb);                  // 256 B
  u16* Wq16   = (u16*)(wsb + 256);              // 2 MB
  u16* Wk16   = (u16*)(wsb + 2097408);          // 1.5 MB
  u16* WvT    = (u16*)(wsb + 3670272);          // 1.5 MB
  u16* GT     = (u16*)(wsb + 5243136);          // (1024, 768) bf16, 1.5 MB
  float* hvec = (float*)(wsb + 6816000);        // 4 KB
  float* uvec = (float*)(wsb + 6820096);        // 769 floats (+pad)
  float* bkq  = (float*)(wsb + 6824192);        // (B, L) fp32, 32 KB
  u16* WkqT   = (u16*)(wsb + 6856960);          // (B*L, C) bf16, 16.8 MB
  u16* vtxtT  = (u16*)(wsb + 23634176);         // (B, C, L) bf16, 16.8 MB
  const long chunkBase = 40411392;
  char* const chunk = wsb + chunkBase;
  u16* tt16   = (u16*)chunk;                    // 12.6 MB (pre-loop only)

  int NB = 4;
  if (ws_size >= chunkBase + 16L * 11796480) NB = 16;
  else if (ws_size >= chunkBase + 8L * 11796480) NB = 8;
  const long vfB = (long)NB * 2304 * 1024 * 2;  // vflat bytes
  const long sB_ = (long)NB * 2304 * 512 * 4;   // S bytes
  u16* vflatN = (u16*)chunk;
  float* SN   = (float*)(chunk + vfB);
  u16* Psum   = (u16*)(chunk + vfB + sB_);

  float* out0 = (float*)d_out;
  const long CN = 1024L * 2304;

  // merged cast Wq|Wk|t_tok + smallvecs (incl. folded softmax3)
  cast3_kernel<<<3968, 256, 0, stream>>>(Wq, Wk, t_tok, Wq16, Wk16, tt16);
  transpose_f32<<<dim3(12, 16, 1), 256, 0, stream>>>(Wv, WvT, 768, 1024, 0, 0);
  smallvecs_kernel<<<449, 256, 0, stream>>>(Wq, Wk, bq, bk, lam, hvec, uvec, wts);

  // GT(ci,t) = sum_co Wq(ci,co) * Wk(t,co)   : (1024, 768), K=1024
  gemm_nt<0, 0, false><<<dim3(8, 6, 1), 256, 0, stream>>>(
      Wq16, 0, 1024, Wk16, 0, 1024, GT, 0, 768, nullptr, nullptr, nullptr, 1.0f, 1024);
  // WkqT(l,ci) = sum_t tt16(l,t) * GT(ci,t) + h(ci)  : (8192, 1024), K=768
  gemm_nt<1, 0, false><<<dim3(64, 8, 1), 256, 0, stream>>>(
      tt16, 0, 768, GT, 0, 768, WkqT, 0, 1024, hvec, nullptr, nullptr, 1.0f, 768);
  // v_txtT(b) = Wv^T @ t_tok(b)^T + bv (per-m) : (1024,512) per batch, K=768
  gemm_nt<2, 0, false><<<dim3(8, 4, 16), 256, 0, stream>>>(
      WvT, 0, 768, tt16, 512L * 768, 768, vtxtT, 1024L * 512, 512, bv, nullptr, nullptr, 1.0f, 768);
  // bkq[b,l] = scale * (tt16[b,l,:].u + beta0)
  bkq_kernel<<<2048, 256, 0, stream>>>(tt16, uvec, bkq);

  for (int b0 = 0; b0 < 16; b0 += NB) {
    // vflat = transpose(v_feat NB-batch chunk) as bf16: (NB*N, C)
    transpose_f32<<<dim3(16, 36, NB), 256, 0, stream>>>(
        v_feat + b0 * CN, vflatN, 1024, 2304, CN, 2304L * 1024);
    // S = (vflat @ WkqT_b^T) / 32  (fp32, per batch), split-K2
    gemm_s_sk2<<<dim3(18, 4, NB), 512, 0, stream>>>(
        vflatN, 2304L * 1024, 1024, WkqT + (long)b0 * (512L * 1024), 512L * 1024, 1024,
        SN, 2304L * 512, 512, 0.03125f, 1024);
    // fused 25-tap pool + 3 softmaxes -> single weighted Psum (K=512 for PV)
    pool_sm<<<576 * NB, 256, 0, stream>>>(SN, bkq + (long)b0 * 512, Psum, wts);
    // out^T: out(c,n) = sum_l vtxtT(c,l) * Psum(n,l) + v_feat(c,n)
    gemm_nt<0, 3, false><<<dim3(8, 18, NB), 256, 0, stream>>>(
        vtxtT + (long)b0 * (1024L * 512), 1024L * 512, 512, Psum, 2304L * 512, 512,
        out0 + b0 * CN, CN, 2304, nullptr, v_feat + b0 * CN, nullptr, 1.0f, 512);
  }

  // out1 = t_tok (raw fp32 copy)
  hipMemcpyAsync((void*)(out0 + 37748736L), (const void*)t_tok, 25165824L,
                 hipMemcpyDeviceToDevice, stream);
}